// Round 1
// baseline (1127.397 us; speedup 1.0000x reference)
//
#include <hip/hip_runtime.h>
#include <math.h>

#define D 128

// ---------------- CSR build (by dst) ----------------
__global__ void k_count(const int* __restrict__ ei, int* __restrict__ deg, int E) {
  int e = blockIdx.x * 256 + threadIdx.x;
  if (e < E) atomicAdd(&deg[ei[E + e]], 1);
}

__global__ __launch_bounds__(1024) void k_scan(const int* __restrict__ deg,
    int* __restrict__ row_ptr, int* __restrict__ cursor, int n, int per) {
  int tid = threadIdx.x;
  int start = tid * per;
  int end = min(start + per, n);
  int sum = 0;
  for (int i = start; i < end; i++) sum += deg[i];
  int lane = tid & 63, wid = tid >> 6;
  __shared__ int ws[16];
  int incl = sum;
  #pragma unroll
  for (int off = 1; off < 64; off <<= 1) {
    int t = __shfl_up(incl, off, 64);
    if (lane >= off) incl += t;
  }
  if (lane == 63) ws[wid] = incl;
  __syncthreads();
  if (tid < 16) {
    int v = ws[tid];
    int inc2 = v;
    #pragma unroll
    for (int off = 1; off < 16; off <<= 1) {
      int t = __shfl_up(inc2, off, 16);
      if (tid >= off) inc2 += t;
    }
    ws[tid] = inc2 - v;  // exclusive prefix of wave sums
  }
  __syncthreads();
  int run = ws[wid] + (incl - sum);  // exclusive prefix for this thread
  for (int i = start; i < end; i++) {
    int d = deg[i];
    cursor[i] = run;
    run += d;
    row_ptr[i + 1] = run;
  }
  if (tid == 0) row_ptr[0] = 0;
}

__global__ void k_fill(const int* __restrict__ ei, int* __restrict__ cursor,
                       int* __restrict__ col, int E) {
  int e = blockIdx.x * 256 + threadIdx.x;
  if (e < E) {
    int pos = atomicAdd(&cursor[ei[E + e]], 1);
    col[pos] = ei[e];  // store src
  }
}

// ---------------- GIN aggregate: m = (1+eps)*h + sum_{s in N(n)} h[s] ----------------
__global__ __launch_bounds__(256) void k_aggregate(const float* __restrict__ h,
    const int* __restrict__ row_ptr, const int* __restrict__ col,
    const float* __restrict__ eps, int layer, float* __restrict__ m, int n) {
  int node = blockIdx.x * 8 + (threadIdx.x >> 5);
  if (node >= n) return;
  int c = (threadIdx.x & 31) << 2;
  float4 acc = make_float4(0.f, 0.f, 0.f, 0.f);
  int beg = row_ptr[node], end = row_ptr[node + 1];
  for (int i = beg; i < end; i++) {
    int s = col[i];  // broadcast across the 32 lanes of this node
    const float4 v = *(const float4*)(h + (size_t)s * D + c);
    acc.x += v.x; acc.y += v.y; acc.z += v.z; acc.w += v.w;
  }
  float ep = 1.0f + eps[layer];
  const float4 hv = *(const float4*)(h + (size_t)node * D + c);
  acc.x = fmaf(ep, hv.x, acc.x);
  acc.y = fmaf(ep, hv.y, acc.y);
  acc.z = fmaf(ep, hv.z, acc.z);
  acc.w = fmaf(ep, hv.w, acc.w);
  *(float4*)(m + (size_t)node * D + c) = acc;
}

// ---------------- GEMM [N,128]@[128,128] with fused affine/ReLU epilogue ----------------
// stages: 0 = +bias,ReLU ; 1 = +bias,BN,ReLU ; 2 = +bias,BN,ReLU,BN,ReLU
__global__ __launch_bounds__(256) void k_gemm128(
    const float* __restrict__ in, const float* __restrict__ W,
    const float* __restrict__ bias,
    const float* __restrict__ g1v, const float* __restrict__ be1,
    const float* __restrict__ rm1, const float* __restrict__ rv1,
    const float* __restrict__ g2v, const float* __restrict__ be2,
    const float* __restrict__ rm2, const float* __restrict__ rv2,
    float* __restrict__ out, int N, int stages) {
  __shared__ float sIn[64][D];  // 32KB input tile (row-major)
  __shared__ float sW[64][D];   // 32KB: one k-half of W at a time  -> 64KB total
  int tid = threadIdx.x;
  int row0 = blockIdx.x * 64;
  int nrows = min(64, N - row0);

  // stage input tile (zero-pad tail rows)
  for (int i = tid; i < 64 * 32; i += 256) {
    int r = i >> 5, k4 = (i & 31) << 2;
    float4 v = make_float4(0.f, 0.f, 0.f, 0.f);
    if (r < nrows) v = *(const float4*)(in + (size_t)(row0 + r) * D + k4);
    *(float4*)&sIn[r][k4] = v;
  }

  int tx = tid & 31, ty = tid >> 5;
  int c0 = tx << 2, r0 = ty << 3;
  float acc[8][4];
  #pragma unroll
  for (int i = 0; i < 8; i++)
    #pragma unroll
    for (int j = 0; j < 4; j++) acc[i][j] = 0.f;

  for (int half = 0; half < 2; half++) {
    __syncthreads();  // protects sIn staging (1st iter) and sW reuse (2nd iter)
    const float* Wh = W + half * 64 * D;
    for (int i = tid * 4; i < 64 * D; i += 1024)
      *(float4*)(&sW[0][0] + i) = *(const float4*)(Wh + i);
    __syncthreads();
    int kbase = half * 64;
    #pragma unroll 4
    for (int kk = 0; kk < 64; kk += 4) {
      float4 b0 = *(float4*)&sW[kk + 0][c0];
      float4 b1 = *(float4*)&sW[kk + 1][c0];
      float4 b2 = *(float4*)&sW[kk + 2][c0];
      float4 b3 = *(float4*)&sW[kk + 3][c0];
      #pragma unroll
      for (int i = 0; i < 8; i++) {
        float4 a = *(float4*)&sIn[r0 + i][kbase + kk];  // broadcast read
        acc[i][0] += a.x * b0.x + a.y * b1.x + a.z * b2.x + a.w * b3.x;
        acc[i][1] += a.x * b0.y + a.y * b1.y + a.z * b2.y + a.w * b3.y;
        acc[i][2] += a.x * b0.z + a.y * b1.z + a.z * b2.z + a.w * b3.z;
        acc[i][3] += a.x * b0.w + a.y * b1.w + a.z * b2.w + a.w * b3.w;
      }
    }
  }

  // fused epilogue: y -> y*s1+t1, relu, [y*s2+t2, relu]
  float s1[4], t1[4], s2[4], t2[4];
  #pragma unroll
  for (int j = 0; j < 4; j++) {
    int cj = c0 + j;
    float sv = 1.0f, tv = bias ? bias[cj] : 0.0f;
    if (stages >= 1) {
      float inv = rsqrtf(rv1[cj] + 1e-5f);
      float sg = g1v[cj] * inv;
      tv = (tv - rm1[cj]) * sg + be1[cj];
      sv = sg;
    }
    s1[j] = sv; t1[j] = tv;
    if (stages >= 2) {
      float inv = rsqrtf(rv2[cj] + 1e-5f);
      float sg = g2v[cj] * inv;
      s2[j] = sg; t2[j] = be2[cj] - rm2[cj] * sg;
    } else { s2[j] = 1.f; t2[j] = 0.f; }
  }
  #pragma unroll
  for (int i = 0; i < 8; i++) {
    int r = r0 + i;
    if (r < nrows) {
      float4 o;
      float* v = &o.x;
      #pragma unroll
      for (int j = 0; j < 4; j++) {
        float y = acc[i][j] * s1[j] + t1[j];
        y = fmaxf(y, 0.f);
        if (stages >= 2) { y = y * s2[j] + t2[j]; y = fmaxf(y, 0.f); }
        v[j] = y;
      }
      *(float4*)(out + (size_t)(row0 + r) * D + c0) = o;
    }
  }
}

// ---------------- attention MLP: wave per node ----------------
__global__ __launch_bounds__(256) void k_attention(const float* __restrict__ h,
    const float* __restrict__ aW1, const float* __restrict__ ab1,
    const float* __restrict__ aW2, const float* __restrict__ ab2,
    const float* __restrict__ aW3, const float* __restrict__ ab3,
    const float* __restrict__ temp, float* __restrict__ scores, int n) {
  __shared__ float sh[4][D];
  __shared__ float sa1[4][64];
  __shared__ float sa2[4][32];
  int wid = threadIdx.x >> 6, lane = threadIdx.x & 63;
  int node = blockIdx.x * 4 + wid;
  int nodec = min(node, n - 1);
  const float* hr = h + (size_t)nodec * D;
  float2 v = *(const float2*)(hr + lane * 2);
  sh[wid][lane * 2] = v.x;
  sh[wid][lane * 2 + 1] = v.y;
  __syncthreads();
  float a = ab1[lane];
  #pragma unroll 8
  for (int k = 0; k < D; k++) a = fmaf(sh[wid][k], aW1[k * 64 + lane], a);
  a = fmaxf(a, 0.2f * a);  // leaky_relu(x,0.2) == max(x, 0.2x)
  sa1[wid][lane] = a;
  __syncthreads();
  if (lane < 32) {
    float a2 = ab2[lane];
    #pragma unroll 8
    for (int k = 0; k < 64; k++) a2 = fmaf(sa1[wid][k], aW2[k * 32 + lane], a2);
    a2 = fmaxf(a2, 0.2f * a2);
    sa2[wid][lane] = a2;
  }
  __syncthreads();
  if (lane == 0 && node < n) {
    float l3 = ab3[0];
    #pragma unroll 8
    for (int k = 0; k < 32; k++) l3 = fmaf(sa2[wid][k], aW3[k], l3);
    l3 = fminf(fmaxf(l3, -10.f), 10.f);
    scores[node] = 1.0f / (1.0f + __expf(-l3 * temp[0]));
  }
}

// ---------------- attention-weighted pool (batch sorted) ----------------
__global__ __launch_bounds__(128) void k_pool(const float* __restrict__ h,
    const float* __restrict__ scores, const int* __restrict__ batch,
    float* __restrict__ ge, int n) {
  const int NPB = 256;
  int f = threadIdx.x;
  int n0 = blockIdx.x * NPB;
  if (n0 >= n) return;
  int nend = min(n0 + NPB, n);
  float acc = 0.f;
  int cur = batch[n0];  // uniform across threads (broadcast)
  for (int i = n0; i < nend; i++) {
    int b = batch[i];
    if (b != cur) {
      atomicAdd(&ge[(size_t)cur * D + f], acc);
      acc = 0.f;
      cur = b;
    }
    acc = fmaf(h[(size_t)i * D + f], scores[i], acc);
  }
  atomicAdd(&ge[(size_t)cur * D + f], acc);
}

// ---------------- classifier: block per graph ----------------
__global__ __launch_bounds__(128) void k_classifier(const float* __restrict__ ge,
    const float* __restrict__ cW1, const float* __restrict__ cb1,
    const float* __restrict__ cW2, const float* __restrict__ cb2,
    float* __restrict__ logits, int B) {
  __shared__ float sg[D];
  __shared__ float st[D];
  int g = blockIdx.x;
  int tid = threadIdx.x;
  sg[tid] = ge[(size_t)g * D + tid];
  __syncthreads();
  float a = cb1[tid];
  #pragma unroll 8
  for (int k = 0; k < D; k++) a = fmaf(sg[k], cW1[k * D + tid], a);
  st[tid] = fmaxf(a, 0.f);
  __syncthreads();
  if (tid < 3) {
    float a2 = cb2[tid];
    for (int k = 0; k < D; k++) a2 = fmaf(st[k], cW2[k * 3 + tid], a2);
    logits[(size_t)g * 3 + tid] = a2;
  }
}

extern "C" void kernel_launch(void* const* d_in, const int* in_sizes, int n_in,
                              void* d_out, int out_size, void* d_ws, size_t ws_size,
                              hipStream_t stream) {
  const float* x     = (const float*)d_in[0];
  const int*   ei    = (const int*)d_in[1];
  const int*   batch = (const int*)d_in[2];
  const float* enc_W = (const float*)d_in[3];
  const float* enc_b = (const float*)d_in[4];
  const float* W1    = (const float*)d_in[5];
  const float* b1    = (const float*)d_in[6];
  const float* g1    = (const float*)d_in[7];
  const float* beta1 = (const float*)d_in[8];
  const float* rm1   = (const float*)d_in[9];
  const float* rv1   = (const float*)d_in[10];
  const float* W2    = (const float*)d_in[11];
  const float* b2    = (const float*)d_in[12];
  const float* g2    = (const float*)d_in[13];
  const float* beta2 = (const float*)d_in[14];
  const float* rm2   = (const float*)d_in[15];
  const float* rv2   = (const float*)d_in[16];
  const float* eps   = (const float*)d_in[17];
  const float* og    = (const float*)d_in[18];
  const float* ob    = (const float*)d_in[19];
  const float* orm   = (const float*)d_in[20];
  const float* orv   = (const float*)d_in[21];
  const float* aW1   = (const float*)d_in[22];
  const float* ab1   = (const float*)d_in[23];
  const float* aW2   = (const float*)d_in[24];
  const float* ab2   = (const float*)d_in[25];
  const float* aW3   = (const float*)d_in[26];
  const float* ab3   = (const float*)d_in[27];
  const float* temp  = (const float*)d_in[28];
  const float* cW1   = (const float*)d_in[29];
  const float* cb1   = (const float*)d_in[30];
  const float* cW2   = (const float*)d_in[31];
  const float* cb2   = (const float*)d_in[32];

  int N = in_sizes[0] / D;
  int E = in_sizes[1] / 2;
  int B = (out_size - N) / (3 + D);

  // workspace: h, m (ping-pong), then CSR ints  (~55 MB total)
  float* hbuf = (float*)d_ws;
  float* mbuf = hbuf + (size_t)N * D;
  int* deg     = (int*)(mbuf + (size_t)N * D);
  int* row_ptr = deg + N;
  int* cursor  = row_ptr + N + 1;
  int* colidx  = cursor + N;

  float* logits = (float*)d_out;
  float* ge     = logits + (size_t)B * 3;
  float* scores = ge + (size_t)B * D;

  // CSR build (recomputed every call; deterministic)
  hipMemsetAsync(deg, 0, (size_t)N * sizeof(int), stream);
  k_count<<<(E + 255) / 256, 256, 0, stream>>>(ei, deg, E);
  int per = (N + 1023) / 1024;
  k_scan<<<1, 1024, 0, stream>>>(deg, row_ptr, cursor, N, per);
  k_fill<<<(E + 255) / 256, 256, 0, stream>>>(ei, cursor, colidx, E);

  int gblocks = (N + 63) / 64;
  // encoder: h = relu(x@enc_W + enc_b)
  k_gemm128<<<gblocks, 256, 0, stream>>>(x, enc_W, enc_b,
      nullptr, nullptr, nullptr, nullptr, nullptr, nullptr, nullptr, nullptr,
      hbuf, N, 0);

  for (int l = 0; l < 3; l++) {
    k_aggregate<<<(N + 7) / 8, 256, 0, stream>>>(hbuf, row_ptr, colidx, eps, l, mbuf, N);
    // m = relu(bn1(m@W1 + b1))   (in-place safe: block reads its rows before writes)
    k_gemm128<<<gblocks, 256, 0, stream>>>(mbuf, W1 + (size_t)l * D * D, b1 + l * D,
        g1 + l * D, beta1 + l * D, rm1 + l * D, rv1 + l * D,
        nullptr, nullptr, nullptr, nullptr, mbuf, N, 1);
    // h = relu(bn_outer(relu(bn2(m@W2 + b2))))
    k_gemm128<<<gblocks, 256, 0, stream>>>(mbuf, W2 + (size_t)l * D * D, b2 + l * D,
        g2 + l * D, beta2 + l * D, rm2 + l * D, rv2 + l * D,
        og + l * D, ob + l * D, orm + l * D, orv + l * D, hbuf, N, 2);
  }

  k_attention<<<(N + 3) / 4, 256, 0, stream>>>(hbuf, aW1, ab1, aW2, ab2, aW3, ab3,
                                               temp, scores, N);
  hipMemsetAsync(ge, 0, (size_t)B * D * sizeof(float), stream);
  k_pool<<<(N + 255) / 256, 128, 0, stream>>>(hbuf, scores, batch, ge, N);
  k_classifier<<<B, 128, 0, stream>>>(ge, cW1, cb1, cW2, cb2, logits, B);
}

// Round 2
// 1033.265 us; speedup vs baseline: 1.0911x; 1.0911x over previous
//
#include <hip/hip_runtime.h>
#include <math.h>

#define D 128

// ---------------- CSR build (by dst) ----------------
__global__ void k_count(const int* __restrict__ ei, int* __restrict__ deg, int E) {
  int e = blockIdx.x * 256 + threadIdx.x;
  if (e < E) atomicAdd(&deg[ei[E + e]], 1);
}

// ---- 3-phase parallel exclusive scan over deg[0..n) ----
// phase 1: per-block (1024 elems) sums
__global__ __launch_bounds__(256) void k_bsum(const int* __restrict__ deg,
                                              int* __restrict__ bsums, int n) {
  int base = blockIdx.x * 1024 + threadIdx.x * 4;
  int s = 0;
  #pragma unroll
  for (int j = 0; j < 4; j++)
    if (base + j < n) s += deg[base + j];
  #pragma unroll
  for (int off = 32; off >= 1; off >>= 1) s += __shfl_down(s, off, 64);
  __shared__ int ws[4];
  int lane = threadIdx.x & 63, wid = threadIdx.x >> 6;
  if (lane == 0) ws[wid] = s;
  __syncthreads();
  if (threadIdx.x == 0) bsums[blockIdx.x] = ws[0] + ws[1] + ws[2] + ws[3];
}

// phase 2: single wave scans the (<=64) block sums -> exclusive offsets
__global__ __launch_bounds__(64) void k_bscan(const int* __restrict__ bsums,
                                              int* __restrict__ boffs, int nb) {
  int lane = threadIdx.x;
  int v = (lane < nb) ? bsums[lane] : 0;
  int incl = v;
  #pragma unroll
  for (int off = 1; off < 64; off <<= 1) {
    int t = __shfl_up(incl, off, 64);
    if (lane >= off) incl += t;
  }
  if (lane < nb) boffs[lane] = incl - v;
}

// phase 3: per-block local scan + global offset -> cursor / row_ptr
__global__ __launch_bounds__(256) void k_bapply(const int* __restrict__ deg,
    const int* __restrict__ boffs, int* __restrict__ row_ptr,
    int* __restrict__ cursor, int n) {
  int tid = threadIdx.x;
  int base = blockIdx.x * 1024 + tid * 4;
  int v[4];
  int s = 0;
  #pragma unroll
  for (int j = 0; j < 4; j++) {
    v[j] = (base + j < n) ? deg[base + j] : 0;
    s += v[j];
  }
  int lane = tid & 63, wid = tid >> 6;
  int incl = s;
  #pragma unroll
  for (int off = 1; off < 64; off <<= 1) {
    int t = __shfl_up(incl, off, 64);
    if (lane >= off) incl += t;
  }
  __shared__ int ws[4];
  if (lane == 63) ws[wid] = incl;
  __syncthreads();
  int woff = 0;
  for (int w = 0; w < wid; w++) woff += ws[w];
  int run = boffs[blockIdx.x] + woff + (incl - s);
  #pragma unroll
  for (int j = 0; j < 4; j++) {
    if (base + j < n) {
      cursor[base + j] = run;
      run += v[j];
      row_ptr[base + j + 1] = run;
    }
  }
  if (blockIdx.x == 0 && tid == 0) row_ptr[0] = 0;
}

__global__ void k_fill(const int* __restrict__ ei, int* __restrict__ cursor,
                       int* __restrict__ col, int E) {
  int e = blockIdx.x * 256 + threadIdx.x;
  if (e < E) {
    int pos = atomicAdd(&cursor[ei[E + e]], 1);
    col[pos] = ei[e];  // store src
  }
}

// ---------------- GIN aggregate: m = (1+eps)*h + sum_{s in N(n)} h[s] ----------------
__global__ __launch_bounds__(256) void k_aggregate(const float* __restrict__ h,
    const int* __restrict__ row_ptr, const int* __restrict__ col,
    const float* __restrict__ eps, int layer, float* __restrict__ m, int n) {
  int node = blockIdx.x * 8 + (threadIdx.x >> 5);
  if (node >= n) return;
  int c = (threadIdx.x & 31) << 2;
  float4 acc = make_float4(0.f, 0.f, 0.f, 0.f);
  int beg = row_ptr[node], end = row_ptr[node + 1];
  for (int i = beg; i < end; i++) {
    int s = col[i];  // broadcast across the 32 lanes of this node
    const float4 v = *(const float4*)(h + (size_t)s * D + c);
    acc.x += v.x; acc.y += v.y; acc.z += v.z; acc.w += v.w;
  }
  float ep = 1.0f + eps[layer];
  const float4 hv = *(const float4*)(h + (size_t)node * D + c);
  acc.x = fmaf(ep, hv.x, acc.x);
  acc.y = fmaf(ep, hv.y, acc.y);
  acc.z = fmaf(ep, hv.z, acc.z);
  acc.w = fmaf(ep, hv.w, acc.w);
  *(float4*)(m + (size_t)node * D + c) = acc;
}

// ---------------- GEMM [N,128]@[128,128] with fused affine/ReLU epilogue ----------------
// stages: 0 = +bias,ReLU ; 1 = +bias,BN,ReLU ; 2 = +bias,BN,ReLU,BN,ReLU
__global__ __launch_bounds__(256) void k_gemm128(
    const float* __restrict__ in, const float* __restrict__ W,
    const float* __restrict__ bias,
    const float* __restrict__ g1v, const float* __restrict__ be1,
    const float* __restrict__ rm1, const float* __restrict__ rv1,
    const float* __restrict__ g2v, const float* __restrict__ be2,
    const float* __restrict__ rm2, const float* __restrict__ rv2,
    float* __restrict__ out, int N, int stages) {
  __shared__ float sIn[64][D];  // 32KB input tile (row-major)
  __shared__ float sW[64][D];   // 32KB: one k-half of W at a time  -> 64KB total
  int tid = threadIdx.x;
  int row0 = blockIdx.x * 64;
  int nrows = min(64, N - row0);

  // stage input tile (zero-pad tail rows)
  for (int i = tid; i < 64 * 32; i += 256) {
    int r = i >> 5, k4 = (i & 31) << 2;
    float4 v = make_float4(0.f, 0.f, 0.f, 0.f);
    if (r < nrows) v = *(const float4*)(in + (size_t)(row0 + r) * D + k4);
    *(float4*)&sIn[r][k4] = v;
  }

  int tx = tid & 31, ty = tid >> 5;
  int c0 = tx << 2, r0 = ty << 3;
  float acc[8][4];
  #pragma unroll
  for (int i = 0; i < 8; i++)
    #pragma unroll
    for (int j = 0; j < 4; j++) acc[i][j] = 0.f;

  for (int half = 0; half < 2; half++) {
    __syncthreads();  // protects sIn staging (1st iter) and sW reuse (2nd iter)
    const float* Wh = W + half * 64 * D;
    for (int i = tid * 4; i < 64 * D; i += 1024)
      *(float4*)(&sW[0][0] + i) = *(const float4*)(Wh + i);
    __syncthreads();
    int kbase = half * 64;
    #pragma unroll 4
    for (int kk = 0; kk < 64; kk += 4) {
      float4 b0 = *(float4*)&sW[kk + 0][c0];
      float4 b1 = *(float4*)&sW[kk + 1][c0];
      float4 b2 = *(float4*)&sW[kk + 2][c0];
      float4 b3 = *(float4*)&sW[kk + 3][c0];
      #pragma unroll
      for (int i = 0; i < 8; i++) {
        float4 a = *(float4*)&sIn[r0 + i][kbase + kk];  // broadcast read
        acc[i][0] += a.x * b0.x + a.y * b1.x + a.z * b2.x + a.w * b3.x;
        acc[i][1] += a.x * b0.y + a.y * b1.y + a.z * b2.y + a.w * b3.y;
        acc[i][2] += a.x * b0.z + a.y * b1.z + a.z * b2.z + a.w * b3.z;
        acc[i][3] += a.x * b0.w + a.y * b1.w + a.z * b2.w + a.w * b3.w;
      }
    }
  }

  // fused epilogue: y -> y*s1+t1, relu, [y*s2+t2, relu]
  float s1[4], t1[4], s2[4], t2[4];
  #pragma unroll
  for (int j = 0; j < 4; j++) {
    int cj = c0 + j;
    float sv = 1.0f, tv = bias ? bias[cj] : 0.0f;
    if (stages >= 1) {
      float inv = rsqrtf(rv1[cj] + 1e-5f);
      float sg = g1v[cj] * inv;
      tv = (tv - rm1[cj]) * sg + be1[cj];
      sv = sg;
    }
    s1[j] = sv; t1[j] = tv;
    if (stages >= 2) {
      float inv = rsqrtf(rv2[cj] + 1e-5f);
      float sg = g2v[cj] * inv;
      s2[j] = sg; t2[j] = be2[cj] - rm2[cj] * sg;
    } else { s2[j] = 1.f; t2[j] = 0.f; }
  }
  #pragma unroll
  for (int i = 0; i < 8; i++) {
    int r = r0 + i;
    if (r < nrows) {
      float4 o;
      float* v = &o.x;
      #pragma unroll
      for (int j = 0; j < 4; j++) {
        float y = acc[i][j] * s1[j] + t1[j];
        y = fmaxf(y, 0.f);
        if (stages >= 2) { y = y * s2[j] + t2[j]; y = fmaxf(y, 0.f); }
        v[j] = y;
      }
      *(float4*)(out + (size_t)(row0 + r) * D + c0) = o;
    }
  }
}

// ---------------- attention MLP: wave per node ----------------
__global__ __launch_bounds__(256) void k_attention(const float* __restrict__ h,
    const float* __restrict__ aW1, const float* __restrict__ ab1,
    const float* __restrict__ aW2, const float* __restrict__ ab2,
    const float* __restrict__ aW3, const float* __restrict__ ab3,
    const float* __restrict__ temp, float* __restrict__ scores, int n) {
  __shared__ float sh[4][D];
  __shared__ float sa1[4][64];
  __shared__ float sa2[4][32];
  int wid = threadIdx.x >> 6, lane = threadIdx.x & 63;
  int node = blockIdx.x * 4 + wid;
  int nodec = min(node, n - 1);
  const float* hr = h + (size_t)nodec * D;
  float2 v = *(const float2*)(hr + lane * 2);
  sh[wid][lane * 2] = v.x;
  sh[wid][lane * 2 + 1] = v.y;
  __syncthreads();
  float a = ab1[lane];
  #pragma unroll 8
  for (int k = 0; k < D; k++) a = fmaf(sh[wid][k], aW1[k * 64 + lane], a);
  a = fmaxf(a, 0.2f * a);  // leaky_relu(x,0.2) == max(x, 0.2x)
  sa1[wid][lane] = a;
  __syncthreads();
  if (lane < 32) {
    float a2 = ab2[lane];
    #pragma unroll 8
    for (int k = 0; k < 64; k++) a2 = fmaf(sa1[wid][k], aW2[k * 32 + lane], a2);
    a2 = fmaxf(a2, 0.2f * a2);
    sa2[wid][lane] = a2;
  }
  __syncthreads();
  if (lane == 0 && node < n) {
    float l3 = ab3[0];
    #pragma unroll 8
    for (int k = 0; k < 32; k++) l3 = fmaf(sa2[wid][k], aW3[k], l3);
    l3 = fminf(fmaxf(l3, -10.f), 10.f);
    scores[node] = 1.0f / (1.0f + __expf(-l3 * temp[0]));
  }
}

// ---------------- attention-weighted pool (batch sorted) ----------------
__global__ __launch_bounds__(128) void k_pool(const float* __restrict__ h,
    const float* __restrict__ scores, const int* __restrict__ batch,
    float* __restrict__ ge, int n) {
  const int NPB = 256;
  int f = threadIdx.x;
  int n0 = blockIdx.x * NPB;
  if (n0 >= n) return;
  int nend = min(n0 + NPB, n);
  float acc = 0.f;
  int cur = batch[n0];  // uniform across threads (broadcast)
  for (int i = n0; i < nend; i++) {
    int b = batch[i];
    if (b != cur) {
      atomicAdd(&ge[(size_t)cur * D + f], acc);
      acc = 0.f;
      cur = b;
    }
    acc = fmaf(h[(size_t)i * D + f], scores[i], acc);
  }
  atomicAdd(&ge[(size_t)cur * D + f], acc);
}

// ---------------- classifier: block per graph ----------------
__global__ __launch_bounds__(128) void k_classifier(const float* __restrict__ ge,
    const float* __restrict__ cW1, const float* __restrict__ cb1,
    const float* __restrict__ cW2, const float* __restrict__ cb2,
    float* __restrict__ logits, int B) {
  __shared__ float sg[D];
  __shared__ float st[D];
  int g = blockIdx.x;
  int tid = threadIdx.x;
  sg[tid] = ge[(size_t)g * D + tid];
  __syncthreads();
  float a = cb1[tid];
  #pragma unroll 8
  for (int k = 0; k < D; k++) a = fmaf(sg[k], cW1[k * D + tid], a);
  st[tid] = fmaxf(a, 0.f);
  __syncthreads();
  if (tid < 3) {
    float a2 = cb2[tid];
    for (int k = 0; k < D; k++) a2 = fmaf(st[k], cW2[k * 3 + tid], a2);
    logits[(size_t)g * 3 + tid] = a2;
  }
}

extern "C" void kernel_launch(void* const* d_in, const int* in_sizes, int n_in,
                              void* d_out, int out_size, void* d_ws, size_t ws_size,
                              hipStream_t stream) {
  const float* x     = (const float*)d_in[0];
  const int*   ei    = (const int*)d_in[1];
  const int*   batch = (const int*)d_in[2];
  const float* enc_W = (const float*)d_in[3];
  const float* enc_b = (const float*)d_in[4];
  const float* W1    = (const float*)d_in[5];
  const float* b1    = (const float*)d_in[6];
  const float* g1    = (const float*)d_in[7];
  const float* beta1 = (const float*)d_in[8];
  const float* rm1   = (const float*)d_in[9];
  const float* rv1   = (const float*)d_in[10];
  const float* W2    = (const float*)d_in[11];
  const float* b2    = (const float*)d_in[12];
  const float* g2    = (const float*)d_in[13];
  const float* beta2 = (const float*)d_in[14];
  const float* rm2   = (const float*)d_in[15];
  const float* rv2   = (const float*)d_in[16];
  const float* eps   = (const float*)d_in[17];
  const float* og    = (const float*)d_in[18];
  const float* ob    = (const float*)d_in[19];
  const float* orm   = (const float*)d_in[20];
  const float* orv   = (const float*)d_in[21];
  const float* aW1   = (const float*)d_in[22];
  const float* ab1   = (const float*)d_in[23];
  const float* aW2   = (const float*)d_in[24];
  const float* ab2   = (const float*)d_in[25];
  const float* aW3   = (const float*)d_in[26];
  const float* ab3   = (const float*)d_in[27];
  const float* temp  = (const float*)d_in[28];
  const float* cW1   = (const float*)d_in[29];
  const float* cb1   = (const float*)d_in[30];
  const float* cW2   = (const float*)d_in[31];
  const float* cb2   = (const float*)d_in[32];

  int N = in_sizes[0] / D;
  int E = in_sizes[1] / 2;
  int B = (out_size - N) / (3 + D);

  // workspace: h, m (ping-pong), then CSR ints  (~55 MB total)
  float* hbuf = (float*)d_ws;
  float* mbuf = hbuf + (size_t)N * D;
  int* deg     = (int*)(mbuf + (size_t)N * D);
  int* row_ptr = deg + N;
  int* cursor  = row_ptr + N + 1;
  int* colidx  = cursor + N;
  int* bsums   = colidx + E;   // scan temporaries (<=64 each)
  int* boffs   = bsums + 64;

  float* logits = (float*)d_out;
  float* ge     = logits + (size_t)B * 3;
  float* scores = ge + (size_t)B * D;

  // CSR build (recomputed every call; deterministic)
  hipMemsetAsync(deg, 0, (size_t)N * sizeof(int), stream);
  k_count<<<(E + 255) / 256, 256, 0, stream>>>(ei, deg, E);
  int nb = (N + 1023) / 1024;  // <= 64 for N <= 65536
  k_bsum<<<nb, 256, 0, stream>>>(deg, bsums, N);
  k_bscan<<<1, 64, 0, stream>>>(bsums, boffs, nb);
  k_bapply<<<nb, 256, 0, stream>>>(deg, boffs, row_ptr, cursor, N);
  k_fill<<<(E + 255) / 256, 256, 0, stream>>>(ei, cursor, colidx, E);

  int gblocks = (N + 63) / 64;
  // encoder: h = relu(x@enc_W + enc_b)
  k_gemm128<<<gblocks, 256, 0, stream>>>(x, enc_W, enc_b,
      nullptr, nullptr, nullptr, nullptr, nullptr, nullptr, nullptr, nullptr,
      hbuf, N, 0);

  for (int l = 0; l < 3; l++) {
    k_aggregate<<<(N + 7) / 8, 256, 0, stream>>>(hbuf, row_ptr, colidx, eps, l, mbuf, N);
    // m = relu(bn1(m@W1 + b1))   (in-place safe: block reads its rows before writes)
    k_gemm128<<<gblocks, 256, 0, stream>>>(mbuf, W1 + (size_t)l * D * D, b1 + l * D,
        g1 + l * D, beta1 + l * D, rm1 + l * D, rv1 + l * D,
        nullptr, nullptr, nullptr, nullptr, mbuf, N, 1);
    // h = relu(bn_outer(relu(bn2(m@W2 + b2))))
    k_gemm128<<<gblocks, 256, 0, stream>>>(mbuf, W2 + (size_t)l * D * D, b2 + l * D,
        g2 + l * D, beta2 + l * D, rm2 + l * D, rv2 + l * D,
        og + l * D, ob + l * D, orm + l * D, orv + l * D, hbuf, N, 2);
  }

  k_attention<<<(N + 3) / 4, 256, 0, stream>>>(hbuf, aW1, ab1, aW2, ab2, aW3, ab3,
                                               temp, scores, N);
  hipMemsetAsync(ge, 0, (size_t)B * D * sizeof(float), stream);
  k_pool<<<(N + 255) / 256, 128, 0, stream>>>(hbuf, scores, batch, ge, N);
  k_classifier<<<B, 128, 0, stream>>>(ge, cW1, cb1, cW2, cb2, logits, B);
}

// Round 3
// 991.839 us; speedup vs baseline: 1.1367x; 1.0418x over previous
//
#include <hip/hip_runtime.h>
#include <math.h>

#define D 128

// ---------------- CSR build (by dst) ----------------
__global__ void k_count(const int* __restrict__ ei, int* __restrict__ deg, int E) {
  int e = blockIdx.x * 256 + threadIdx.x;
  if (e < E) atomicAdd(&deg[ei[E + e]], 1);
}

// ---- 3-phase parallel exclusive scan over deg[0..n) ----
__global__ __launch_bounds__(256) void k_bsum(const int* __restrict__ deg,
                                              int* __restrict__ bsums, int n) {
  int base = blockIdx.x * 1024 + threadIdx.x * 4;
  int s = 0;
  #pragma unroll
  for (int j = 0; j < 4; j++)
    if (base + j < n) s += deg[base + j];
  #pragma unroll
  for (int off = 32; off >= 1; off >>= 1) s += __shfl_down(s, off, 64);
  __shared__ int ws[4];
  int lane = threadIdx.x & 63, wid = threadIdx.x >> 6;
  if (lane == 0) ws[wid] = s;
  __syncthreads();
  if (threadIdx.x == 0) bsums[blockIdx.x] = ws[0] + ws[1] + ws[2] + ws[3];
}

__global__ __launch_bounds__(64) void k_bscan(const int* __restrict__ bsums,
                                              int* __restrict__ boffs, int nb) {
  int lane = threadIdx.x;
  int v = (lane < nb) ? bsums[lane] : 0;
  int incl = v;
  #pragma unroll
  for (int off = 1; off < 64; off <<= 1) {
    int t = __shfl_up(incl, off, 64);
    if (lane >= off) incl += t;
  }
  if (lane < nb) boffs[lane] = incl - v;
}

__global__ __launch_bounds__(256) void k_bapply(const int* __restrict__ deg,
    const int* __restrict__ boffs, int* __restrict__ row_ptr,
    int* __restrict__ cursor, int n) {
  int tid = threadIdx.x;
  int base = blockIdx.x * 1024 + tid * 4;
  int v[4];
  int s = 0;
  #pragma unroll
  for (int j = 0; j < 4; j++) {
    v[j] = (base + j < n) ? deg[base + j] : 0;
    s += v[j];
  }
  int lane = tid & 63, wid = tid >> 6;
  int incl = s;
  #pragma unroll
  for (int off = 1; off < 64; off <<= 1) {
    int t = __shfl_up(incl, off, 64);
    if (lane >= off) incl += t;
  }
  __shared__ int ws[4];
  if (lane == 63) ws[wid] = incl;
  __syncthreads();
  int woff = 0;
  for (int w = 0; w < wid; w++) woff += ws[w];
  int run = boffs[blockIdx.x] + woff + (incl - s);
  #pragma unroll
  for (int j = 0; j < 4; j++) {
    if (base + j < n) {
      cursor[base + j] = run;
      run += v[j];
      row_ptr[base + j + 1] = run;
    }
  }
  if (blockIdx.x == 0 && tid == 0) row_ptr[0] = 0;
}

__global__ void k_fill(const int* __restrict__ ei, int* __restrict__ cursor,
                       int* __restrict__ col, int E) {
  int e = blockIdx.x * 256 + threadIdx.x;
  if (e < E) {
    int pos = atomicAdd(&cursor[ei[E + e]], 1);
    col[pos] = ei[e];  // store src
  }
}

// ---------------- GIN aggregate: m = (1+eps)*h + sum_{s in N(n)} h[s] ----------------
__global__ __launch_bounds__(256) void k_aggregate(const float* __restrict__ h,
    const int* __restrict__ row_ptr, const int* __restrict__ col,
    const float* __restrict__ eps, int layer, float* __restrict__ m, int n) {
  int node = blockIdx.x * 8 + (threadIdx.x >> 5);
  if (node >= n) return;
  int c = (threadIdx.x & 31) << 2;
  float4 acc = make_float4(0.f, 0.f, 0.f, 0.f);
  int beg = row_ptr[node], end = row_ptr[node + 1];
  for (int i = beg; i < end; i++) {
    int s = col[i];  // broadcast across the 32 lanes of this node
    const float4 v = *(const float4*)(h + (size_t)s * D + c);
    acc.x += v.x; acc.y += v.y; acc.z += v.z; acc.w += v.w;
  }
  float ep = 1.0f + eps[layer];
  const float4 hv = *(const float4*)(h + (size_t)node * D + c);
  acc.x = fmaf(ep, hv.x, acc.x);
  acc.y = fmaf(ep, hv.y, acc.y);
  acc.z = fmaf(ep, hv.z, acc.z);
  acc.w = fmaf(ep, hv.w, acc.w);
  *(float4*)(m + (size_t)node * D + c) = acc;
}

// ---------------- GEMM [N,128]@[128,128] with fused affine/ReLU epilogue ----------------
// stages: 0 = +bias,ReLU ; 1 = +bias,BN,ReLU ; 2 = +bias,BN,ReLU,BN,ReLU
__global__ __launch_bounds__(256) void k_gemm128(
    const float* __restrict__ in, const float* __restrict__ W,
    const float* __restrict__ bias,
    const float* __restrict__ g1v, const float* __restrict__ be1,
    const float* __restrict__ rm1, const float* __restrict__ rv1,
    const float* __restrict__ g2v, const float* __restrict__ be2,
    const float* __restrict__ rm2, const float* __restrict__ rv2,
    float* __restrict__ out, int N, int stages) {
  __shared__ float sIn[64][D];  // 32KB input tile (row-major)
  __shared__ float sW[64][D];   // 32KB: one k-half of W at a time  -> 64KB total
  int tid = threadIdx.x;
  int row0 = blockIdx.x * 64;
  int nrows = min(64, N - row0);

  // stage input tile (zero-pad tail rows)
  for (int i = tid; i < 64 * 32; i += 256) {
    int r = i >> 5, k4 = (i & 31) << 2;
    float4 v = make_float4(0.f, 0.f, 0.f, 0.f);
    if (r < nrows) v = *(const float4*)(in + (size_t)(row0 + r) * D + k4);
    *(float4*)&sIn[r][k4] = v;
  }

  int tx = tid & 31, ty = tid >> 5;
  int c0 = tx << 2, r0 = ty << 3;
  float acc[8][4];
  #pragma unroll
  for (int i = 0; i < 8; i++)
    #pragma unroll
    for (int j = 0; j < 4; j++) acc[i][j] = 0.f;

  for (int half = 0; half < 2; half++) {
    __syncthreads();  // protects sIn staging (1st iter) and sW reuse (2nd iter)
    const float* Wh = W + half * 64 * D;
    for (int i = tid * 4; i < 64 * D; i += 1024)
      *(float4*)(&sW[0][0] + i) = *(const float4*)(Wh + i);
    __syncthreads();
    int kbase = half * 64;
    #pragma unroll 4
    for (int kk = 0; kk < 64; kk += 4) {
      float4 b0 = *(float4*)&sW[kk + 0][c0];
      float4 b1 = *(float4*)&sW[kk + 1][c0];
      float4 b2 = *(float4*)&sW[kk + 2][c0];
      float4 b3 = *(float4*)&sW[kk + 3][c0];
      #pragma unroll
      for (int i = 0; i < 8; i++) {
        float4 a = *(float4*)&sIn[r0 + i][kbase + kk];  // broadcast read
        acc[i][0] += a.x * b0.x + a.y * b1.x + a.z * b2.x + a.w * b3.x;
        acc[i][1] += a.x * b0.y + a.y * b1.y + a.z * b2.y + a.w * b3.y;
        acc[i][2] += a.x * b0.z + a.y * b1.z + a.z * b2.z + a.w * b3.z;
        acc[i][3] += a.x * b0.w + a.y * b1.w + a.z * b2.w + a.w * b3.w;
      }
    }
  }

  // fused epilogue: y -> y*s1+t1, relu, [y*s2+t2, relu]
  float s1[4], t1[4], s2[4], t2[4];
  #pragma unroll
  for (int j = 0; j < 4; j++) {
    int cj = c0 + j;
    float sv = 1.0f, tv = bias ? bias[cj] : 0.0f;
    if (stages >= 1) {
      float inv = rsqrtf(rv1[cj] + 1e-5f);
      float sg = g1v[cj] * inv;
      tv = (tv - rm1[cj]) * sg + be1[cj];
      sv = sg;
    }
    s1[j] = sv; t1[j] = tv;
    if (stages >= 2) {
      float inv = rsqrtf(rv2[cj] + 1e-5f);
      float sg = g2v[cj] * inv;
      s2[j] = sg; t2[j] = be2[cj] - rm2[cj] * sg;
    } else { s2[j] = 1.f; t2[j] = 0.f; }
  }
  #pragma unroll
  for (int i = 0; i < 8; i++) {
    int r = r0 + i;
    if (r < nrows) {
      float4 o;
      float* v = &o.x;
      #pragma unroll
      for (int j = 0; j < 4; j++) {
        float y = acc[i][j] * s1[j] + t1[j];
        y = fmaxf(y, 0.f);
        if (stages >= 2) { y = y * s2[j] + t2[j]; y = fmaxf(y, 0.f); }
        v[j] = y;
      }
      *(float4*)(out + (size_t)(row0 + r) * D + c0) = o;
    }
  }
}

// ---------------- attention MLP: fused LDS-tiled 3-stage GEMM ----------------
// block = 256 threads = 64 nodes. LDS reused across phases (64KB static).
__global__ __launch_bounds__(256) void k_attention(const float* __restrict__ h,
    const float* __restrict__ aW1, const float* __restrict__ ab1,
    const float* __restrict__ aW2, const float* __restrict__ ab2,
    const float* __restrict__ aW3, const float* __restrict__ ab3,
    const float* __restrict__ temp, float* __restrict__ scores, int n) {
  __shared__ float smem[16384];              // 64KB
  float* sH  = smem;                         // [64][128]
  float* sW1 = smem + 8192;                  // [128][64]
  int tid = threadIdx.x;
  int node0 = blockIdx.x * 64;

  // stage h tile (clamped) + aW1
  for (int i4 = tid; i4 < 2048; i4 += 256) {
    int r = i4 >> 5, c4 = (i4 & 31) << 2;
    int nd = min(node0 + r, n - 1);
    *(float4*)&sH[r * 128 + c4] = *(const float4*)(h + (size_t)nd * D + c4);
  }
  for (int i4 = tid; i4 < 2048; i4 += 256)
    *(float4*)&sW1[i4 * 4] = *(const float4*)(aW1 + i4 * 4);
  __syncthreads();

  // phase 1: a1[64][64] = leaky(sH @ aW1 + ab1); thread = 8 nodes x 2 cols
  int tx = tid & 31, ty = tid >> 5;          // within wave: only 2 ty groups -> 2-way LDS max
  int c0 = tx * 2, r0 = ty * 8;
  float acc[8][2];
  #pragma unroll
  for (int i = 0; i < 8; i++) { acc[i][0] = 0.f; acc[i][1] = 0.f; }
  #pragma unroll 4
  for (int kk = 0; kk < 128; kk += 4) {
    float2 b0 = *(float2*)&sW1[(kk + 0) * 64 + c0];
    float2 b1 = *(float2*)&sW1[(kk + 1) * 64 + c0];
    float2 b2 = *(float2*)&sW1[(kk + 2) * 64 + c0];
    float2 b3 = *(float2*)&sW1[(kk + 3) * 64 + c0];
    #pragma unroll
    for (int i = 0; i < 8; i++) {
      float4 a = *(float4*)&sH[(r0 + i) * 128 + kk];
      acc[i][0] += a.x * b0.x + a.y * b1.x + a.z * b2.x + a.w * b3.x;
      acc[i][1] += a.x * b0.y + a.y * b1.y + a.z * b2.y + a.w * b3.y;
    }
  }
  float bb0 = ab1[c0], bb1 = ab1[c0 + 1];    // L2-cached broadcast
  __syncthreads();                            // phase-1 reads done; LDS reuse below

  float* a1B = smem;                          // [64][68] (pad: 2-row step = 8 banks)
  float* sW2 = smem + 8192;                   // [64][32]
  float* a2B = smem + 8192 + 2048;            // [64][36]
  #pragma unroll
  for (int i = 0; i < 8; i++) {
    float v0 = acc[i][0] + bb0; v0 = fmaxf(v0, 0.2f * v0);
    float v1 = acc[i][1] + bb1; v1 = fmaxf(v1, 0.2f * v1);
    *(float2*)&a1B[(r0 + i) * 68 + c0] = make_float2(v0, v1);
  }
  for (int i4 = tid; i4 < 512; i4 += 256)
    *(float4*)&sW2[i4 * 4] = *(const float4*)(aW2 + i4 * 4);
  __syncthreads();

  // phase 2: a2[64][32] = leaky(a1 @ aW2 + ab2); thread = 2 nodes x 4 cols
  int tx2 = tid & 7, ty2 = tid >> 3;
  int cc0 = tx2 * 4, rr0 = ty2 * 2;
  float acc2[2][4];
  #pragma unroll
  for (int i = 0; i < 2; i++)
    #pragma unroll
    for (int j = 0; j < 4; j++) acc2[i][j] = 0.f;
  #pragma unroll 4
  for (int k = 0; k < 64; k += 4) {
    float4 b0 = *(float4*)&sW2[(k + 0) * 32 + cc0];
    float4 b1 = *(float4*)&sW2[(k + 1) * 32 + cc0];
    float4 b2 = *(float4*)&sW2[(k + 2) * 32 + cc0];
    float4 b3 = *(float4*)&sW2[(k + 3) * 32 + cc0];
    #pragma unroll
    for (int i = 0; i < 2; i++) {
      float4 a = *(float4*)&a1B[(rr0 + i) * 68 + k];
      acc2[i][0] += a.x * b0.x + a.y * b1.x + a.z * b2.x + a.w * b3.x;
      acc2[i][1] += a.x * b0.y + a.y * b1.y + a.z * b2.y + a.w * b3.y;
      acc2[i][2] += a.x * b0.z + a.y * b1.z + a.z * b2.z + a.w * b3.z;
      acc2[i][3] += a.x * b0.w + a.y * b1.w + a.z * b2.w + a.w * b3.w;
    }
  }
  float4 bias2 = *(const float4*)(ab2 + cc0);
  #pragma unroll
  for (int i = 0; i < 2; i++) {
    float4 o;
    o.x = acc2[i][0] + bias2.x; o.x = fmaxf(o.x, 0.2f * o.x);
    o.y = acc2[i][1] + bias2.y; o.y = fmaxf(o.y, 0.2f * o.y);
    o.z = acc2[i][2] + bias2.z; o.z = fmaxf(o.z, 0.2f * o.z);
    o.w = acc2[i][3] + bias2.w; o.w = fmaxf(o.w, 0.2f * o.w);
    *(float4*)&a2B[(rr0 + i) * 36 + cc0] = o;   // disjoint region: no extra sync needed
  }
  __syncthreads();

  // phase 3: scores = sigmoid(clip(a2 @ aW3 + ab3) * temp); one lane per node
  if (tid < 64) {
    float s = ab3[0];
    #pragma unroll 8
    for (int k = 0; k < 32; k++) s = fmaf(a2B[tid * 36 + k], aW3[k], s);
    s = fminf(fmaxf(s, -10.f), 10.f);
    int node = node0 + tid;
    if (node < n) scores[node] = 1.0f / (1.0f + __expf(-s * temp[0]));
  }
}

// ---------------- attention-weighted pool (batch sorted) ----------------
__global__ __launch_bounds__(128) void k_pool(const float* __restrict__ h,
    const float* __restrict__ scores, const int* __restrict__ batch,
    float* __restrict__ ge, int n) {
  const int NPB = 256;
  int f = threadIdx.x;
  int n0 = blockIdx.x * NPB;
  if (n0 >= n) return;
  int nend = min(n0 + NPB, n);
  float acc = 0.f;
  int cur = batch[n0];  // uniform across threads (broadcast)
  for (int i = n0; i < nend; i++) {
    int b = batch[i];
    if (b != cur) {
      atomicAdd(&ge[(size_t)cur * D + f], acc);
      acc = 0.f;
      cur = b;
    }
    acc = fmaf(h[(size_t)i * D + f], scores[i], acc);
  }
  atomicAdd(&ge[(size_t)cur * D + f], acc);
}

// ---------------- classifier: block per graph ----------------
__global__ __launch_bounds__(128) void k_classifier(const float* __restrict__ ge,
    const float* __restrict__ cW1, const float* __restrict__ cb1,
    const float* __restrict__ cW2, const float* __restrict__ cb2,
    float* __restrict__ logits, int B) {
  __shared__ float sg[D];
  __shared__ float st[D];
  int g = blockIdx.x;
  int tid = threadIdx.x;
  sg[tid] = ge[(size_t)g * D + tid];
  __syncthreads();
  float a = cb1[tid];
  #pragma unroll 8
  for (int k = 0; k < D; k++) a = fmaf(sg[k], cW1[k * D + tid], a);
  st[tid] = fmaxf(a, 0.f);
  __syncthreads();
  if (tid < 3) {
    float a2 = cb2[tid];
    for (int k = 0; k < D; k++) a2 = fmaf(st[k], cW2[k * 3 + tid], a2);
    logits[(size_t)g * 3 + tid] = a2;
  }
}

extern "C" void kernel_launch(void* const* d_in, const int* in_sizes, int n_in,
                              void* d_out, int out_size, void* d_ws, size_t ws_size,
                              hipStream_t stream) {
  const float* x     = (const float*)d_in[0];
  const int*   ei    = (const int*)d_in[1];
  const int*   batch = (const int*)d_in[2];
  const float* enc_W = (const float*)d_in[3];
  const float* enc_b = (const float*)d_in[4];
  const float* W1    = (const float*)d_in[5];
  const float* b1    = (const float*)d_in[6];
  const float* g1    = (const float*)d_in[7];
  const float* beta1 = (const float*)d_in[8];
  const float* rm1   = (const float*)d_in[9];
  const float* rv1   = (const float*)d_in[10];
  const float* W2    = (const float*)d_in[11];
  const float* b2    = (const float*)d_in[12];
  const float* g2    = (const float*)d_in[13];
  const float* beta2 = (const float*)d_in[14];
  const float* rm2   = (const float*)d_in[15];
  const float* rv2   = (const float*)d_in[16];
  const float* eps   = (const float*)d_in[17];
  const float* og    = (const float*)d_in[18];
  const float* ob    = (const float*)d_in[19];
  const float* orm   = (const float*)d_in[20];
  const float* orv   = (const float*)d_in[21];
  const float* aW1   = (const float*)d_in[22];
  const float* ab1   = (const float*)d_in[23];
  const float* aW2   = (const float*)d_in[24];
  const float* ab2   = (const float*)d_in[25];
  const float* aW3   = (const float*)d_in[26];
  const float* ab3   = (const float*)d_in[27];
  const float* temp  = (const float*)d_in[28];
  const float* cW1   = (const float*)d_in[29];
  const float* cb1   = (const float*)d_in[30];
  const float* cW2   = (const float*)d_in[31];
  const float* cb2   = (const float*)d_in[32];

  int N = in_sizes[0] / D;
  int E = in_sizes[1] / 2;
  int B = (out_size - N) / (3 + D);

  // workspace: h, m (ping-pong), then CSR ints  (~55 MB total)
  float* hbuf = (float*)d_ws;
  float* mbuf = hbuf + (size_t)N * D;
  int* deg     = (int*)(mbuf + (size_t)N * D);
  int* row_ptr = deg + N;
  int* cursor  = row_ptr + N + 1;
  int* colidx  = cursor + N;
  int* bsums   = colidx + E;   // scan temporaries (<=64 each)
  int* boffs   = bsums + 64;

  float* logits = (float*)d_out;
  float* ge     = logits + (size_t)B * 3;
  float* scores = ge + (size_t)B * D;

  // CSR build (recomputed every call; deterministic)
  hipMemsetAsync(deg, 0, (size_t)N * sizeof(int), stream);
  k_count<<<(E + 255) / 256, 256, 0, stream>>>(ei, deg, E);
  int nb = (N + 1023) / 1024;  // <= 64 for N <= 65536
  k_bsum<<<nb, 256, 0, stream>>>(deg, bsums, N);
  k_bscan<<<1, 64, 0, stream>>>(bsums, boffs, nb);
  k_bapply<<<nb, 256, 0, stream>>>(deg, boffs, row_ptr, cursor, N);
  k_fill<<<(E + 255) / 256, 256, 0, stream>>>(ei, cursor, colidx, E);

  int gblocks = (N + 63) / 64;
  // encoder: h = relu(x@enc_W + enc_b)
  k_gemm128<<<gblocks, 256, 0, stream>>>(x, enc_W, enc_b,
      nullptr, nullptr, nullptr, nullptr, nullptr, nullptr, nullptr, nullptr,
      hbuf, N, 0);

  for (int l = 0; l < 3; l++) {
    k_aggregate<<<(N + 7) / 8, 256, 0, stream>>>(hbuf, row_ptr, colidx, eps, l, mbuf, N);
    // m = relu(bn1(m@W1 + b1))   (in-place safe: block reads its rows before writes)
    k_gemm128<<<gblocks, 256, 0, stream>>>(mbuf, W1 + (size_t)l * D * D, b1 + l * D,
        g1 + l * D, beta1 + l * D, rm1 + l * D, rv1 + l * D,
        nullptr, nullptr, nullptr, nullptr, mbuf, N, 1);
    // h = relu(bn_outer(relu(bn2(m@W2 + b2))))
    k_gemm128<<<gblocks, 256, 0, stream>>>(mbuf, W2 + (size_t)l * D * D, b2 + l * D,
        g2 + l * D, beta2 + l * D, rm2 + l * D, rv2 + l * D,
        og + l * D, ob + l * D, orm + l * D, orv + l * D, hbuf, N, 2);
  }

  k_attention<<<gblocks, 256, 0, stream>>>(hbuf, aW1, ab1, aW2, ab2, aW3, ab3,
                                           temp, scores, N);
  hipMemsetAsync(ge, 0, (size_t)B * D * sizeof(float), stream);
  k_pool<<<(N + 255) / 256, 128, 0, stream>>>(hbuf, scores, batch, ge, N);
  k_classifier<<<B, 128, 0, stream>>>(ge, cW1, cb1, cW2, cb2, logits, B);
}

// Round 4
// 659.699 us; speedup vs baseline: 1.7090x; 1.5035x over previous
//
#include <hip/hip_runtime.h>
#include <math.h>

#define D 128

typedef short bf16x8 __attribute__((ext_vector_type(8)));
typedef float f32x4 __attribute__((ext_vector_type(4)));

__device__ inline short f2bf(float f) {  // RNE fp32->bf16
  unsigned u = __float_as_uint(f);
  unsigned r = (u + 0x7fffu + ((u >> 16) & 1u)) >> 16;
  return (short)r;
}

// ---------------- CSR build (by dst) ----------------
__global__ void k_count(const int* __restrict__ ei, int* __restrict__ deg, int E) {
  int e = blockIdx.x * 256 + threadIdx.x;
  if (e < E) atomicAdd(&deg[ei[E + e]], 1);
}

__global__ __launch_bounds__(256) void k_bsum(const int* __restrict__ deg,
                                              int* __restrict__ bsums, int n) {
  int base = blockIdx.x * 1024 + threadIdx.x * 4;
  int s = 0;
  #pragma unroll
  for (int j = 0; j < 4; j++)
    if (base + j < n) s += deg[base + j];
  #pragma unroll
  for (int off = 32; off >= 1; off >>= 1) s += __shfl_down(s, off, 64);
  __shared__ int ws[4];
  int lane = threadIdx.x & 63, wid = threadIdx.x >> 6;
  if (lane == 0) ws[wid] = s;
  __syncthreads();
  if (threadIdx.x == 0) bsums[blockIdx.x] = ws[0] + ws[1] + ws[2] + ws[3];
}

__global__ __launch_bounds__(64) void k_bscan(const int* __restrict__ bsums,
                                              int* __restrict__ boffs, int nb) {
  int lane = threadIdx.x;
  int v = (lane < nb) ? bsums[lane] : 0;
  int incl = v;
  #pragma unroll
  for (int off = 1; off < 64; off <<= 1) {
    int t = __shfl_up(incl, off, 64);
    if (lane >= off) incl += t;
  }
  if (lane < nb) boffs[lane] = incl - v;
}

__global__ __launch_bounds__(256) void k_bapply(const int* __restrict__ deg,
    const int* __restrict__ boffs, int* __restrict__ row_ptr,
    int* __restrict__ cursor, int n) {
  int tid = threadIdx.x;
  int base = blockIdx.x * 1024 + tid * 4;
  int v[4];
  int s = 0;
  #pragma unroll
  for (int j = 0; j < 4; j++) {
    v[j] = (base + j < n) ? deg[base + j] : 0;
    s += v[j];
  }
  int lane = tid & 63, wid = tid >> 6;
  int incl = s;
  #pragma unroll
  for (int off = 1; off < 64; off <<= 1) {
    int t = __shfl_up(incl, off, 64);
    if (lane >= off) incl += t;
  }
  __shared__ int ws[4];
  if (lane == 63) ws[wid] = incl;
  __syncthreads();
  int woff = 0;
  for (int w = 0; w < wid; w++) woff += ws[w];
  int run = boffs[blockIdx.x] + woff + (incl - s);
  #pragma unroll
  for (int j = 0; j < 4; j++) {
    if (base + j < n) {
      cursor[base + j] = run;
      run += v[j];
      row_ptr[base + j + 1] = run;
    }
  }
  if (blockIdx.x == 0 && tid == 0) row_ptr[0] = 0;
}

__global__ void k_fill(const int* __restrict__ ei, int* __restrict__ cursor,
                       int* __restrict__ col, int E) {
  int e = blockIdx.x * 256 + threadIdx.x;
  if (e < E) {
    int pos = atomicAdd(&cursor[ei[E + e]], 1);
    col[pos] = ei[e];  // store src
  }
}

// ---------------- weight prep: WT[n][k] = bf16(W[k][n]) for 7 matrices ----------------
// block b: 0=enc, 1,3,5 = W1 layer (b-1)/2, 2,4,6 = W2 layer b/2-1
__global__ __launch_bounds__(256) void k_prep_w(const float* __restrict__ encW,
    const float* __restrict__ W1, const float* __restrict__ W2,
    unsigned short* __restrict__ WT) {
  int b = blockIdx.x;
  const float* src;
  if (b == 0) src = encW;
  else if (b & 1) src = W1 + (size_t)((b - 1) / 2) * D * D;
  else src = W2 + (size_t)(b / 2 - 1) * D * D;
  unsigned short* dst = WT + (size_t)b * D * D;
  for (int e = threadIdx.x; e < D * D; e += 256) {
    int n = e >> 7, k = e & 127;
    dst[n * D + k] = (unsigned short)f2bf(src[k * D + n]);
  }
}

// ---------------- fused epilogue scales: (s1,t1,s2,t2) per col per stage ----------------
__global__ __launch_bounds__(128) void k_scales(
    const float* __restrict__ enc_b,
    const float* __restrict__ b1, const float* __restrict__ g1,
    const float* __restrict__ be1, const float* __restrict__ rm1, const float* __restrict__ rv1,
    const float* __restrict__ b2, const float* __restrict__ g2,
    const float* __restrict__ be2, const float* __restrict__ rm2, const float* __restrict__ rv2,
    const float* __restrict__ og, const float* __restrict__ ob,
    const float* __restrict__ orm, const float* __restrict__ orv,
    float4* __restrict__ scales) {
  int g = blockIdx.x, c = threadIdx.x;
  float s1 = 1.f, t1 = 0.f, s2 = 1.f, t2 = 0.f;
  if (g == 0) {
    t1 = enc_b[c];
  } else if (g & 1) {
    int l = (g - 1) / 2, i = l * D + c;
    float inv = rsqrtf(rv1[i] + 1e-5f);
    s1 = g1[i] * inv;
    t1 = (b1[i] - rm1[i]) * s1 + be1[i];
  } else {
    int l = g / 2 - 1, i = l * D + c;
    float inv = rsqrtf(rv2[i] + 1e-5f);
    s1 = g2[i] * inv;
    t1 = (b2[i] - rm2[i]) * s1 + be2[i];
    float inv2 = rsqrtf(orv[i] + 1e-5f);
    s2 = og[i] * inv2;
    t2 = ob[i] - orm[i] * s2;
  }
  scales[g * D + c] = make_float4(s1, t1, s2, t2);
}

// ---------------- GIN aggregate: m = (1+eps)*h + sum_{s in N(n)} h[s] ----------------
__global__ __launch_bounds__(256) void k_aggregate(const float* __restrict__ h,
    const int* __restrict__ row_ptr, const int* __restrict__ col,
    const float* __restrict__ eps, int layer, float* __restrict__ m, int n) {
  int node = blockIdx.x * 8 + (threadIdx.x >> 5);
  if (node >= n) return;
  int c = (threadIdx.x & 31) << 2;
  float4 acc = make_float4(0.f, 0.f, 0.f, 0.f);
  int beg = row_ptr[node], end = row_ptr[node + 1];
  for (int i = beg; i < end; i++) {
    int s = col[i];  // broadcast across the 32 lanes of this node
    const float4 v = *(const float4*)(h + (size_t)s * D + c);
    acc.x += v.x; acc.y += v.y; acc.z += v.z; acc.w += v.w;
  }
  float ep = 1.0f + eps[layer];
  const float4 hv = *(const float4*)(h + (size_t)node * D + c);
  acc.x = fmaf(ep, hv.x, acc.x);
  acc.y = fmaf(ep, hv.y, acc.y);
  acc.z = fmaf(ep, hv.z, acc.z);
  acc.w = fmaf(ep, hv.w, acc.w);
  *(float4*)(m + (size_t)node * D + c) = acc;
}

// ---------------- MFMA GEMM [N,128] @ [128,128] + fused affine/ReLU x2 ----------------
// No LDS. Block = 256 thr = 4 waves; wave w owns rows blk*64 + 16w .. +15.
// A: fp32 rows converted to bf16 fragments in registers (once).
// B: WT bf16 [n][k], direct 16B loads (L1-resident, 32KB).
// D = A·B via mfma_f32_16x16x32_bf16: a/b lane&15 = m/n, k = quad*8+j;
// C/D: col = lane&15, row = quad*4 + reg   [guide §3, m89/m91 verified]
__global__ __launch_bounds__(256) void k_mfma(const float* __restrict__ in,
    const unsigned short* __restrict__ WT, const float4* __restrict__ scales,
    float* __restrict__ out, int N) {
  int tid = threadIdx.x;
  int wave = tid >> 6, lane = tid & 63;
  int quad = lane >> 4, l16 = lane & 15;
  int rowA = blockIdx.x * 64 + wave * 16 + l16;
  int rc = min(rowA, N - 1);
  const float* arow = in + (size_t)rc * D;

  // preload A fragments: afr[kk] = A[rowA][kk*32 + quad*8 .. +7] as bf16
  bf16x8 afr[4];
  #pragma unroll
  for (int kk = 0; kk < 4; kk++) {
    int koff = kk * 32 + quad * 8;
    float4 lo = *(const float4*)(arow + koff);
    float4 hi = *(const float4*)(arow + koff + 4);
    afr[kk][0] = f2bf(lo.x); afr[kk][1] = f2bf(lo.y);
    afr[kk][2] = f2bf(lo.z); afr[kk][3] = f2bf(lo.w);
    afr[kk][4] = f2bf(hi.x); afr[kk][5] = f2bf(hi.y);
    afr[kk][6] = f2bf(hi.z); afr[kk][7] = f2bf(hi.w);
  }

  f32x4 acc[8];
  #pragma unroll
  for (int t = 0; t < 8; t++) acc[t] = (f32x4){0.f, 0.f, 0.f, 0.f};

  #pragma unroll
  for (int kk = 0; kk < 4; kk++) {
    int koff = kk * 32 + quad * 8;
    #pragma unroll
    for (int t = 0; t < 8; t++) {
      bf16x8 bfr = *(const bf16x8*)(WT + (size_t)(16 * t + l16) * D + koff);
      acc[t] = __builtin_amdgcn_mfma_f32_16x16x32_bf16(afr[kk], bfr, acc[t], 0, 0, 0);
    }
  }

  // epilogue: y = relu(y*s1+t1); y = relu(y*s2+t2)  (s2=1,t2=0 when unused)
  int rbase = blockIdx.x * 64 + wave * 16 + quad * 4;
  #pragma unroll
  for (int t = 0; t < 8; t++) {
    int colc = 16 * t + l16;
    float4 sc = scales[colc];
    #pragma unroll
    for (int reg = 0; reg < 4; reg++) {
      int row = rbase + reg;
      if (row < N) {
        float y = acc[t][reg] * sc.x + sc.y;
        y = fmaxf(y, 0.f);
        y = y * sc.z + sc.w;
        y = fmaxf(y, 0.f);
        out[(size_t)row * D + colc] = y;
      }
    }
  }
}

// ---------------- attention MLP: fused LDS-tiled 3-stage GEMM ----------------
__global__ __launch_bounds__(256) void k_attention(const float* __restrict__ h,
    const float* __restrict__ aW1, const float* __restrict__ ab1,
    const float* __restrict__ aW2, const float* __restrict__ ab2,
    const float* __restrict__ aW3, const float* __restrict__ ab3,
    const float* __restrict__ temp, float* __restrict__ scores, int n) {
  __shared__ float smem[16384];              // 64KB
  float* sH  = smem;                         // [64][128]
  float* sW1 = smem + 8192;                  // [128][64]
  int tid = threadIdx.x;
  int node0 = blockIdx.x * 64;

  for (int i4 = tid; i4 < 2048; i4 += 256) {
    int r = i4 >> 5, c4 = (i4 & 31) << 2;
    int nd = min(node0 + r, n - 1);
    *(float4*)&sH[r * 128 + c4] = *(const float4*)(h + (size_t)nd * D + c4);
  }
  for (int i4 = tid; i4 < 2048; i4 += 256)
    *(float4*)&sW1[i4 * 4] = *(const float4*)(aW1 + i4 * 4);
  __syncthreads();

  int tx = tid & 31, ty = tid >> 5;
  int c0 = tx * 2, r0 = ty * 8;
  float acc[8][2];
  #pragma unroll
  for (int i = 0; i < 8; i++) { acc[i][0] = 0.f; acc[i][1] = 0.f; }
  #pragma unroll 4
  for (int kk = 0; kk < 128; kk += 4) {
    float2 b0 = *(float2*)&sW1[(kk + 0) * 64 + c0];
    float2 b1 = *(float2*)&sW1[(kk + 1) * 64 + c0];
    float2 b2 = *(float2*)&sW1[(kk + 2) * 64 + c0];
    float2 b3 = *(float2*)&sW1[(kk + 3) * 64 + c0];
    #pragma unroll
    for (int i = 0; i < 8; i++) {
      float4 a = *(float4*)&sH[(r0 + i) * 128 + kk];
      acc[i][0] += a.x * b0.x + a.y * b1.x + a.z * b2.x + a.w * b3.x;
      acc[i][1] += a.x * b0.y + a.y * b1.y + a.z * b2.y + a.w * b3.y;
    }
  }
  float bb0 = ab1[c0], bb1 = ab1[c0 + 1];
  __syncthreads();

  float* a1B = smem;                          // [64][68]
  float* sW2 = smem + 8192;                   // [64][32]
  float* a2B = smem + 8192 + 2048;            // [64][36]
  #pragma unroll
  for (int i = 0; i < 8; i++) {
    float v0 = acc[i][0] + bb0; v0 = fmaxf(v0, 0.2f * v0);
    float v1 = acc[i][1] + bb1; v1 = fmaxf(v1, 0.2f * v1);
    *(float2*)&a1B[(r0 + i) * 68 + c0] = make_float2(v0, v1);
  }
  for (int i4 = tid; i4 < 512; i4 += 256)
    *(float4*)&sW2[i4 * 4] = *(const float4*)(aW2 + i4 * 4);
  __syncthreads();

  int tx2 = tid & 7, ty2 = tid >> 3;
  int cc0 = tx2 * 4, rr0 = ty2 * 2;
  float acc2[2][4];
  #pragma unroll
  for (int i = 0; i < 2; i++)
    #pragma unroll
    for (int j = 0; j < 4; j++) acc2[i][j] = 0.f;
  #pragma unroll 4
  for (int k = 0; k < 64; k += 4) {
    float4 b0 = *(float4*)&sW2[(k + 0) * 32 + cc0];
    float4 b1 = *(float4*)&sW2[(k + 1) * 32 + cc0];
    float4 b2 = *(float4*)&sW2[(k + 2) * 32 + cc0];
    float4 b3 = *(float4*)&sW2[(k + 3) * 32 + cc0];
    #pragma unroll
    for (int i = 0; i < 2; i++) {
      float4 a = *(float4*)&a1B[(rr0 + i) * 68 + k];
      acc2[i][0] += a.x * b0.x + a.y * b1.x + a.z * b2.x + a.w * b3.x;
      acc2[i][1] += a.x * b0.y + a.y * b1.y + a.z * b2.y + a.w * b3.y;
      acc2[i][2] += a.x * b0.z + a.y * b1.z + a.z * b2.z + a.w * b3.z;
      acc2[i][3] += a.x * b0.w + a.y * b1.w + a.z * b2.w + a.w * b3.w;
    }
  }
  float4 bias2 = *(const float4*)(ab2 + cc0);
  #pragma unroll
  for (int i = 0; i < 2; i++) {
    float4 o;
    o.x = acc2[i][0] + bias2.x; o.x = fmaxf(o.x, 0.2f * o.x);
    o.y = acc2[i][1] + bias2.y; o.y = fmaxf(o.y, 0.2f * o.y);
    o.z = acc2[i][2] + bias2.z; o.z = fmaxf(o.z, 0.2f * o.z);
    o.w = acc2[i][3] + bias2.w; o.w = fmaxf(o.w, 0.2f * o.w);
    *(float4*)&a2B[(rr0 + i) * 36 + cc0] = o;
  }
  __syncthreads();

  if (tid < 64) {
    float s = ab3[0];
    #pragma unroll 8
    for (int k = 0; k < 32; k++) s = fmaf(a2B[tid * 36 + k], aW3[k], s);
    s = fminf(fmaxf(s, -10.f), 10.f);
    int node = node0 + tid;
    if (node < n) scores[node] = 1.0f / (1.0f + __expf(-s * temp[0]));
  }
}

// ---------------- attention-weighted pool (batch sorted) ----------------
__global__ __launch_bounds__(128) void k_pool(const float* __restrict__ h,
    const float* __restrict__ scores, const int* __restrict__ batch,
    float* __restrict__ ge, int n) {
  const int NPB = 32;   // small chunks -> 1563 blocks -> latency hidden
  int f = threadIdx.x;
  int n0 = blockIdx.x * NPB;
  if (n0 >= n) return;
  int nend = min(n0 + NPB, n);
  float acc = 0.f;
  int cur = batch[n0];
  for (int i = n0; i < nend; i++) {
    int b = batch[i];
    if (b != cur) {
      atomicAdd(&ge[(size_t)cur * D + f], acc);
      acc = 0.f;
      cur = b;
    }
    acc = fmaf(h[(size_t)i * D + f], scores[i], acc);
  }
  atomicAdd(&ge[(size_t)cur * D + f], acc);
}

// ---------------- classifier: block per graph ----------------
__global__ __launch_bounds__(128) void k_classifier(const float* __restrict__ ge,
    const float* __restrict__ cW1, const float* __restrict__ cb1,
    const float* __restrict__ cW2, const float* __restrict__ cb2,
    float* __restrict__ logits, int B) {
  __shared__ float sg[D];
  __shared__ float st[D];
  int g = blockIdx.x;
  int tid = threadIdx.x;
  sg[tid] = ge[(size_t)g * D + tid];
  __syncthreads();
  float a = cb1[tid];
  #pragma unroll 8
  for (int k = 0; k < D; k++) a = fmaf(sg[k], cW1[k * D + tid], a);
  st[tid] = fmaxf(a, 0.f);
  __syncthreads();
  if (tid < 3) {
    float a2 = cb2[tid];
    for (int k = 0; k < D; k++) a2 = fmaf(st[k], cW2[k * 3 + tid], a2);
    logits[(size_t)g * 3 + tid] = a2;
  }
}

extern "C" void kernel_launch(void* const* d_in, const int* in_sizes, int n_in,
                              void* d_out, int out_size, void* d_ws, size_t ws_size,
                              hipStream_t stream) {
  const float* x     = (const float*)d_in[0];
  const int*   ei    = (const int*)d_in[1];
  const int*   batch = (const int*)d_in[2];
  const float* enc_W = (const float*)d_in[3];
  const float* enc_b = (const float*)d_in[4];
  const float* W1    = (const float*)d_in[5];
  const float* b1    = (const float*)d_in[6];
  const float* g1    = (const float*)d_in[7];
  const float* beta1 = (const float*)d_in[8];
  const float* rm1   = (const float*)d_in[9];
  const float* rv1   = (const float*)d_in[10];
  const float* W2    = (const float*)d_in[11];
  const float* b2    = (const float*)d_in[12];
  const float* g2    = (const float*)d_in[13];
  const float* beta2 = (const float*)d_in[14];
  const float* rm2   = (const float*)d_in[15];
  const float* rv2   = (const float*)d_in[16];
  const float* eps   = (const float*)d_in[17];
  const float* og    = (const float*)d_in[18];
  const float* ob    = (const float*)d_in[19];
  const float* orm   = (const float*)d_in[20];
  const float* orv   = (const float*)d_in[21];
  const float* aW1   = (const float*)d_in[22];
  const float* ab1   = (const float*)d_in[23];
  const float* aW2   = (const float*)d_in[24];
  const float* ab2   = (const float*)d_in[25];
  const float* aW3   = (const float*)d_in[26];
  const float* ab3   = (const float*)d_in[27];
  const float* temp  = (const float*)d_in[28];
  const float* cW1   = (const float*)d_in[29];
  const float* cb1   = (const float*)d_in[30];
  const float* cW2   = (const float*)d_in[31];
  const float* cb2   = (const float*)d_in[32];

  int N = in_sizes[0] / D;
  int E = in_sizes[1] / 2;
  int B = (out_size - N) / (3 + D);

  // workspace: h, m, CSR ints, then bf16 W^T + scales  (~55.3 MB total)
  float* hbuf = (float*)d_ws;
  float* mbuf = hbuf + (size_t)N * D;
  int* deg     = (int*)(mbuf + (size_t)N * D);
  int* row_ptr = deg + N;
  int* cursor  = row_ptr + N + 1;
  int* colidx  = cursor + N;
  int* bsums   = colidx + E;
  int* boffs   = bsums + 64;
  uintptr_t p = (uintptr_t)(boffs + 64);
  p = (p + 15) & ~(uintptr_t)15;
  unsigned short* WT = (unsigned short*)p;          // 7 * 128*128 bf16
  float4* sc_all = (float4*)(WT + 7 * D * D);       // 7 * 128 float4

  float* logits = (float*)d_out;
  float* ge     = logits + (size_t)B * 3;
  float* scores = ge + (size_t)B * D;

  // weight prep + epilogue scales (independent of graph build)
  k_prep_w<<<7, 256, 0, stream>>>(enc_W, W1, W2, WT);
  k_scales<<<7, 128, 0, stream>>>(enc_b, b1, g1, beta1, rm1, rv1,
                                  b2, g2, beta2, rm2, rv2, og, ob, orm, orv, sc_all);

  // CSR build
  hipMemsetAsync(deg, 0, (size_t)N * sizeof(int), stream);
  k_count<<<(E + 255) / 256, 256, 0, stream>>>(ei, deg, E);
  int nb = (N + 1023) / 1024;
  k_bsum<<<nb, 256, 0, stream>>>(deg, bsums, N);
  k_bscan<<<1, 64, 0, stream>>>(bsums, boffs, nb);
  k_bapply<<<nb, 256, 0, stream>>>(deg, boffs, row_ptr, cursor, N);
  k_fill<<<(E + 255) / 256, 256, 0, stream>>>(ei, cursor, colidx, E);

  int gblocks = (N + 63) / 64;
  // encoder: h = relu(x@enc_W + enc_b)
  k_mfma<<<gblocks, 256, 0, stream>>>(x, WT, sc_all, hbuf, N);

  for (int l = 0; l < 3; l++) {
    k_aggregate<<<(N + 7) / 8, 256, 0, stream>>>(hbuf, row_ptr, colidx, eps, l, mbuf, N);
    // m = relu(bn1(m@W1 + b1))  (in-place: each wave reads its own 16 rows first)
    k_mfma<<<gblocks, 256, 0, stream>>>(mbuf, WT + (size_t)(1 + 2 * l) * D * D,
                                        sc_all + (1 + 2 * l) * D, mbuf, N);
    // h = relu(bn_o(relu(bn2(m@W2 + b2))))
    k_mfma<<<gblocks, 256, 0, stream>>>(mbuf, WT + (size_t)(2 + 2 * l) * D * D,
                                        sc_all + (2 + 2 * l) * D, hbuf, N);
  }

  k_attention<<<gblocks, 256, 0, stream>>>(hbuf, aW1, ab1, aW2, ab2, aW3, ab3,
                                           temp, scores, N);
  hipMemsetAsync(ge, 0, (size_t)B * D * sizeof(float), stream);
  k_pool<<<(N + 31) / 32, 128, 0, stream>>>(hbuf, scores, batch, ge, N);
  k_classifier<<<B, 128, 0, stream>>>(ge, cW1, cb1, cW2, cb2, logits, B);
}

// Round 5
// 615.376 us; speedup vs baseline: 1.8320x; 1.0720x over previous
//
#include <hip/hip_runtime.h>
#include <math.h>

#define D 128

typedef short bf16x8 __attribute__((ext_vector_type(8)));
typedef float f32x4 __attribute__((ext_vector_type(4)));

__device__ inline unsigned short f2bf(float f) {  // RNE fp32->bf16
  unsigned u = __float_as_uint(f);
  return (unsigned short)((u + 0x7fffu + ((u >> 16) & 1u)) >> 16);
}
__device__ inline float bf2f(unsigned short b) {
  return __uint_as_float(((unsigned)b) << 16);
}

// ---------------- CSR build (by dst) ----------------
__global__ void k_count(const int* __restrict__ ei, int* __restrict__ deg, int E) {
  int e = blockIdx.x * 256 + threadIdx.x;
  if (e < E) atomicAdd(&deg[ei[E + e]], 1);
}

__global__ __launch_bounds__(256) void k_bsum(const int* __restrict__ deg,
                                              int* __restrict__ bsums, int n) {
  int base = blockIdx.x * 1024 + threadIdx.x * 4;
  int s = 0;
  #pragma unroll
  for (int j = 0; j < 4; j++)
    if (base + j < n) s += deg[base + j];
  #pragma unroll
  for (int off = 32; off >= 1; off >>= 1) s += __shfl_down(s, off, 64);
  __shared__ int ws[4];
  int lane = threadIdx.x & 63, wid = threadIdx.x >> 6;
  if (lane == 0) ws[wid] = s;
  __syncthreads();
  if (threadIdx.x == 0) bsums[blockIdx.x] = ws[0] + ws[1] + ws[2] + ws[3];
}

__global__ __launch_bounds__(64) void k_bscan(const int* __restrict__ bsums,
                                              int* __restrict__ boffs, int nb) {
  int lane = threadIdx.x;
  int v = (lane < nb) ? bsums[lane] : 0;
  int incl = v;
  #pragma unroll
  for (int off = 1; off < 64; off <<= 1) {
    int t = __shfl_up(incl, off, 64);
    if (lane >= off) incl += t;
  }
  if (lane < nb) boffs[lane] = incl - v;
}

__global__ __launch_bounds__(256) void k_bapply(const int* __restrict__ deg,
    const int* __restrict__ boffs, int* __restrict__ row_ptr,
    int* __restrict__ cursor, int n) {
  int tid = threadIdx.x;
  int base = blockIdx.x * 1024 + tid * 4;
  int v[4];
  int s = 0;
  #pragma unroll
  for (int j = 0; j < 4; j++) {
    v[j] = (base + j < n) ? deg[base + j] : 0;
    s += v[j];
  }
  int lane = tid & 63, wid = tid >> 6;
  int incl = s;
  #pragma unroll
  for (int off = 1; off < 64; off <<= 1) {
    int t = __shfl_up(incl, off, 64);
    if (lane >= off) incl += t;
  }
  __shared__ int ws[4];
  if (lane == 63) ws[wid] = incl;
  __syncthreads();
  int woff = 0;
  for (int w = 0; w < wid; w++) woff += ws[w];
  int run = boffs[blockIdx.x] + woff + (incl - s);
  #pragma unroll
  for (int j = 0; j < 4; j++) {
    if (base + j < n) {
      cursor[base + j] = run;
      run += v[j];
      row_ptr[base + j + 1] = run;
    }
  }
  if (blockIdx.x == 0 && tid == 0) row_ptr[0] = 0;
}

__global__ void k_fill(const int* __restrict__ ei, int* __restrict__ cursor,
                       int* __restrict__ col, int E) {
  int e = blockIdx.x * 256 + threadIdx.x;
  if (e < E) {
    int pos = atomicAdd(&cursor[ei[E + e]], 1);
    col[pos] = ei[e];  // store src
  }
}

// ---------------- weight prep: WT[n][k] = bf16(W[k][n]) for 7 matrices ----------------
__global__ __launch_bounds__(256) void k_prep_w(const float* __restrict__ encW,
    const float* __restrict__ W1, const float* __restrict__ W2,
    unsigned short* __restrict__ WT) {
  int b = blockIdx.x;
  const float* src;
  if (b == 0) src = encW;
  else if (b & 1) src = W1 + (size_t)((b - 1) / 2) * D * D;
  else src = W2 + (size_t)(b / 2 - 1) * D * D;
  unsigned short* dst = WT + (size_t)b * D * D;
  for (int e = threadIdx.x; e < D * D; e += 256) {
    int n = e >> 7, k = e & 127;
    dst[n * D + k] = f2bf(src[k * D + n]);
  }
}

// ---------------- fused epilogue scales: (s1,t1,s2,t2) per col per stage ----------------
__global__ __launch_bounds__(128) void k_scales(
    const float* __restrict__ enc_b,
    const float* __restrict__ b1, const float* __restrict__ g1,
    const float* __restrict__ be1, const float* __restrict__ rm1, const float* __restrict__ rv1,
    const float* __restrict__ b2, const float* __restrict__ g2,
    const float* __restrict__ be2, const float* __restrict__ rm2, const float* __restrict__ rv2,
    const float* __restrict__ og, const float* __restrict__ ob,
    const float* __restrict__ orm, const float* __restrict__ orv,
    float4* __restrict__ scales) {
  int g = blockIdx.x, c = threadIdx.x;
  float s1 = 1.f, t1 = 0.f, s2 = 1.f, t2 = 0.f;
  if (g == 0) {
    t1 = enc_b[c];
  } else if (g & 1) {
    int l = (g - 1) / 2, i = l * D + c;
    float inv = rsqrtf(rv1[i] + 1e-5f);
    s1 = g1[i] * inv;
    t1 = (b1[i] - rm1[i]) * s1 + be1[i];
  } else {
    int l = g / 2 - 1, i = l * D + c;
    float inv = rsqrtf(rv2[i] + 1e-5f);
    s1 = g2[i] * inv;
    t1 = (b2[i] - rm2[i]) * s1 + be2[i];
    float inv2 = rsqrtf(orv[i] + 1e-5f);
    s2 = og[i] * inv2;
    t2 = ob[i] - orm[i] * s2;
  }
  scales[g * D + c] = make_float4(s1, t1, s2, t2);
}

// ---------------- GIN aggregate (bf16 in/out): m = (1+eps)*h + sum h[src] ----------------
__global__ __launch_bounds__(256) void k_aggregate(const unsigned short* __restrict__ h,
    const int* __restrict__ row_ptr, const int* __restrict__ col,
    const float* __restrict__ eps, int layer, unsigned short* __restrict__ m, int n) {
  int node = blockIdx.x * 8 + (threadIdx.x >> 5);
  if (node >= n) return;
  int c = (threadIdx.x & 31) << 2;           // 4 bf16 cols per lane (8B loads)
  float4 acc = make_float4(0.f, 0.f, 0.f, 0.f);
  int beg = row_ptr[node], end = row_ptr[node + 1];
  int i = beg;
  for (; i + 1 < end; i += 2) {              // 2-wide: more loads in flight
    int s0 = col[i], s1 = col[i + 1];
    ushort4 v0 = *(const ushort4*)(h + (size_t)s0 * D + c);
    ushort4 v1 = *(const ushort4*)(h + (size_t)s1 * D + c);
    acc.x += bf2f(v0.x) + bf2f(v1.x);
    acc.y += bf2f(v0.y) + bf2f(v1.y);
    acc.z += bf2f(v0.z) + bf2f(v1.z);
    acc.w += bf2f(v0.w) + bf2f(v1.w);
  }
  if (i < end) {
    int s0 = col[i];
    ushort4 v0 = *(const ushort4*)(h + (size_t)s0 * D + c);
    acc.x += bf2f(v0.x); acc.y += bf2f(v0.y);
    acc.z += bf2f(v0.z); acc.w += bf2f(v0.w);
  }
  float ep = 1.0f + eps[layer];
  ushort4 hv = *(const ushort4*)(h + (size_t)node * D + c);
  acc.x = fmaf(ep, bf2f(hv.x), acc.x);
  acc.y = fmaf(ep, bf2f(hv.y), acc.y);
  acc.z = fmaf(ep, bf2f(hv.z), acc.z);
  acc.w = fmaf(ep, bf2f(hv.w), acc.w);
  ushort4 o;
  o.x = f2bf(acc.x); o.y = f2bf(acc.y); o.z = f2bf(acc.z); o.w = f2bf(acc.w);
  *(ushort4*)(m + (size_t)node * D + c) = o;
}

// ---------------- MFMA GEMM [N,128] @ [128,128] + fused affine/ReLU x2 ----------------
// No LDS. Block = 256 thr = 4 waves; wave w owns rows blk*64 + 16w .. +15.
// in: bf16 rows (or fp32 when fp32in!=0, encoder only). out: bf16.
__global__ __launch_bounds__(256) void k_mfma(const void* __restrict__ in_, int fp32in,
    const unsigned short* __restrict__ WT, const float4* __restrict__ scales,
    unsigned short* __restrict__ out, int N) {
  int tid = threadIdx.x;
  int wave = tid >> 6, lane = tid & 63;
  int quad = lane >> 4, l16 = lane & 15;
  int rowA = blockIdx.x * 64 + wave * 16 + l16;
  int rc = min(rowA, N - 1);

  bf16x8 afr[4];
  if (fp32in) {
    const float* arow = (const float*)in_ + (size_t)rc * D;
    #pragma unroll
    for (int kk = 0; kk < 4; kk++) {
      int koff = kk * 32 + quad * 8;
      float4 lo = *(const float4*)(arow + koff);
      float4 hi = *(const float4*)(arow + koff + 4);
      afr[kk][0] = f2bf(lo.x); afr[kk][1] = f2bf(lo.y);
      afr[kk][2] = f2bf(lo.z); afr[kk][3] = f2bf(lo.w);
      afr[kk][4] = f2bf(hi.x); afr[kk][5] = f2bf(hi.y);
      afr[kk][6] = f2bf(hi.z); afr[kk][7] = f2bf(hi.w);
    }
  } else {
    const unsigned short* arow = (const unsigned short*)in_ + (size_t)rc * D;
    #pragma unroll
    for (int kk = 0; kk < 4; kk++)
      afr[kk] = *(const bf16x8*)(arow + kk * 32 + quad * 8);
  }

  f32x4 acc[8];
  #pragma unroll
  for (int t = 0; t < 8; t++) acc[t] = (f32x4){0.f, 0.f, 0.f, 0.f};

  #pragma unroll
  for (int kk = 0; kk < 4; kk++) {
    int koff = kk * 32 + quad * 8;
    #pragma unroll
    for (int t = 0; t < 8; t++) {
      bf16x8 bfr = *(const bf16x8*)(WT + (size_t)(16 * t + l16) * D + koff);
      acc[t] = __builtin_amdgcn_mfma_f32_16x16x32_bf16(afr[kk], bfr, acc[t], 0, 0, 0);
    }
  }

  int rbase = blockIdx.x * 64 + wave * 16 + quad * 4;
  #pragma unroll
  for (int t = 0; t < 8; t++) {
    int colc = 16 * t + l16;
    float4 sc = scales[colc];
    #pragma unroll
    for (int reg = 0; reg < 4; reg++) {
      int row = rbase + reg;
      if (row < N) {
        float y = acc[t][reg] * sc.x + sc.y;
        y = fmaxf(y, 0.f);
        y = y * sc.z + sc.w;
        y = fmaxf(y, 0.f);
        out[(size_t)row * D + colc] = f2bf(y);
      }
    }
  }
}

// ---------------- attention MLP: fused LDS-tiled 3-stage GEMM (h bf16) ----------------
__global__ __launch_bounds__(256) void k_attention(const unsigned short* __restrict__ h,
    const float* __restrict__ aW1, const float* __restrict__ ab1,
    const float* __restrict__ aW2, const float* __restrict__ ab2,
    const float* __restrict__ aW3, const float* __restrict__ ab3,
    const float* __restrict__ temp, float* __restrict__ scores, int n) {
  __shared__ float smem[16384];              // 64KB
  float* sH  = smem;                         // [64][128]
  float* sW1 = smem + 8192;                  // [128][64]
  int tid = threadIdx.x;
  int node0 = blockIdx.x * 64;

  // stage h (bf16 -> fp32): 64 rows x 16 chunks of 8 elems
  for (int i = tid; i < 1024; i += 256) {
    int r = i >> 4, c8 = (i & 15) << 3;
    int nd = min(node0 + r, n - 1);
    uint4 u = *(const uint4*)(h + (size_t)nd * D + c8);
    float* dst = &sH[r * 128 + c8];
    dst[0] = __uint_as_float(u.x << 16); dst[1] = __uint_as_float(u.x & 0xffff0000u);
    dst[2] = __uint_as_float(u.y << 16); dst[3] = __uint_as_float(u.y & 0xffff0000u);
    dst[4] = __uint_as_float(u.z << 16); dst[5] = __uint_as_float(u.z & 0xffff0000u);
    dst[6] = __uint_as_float(u.w << 16); dst[7] = __uint_as_float(u.w & 0xffff0000u);
  }
  for (int i4 = tid; i4 < 2048; i4 += 256)
    *(float4*)&sW1[i4 * 4] = *(const float4*)(aW1 + i4 * 4);
  __syncthreads();

  int tx = tid & 31, ty = tid >> 5;
  int c0 = tx * 2, r0 = ty * 8;
  float acc[8][2];
  #pragma unroll
  for (int i = 0; i < 8; i++) { acc[i][0] = 0.f; acc[i][1] = 0.f; }
  #pragma unroll 4
  for (int kk = 0; kk < 128; kk += 4) {
    float2 b0 = *(float2*)&sW1[(kk + 0) * 64 + c0];
    float2 b1 = *(float2*)&sW1[(kk + 1) * 64 + c0];
    float2 b2 = *(float2*)&sW1[(kk + 2) * 64 + c0];
    float2 b3 = *(float2*)&sW1[(kk + 3) * 64 + c0];
    #pragma unroll
    for (int i = 0; i < 8; i++) {
      float4 a = *(float4*)&sH[(r0 + i) * 128 + kk];
      acc[i][0] += a.x * b0.x + a.y * b1.x + a.z * b2.x + a.w * b3.x;
      acc[i][1] += a.x * b0.y + a.y * b1.y + a.z * b2.y + a.w * b3.y;
    }
  }
  float bb0 = ab1[c0], bb1 = ab1[c0 + 1];
  __syncthreads();

  float* a1B = smem;                          // [64][68]
  float* sW2 = smem + 8192;                   // [64][32]
  float* a2B = smem + 8192 + 2048;            // [64][36]
  #pragma unroll
  for (int i = 0; i < 8; i++) {
    float v0 = acc[i][0] + bb0; v0 = fmaxf(v0, 0.2f * v0);
    float v1 = acc[i][1] + bb1; v1 = fmaxf(v1, 0.2f * v1);
    *(float2*)&a1B[(r0 + i) * 68 + c0] = make_float2(v0, v1);
  }
  for (int i4 = tid; i4 < 512; i4 += 256)
    *(float4*)&sW2[i4 * 4] = *(const float4*)(aW2 + i4 * 4);
  __syncthreads();

  int tx2 = tid & 7, ty2 = tid >> 3;
  int cc0 = tx2 * 4, rr0 = ty2 * 2;
  float acc2[2][4];
  #pragma unroll
  for (int i = 0; i < 2; i++)
    #pragma unroll
    for (int j = 0; j < 4; j++) acc2[i][j] = 0.f;
  #pragma unroll 4
  for (int k = 0; k < 64; k += 4) {
    float4 b0 = *(float4*)&sW2[(k + 0) * 32 + cc0];
    float4 b1 = *(float4*)&sW2[(k + 1) * 32 + cc0];
    float4 b2 = *(float4*)&sW2[(k + 2) * 32 + cc0];
    float4 b3 = *(float4*)&sW2[(k + 3) * 32 + cc0];
    #pragma unroll
    for (int i = 0; i < 2; i++) {
      float4 a = *(float4*)&a1B[(rr0 + i) * 68 + k];
      acc2[i][0] += a.x * b0.x + a.y * b1.x + a.z * b2.x + a.w * b3.x;
      acc2[i][1] += a.x * b0.y + a.y * b1.y + a.z * b2.y + a.w * b3.y;
      acc2[i][2] += a.x * b0.z + a.y * b1.z + a.z * b2.z + a.w * b3.z;
      acc2[i][3] += a.x * b0.w + a.y * b1.w + a.z * b2.w + a.w * b3.w;
    }
  }
  float4 bias2 = *(const float4*)(ab2 + cc0);
  #pragma unroll
  for (int i = 0; i < 2; i++) {
    float4 o;
    o.x = acc2[i][0] + bias2.x; o.x = fmaxf(o.x, 0.2f * o.x);
    o.y = acc2[i][1] + bias2.y; o.y = fmaxf(o.y, 0.2f * o.y);
    o.z = acc2[i][2] + bias2.z; o.z = fmaxf(o.z, 0.2f * o.z);
    o.w = acc2[i][3] + bias2.w; o.w = fmaxf(o.w, 0.2f * o.w);
    *(float4*)&a2B[(rr0 + i) * 36 + cc0] = o;
  }
  __syncthreads();

  if (tid < 64) {
    float s = ab3[0];
    #pragma unroll 8
    for (int k = 0; k < 32; k++) s = fmaf(a2B[tid * 36 + k], aW3[k], s);
    s = fminf(fmaxf(s, -10.f), 10.f);
    int node = node0 + tid;
    if (node < n) scores[node] = 1.0f / (1.0f + __expf(-s * temp[0]));
  }
}

// ---------------- attention-weighted pool (batch sorted, h bf16) ----------------
__global__ __launch_bounds__(128) void k_pool(const unsigned short* __restrict__ h,
    const float* __restrict__ scores, const int* __restrict__ batch,
    float* __restrict__ ge, int n) {
  const int NPB = 32;
  int f = threadIdx.x;
  int n0 = blockIdx.x * NPB;
  if (n0 >= n) return;
  int nend = min(n0 + NPB, n);
  float acc = 0.f;
  int cur = batch[n0];
  for (int i = n0; i < nend; i++) {
    int b = batch[i];
    if (b != cur) {
      atomicAdd(&ge[(size_t)cur * D + f], acc);
      acc = 0.f;
      cur = b;
    }
    acc = fmaf(bf2f(h[(size_t)i * D + f]), scores[i], acc);
  }
  atomicAdd(&ge[(size_t)cur * D + f], acc);
}

// ---------------- classifier: block per graph ----------------
__global__ __launch_bounds__(128) void k_classifier(const float* __restrict__ ge,
    const float* __restrict__ cW1, const float* __restrict__ cb1,
    const float* __restrict__ cW2, const float* __restrict__ cb2,
    float* __restrict__ logits, int B) {
  __shared__ float sg[D];
  __shared__ float st[D];
  int g = blockIdx.x;
  int tid = threadIdx.x;
  sg[tid] = ge[(size_t)g * D + tid];
  __syncthreads();
  float a = cb1[tid];
  #pragma unroll 8
  for (int k = 0; k < D; k++) a = fmaf(sg[k], cW1[k * D + tid], a);
  st[tid] = fmaxf(a, 0.f);
  __syncthreads();
  if (tid < 3) {
    float a2 = cb2[tid];
    for (int k = 0; k < D; k++) a2 = fmaf(st[k], cW2[k * 3 + tid], a2);
    logits[(size_t)g * 3 + tid] = a2;
  }
}

extern "C" void kernel_launch(void* const* d_in, const int* in_sizes, int n_in,
                              void* d_out, int out_size, void* d_ws, size_t ws_size,
                              hipStream_t stream) {
  const float* x     = (const float*)d_in[0];
  const int*   ei    = (const int*)d_in[1];
  const int*   batch = (const int*)d_in[2];
  const float* enc_W = (const float*)d_in[3];
  const float* enc_b = (const float*)d_in[4];
  const float* W1    = (const float*)d_in[5];
  const float* b1    = (const float*)d_in[6];
  const float* g1    = (const float*)d_in[7];
  const float* beta1 = (const float*)d_in[8];
  const float* rm1   = (const float*)d_in[9];
  const float* rv1   = (const float*)d_in[10];
  const float* W2    = (const float*)d_in[11];
  const float* b2    = (const float*)d_in[12];
  const float* g2    = (const float*)d_in[13];
  const float* beta2 = (const float*)d_in[14];
  const float* rm2   = (const float*)d_in[15];
  const float* rv2   = (const float*)d_in[16];
  const float* eps   = (const float*)d_in[17];
  const float* og    = (const float*)d_in[18];
  const float* ob    = (const float*)d_in[19];
  const float* orm   = (const float*)d_in[20];
  const float* orv   = (const float*)d_in[21];
  const float* aW1   = (const float*)d_in[22];
  const float* ab1   = (const float*)d_in[23];
  const float* aW2   = (const float*)d_in[24];
  const float* ab2   = (const float*)d_in[25];
  const float* aW3   = (const float*)d_in[26];
  const float* ab3   = (const float*)d_in[27];
  const float* temp  = (const float*)d_in[28];
  const float* cW1   = (const float*)d_in[29];
  const float* cb1   = (const float*)d_in[30];
  const float* cW2   = (const float*)d_in[31];
  const float* cb2   = (const float*)d_in[32];

  int N = in_sizes[0] / D;
  int E = in_sizes[1] / 2;
  int B = (out_size - N) / (3 + D);

  // workspace: bf16 h, m; CSR ints; bf16 W^T; scales
  unsigned short* hbuf = (unsigned short*)d_ws;
  unsigned short* mbuf = hbuf + (size_t)N * D;
  int* deg     = (int*)(mbuf + (size_t)N * D);
  int* row_ptr = deg + N;
  int* cursor  = row_ptr + N + 1;
  int* colidx  = cursor + N;
  int* bsums   = colidx + E;
  int* boffs   = bsums + 64;
  uintptr_t p = (uintptr_t)(boffs + 64);
  p = (p + 15) & ~(uintptr_t)15;
  unsigned short* WT = (unsigned short*)p;          // 7 * 128*128 bf16
  float4* sc_all = (float4*)(WT + 7 * D * D);       // 7 * 128 float4

  float* logits = (float*)d_out;
  float* ge     = logits + (size_t)B * 3;
  float* scores = ge + (size_t)B * D;

  k_prep_w<<<7, 256, 0, stream>>>(enc_W, W1, W2, WT);
  k_scales<<<7, 128, 0, stream>>>(enc_b, b1, g1, beta1, rm1, rv1,
                                  b2, g2, beta2, rm2, rv2, og, ob, orm, orv, sc_all);

  hipMemsetAsync(deg, 0, (size_t)N * sizeof(int), stream);
  k_count<<<(E + 255) / 256, 256, 0, stream>>>(ei, deg, E);
  int nb = (N + 1023) / 1024;
  k_bsum<<<nb, 256, 0, stream>>>(deg, bsums, N);
  k_bscan<<<1, 64, 0, stream>>>(bsums, boffs, nb);
  k_bapply<<<nb, 256, 0, stream>>>(deg, boffs, row_ptr, cursor, N);
  k_fill<<<(E + 255) / 256, 256, 0, stream>>>(ei, cursor, colidx, E);

  int gblocks = (N + 63) / 64;
  // encoder: h = relu(x@enc_W + enc_b)  (fp32 input path)
  k_mfma<<<gblocks, 256, 0, stream>>>(x, 1, WT, sc_all, hbuf, N);

  for (int l = 0; l < 3; l++) {
    k_aggregate<<<(N + 7) / 8, 256, 0, stream>>>(hbuf, row_ptr, colidx, eps, l, mbuf, N);
    k_mfma<<<gblocks, 256, 0, stream>>>(mbuf, 0, WT + (size_t)(1 + 2 * l) * D * D,
                                        sc_all + (1 + 2 * l) * D, mbuf, N);
    k_mfma<<<gblocks, 256, 0, stream>>>(mbuf, 0, WT + (size_t)(2 + 2 * l) * D * D,
                                        sc_all + (2 + 2 * l) * D, hbuf, N);
  }

  k_attention<<<gblocks, 256, 0, stream>>>(hbuf, aW1, ab1, aW2, ab2, aW3, ab3,
                                           temp, scores, N);
  hipMemsetAsync(ge, 0, (size_t)B * D * sizeof(float), stream);
  k_pool<<<(N + 31) / 32, 128, 0, stream>>>(hbuf, scores, batch, ge, N);
  k_classifier<<<B, 128, 0, stream>>>(ge, cW1, cb1, cW2, cb2, logits, B);
}

// Round 6
// 583.358 us; speedup vs baseline: 1.9326x; 1.0549x over previous
//
#include <hip/hip_runtime.h>
#include <math.h>

#define D 128
#define BSH 7                    // bucket = dst >> 7 (128 nodes/bucket)
#define BPAD 16                  // bucket counters padded to 64B lines

typedef short bf16x8 __attribute__((ext_vector_type(8)));
typedef float f32x4 __attribute__((ext_vector_type(4)));

__device__ inline unsigned short f2bf(float f) {  // RNE fp32->bf16
  unsigned u = __float_as_uint(f);
  return (unsigned short)((u + 0x7fffu + ((u >> 16) & 1u)) >> 16);
}
__device__ inline float bf2f(unsigned short b) {
  return __uint_as_float(((unsigned)b) << 16);
}

// ---------------- bucketed CSR build ----------------
// A: bucket histogram (LDS-aggregated, padded global counters)
__global__ __launch_bounds__(256) void k_bhist(const int* __restrict__ ei,
    int* __restrict__ bcnt, int E, int nb) {
  __shared__ int h[512];
  for (int i = threadIdx.x; i < 512; i += 256) h[i] = 0;
  __syncthreads();
  for (int e = blockIdx.x * 256 + threadIdx.x; e < E; e += gridDim.x * 256)
    atomicAdd(&h[ei[E + e] >> BSH], 1);
  __syncthreads();
  for (int i = threadIdx.x; i < nb; i += 256)
    if (h[i]) atomicAdd(&bcnt[i * BPAD], h[i]);
}

// B: scan bucket counts -> boff (exclusive, nb+1) + init bucket cursors
__global__ __launch_bounds__(512) void k_bktscan(const int* __restrict__ bcnt,
    int* __restrict__ boff, int* __restrict__ bcur, int* __restrict__ row_ptr,
    int nb, int N, int E) {
  int tid = threadIdx.x;
  int v = (tid < nb) ? bcnt[tid * BPAD] : 0;
  int lane = tid & 63, w = tid >> 6;
  int incl = v;
  #pragma unroll
  for (int off = 1; off < 64; off <<= 1) {
    int t = __shfl_up(incl, off, 64);
    if (lane >= off) incl += t;
  }
  __shared__ int ws[8];
  if (lane == 63) ws[w] = incl;
  __syncthreads();
  if (tid == 0) {
    int r = 0;
    #pragma unroll
    for (int i = 0; i < 8; i++) { int t = ws[i]; ws[i] = r; r += t; }
  }
  __syncthreads();
  int excl = ws[w] + incl - v;
  if (tid < nb) { boff[tid] = excl; bcur[tid * BPAD] = excl; }
  if (tid == nb - 1) boff[nb] = excl + v;
  if (tid == 0) row_ptr[N] = E;
}

// C: scatter (src,dst) pairs into bucket regions (sequential-ish appends)
__global__ __launch_bounds__(256) void k_bscatter(const int* __restrict__ ei,
    int* __restrict__ bcur, uint2* __restrict__ pairs, int E) {
  int e = blockIdx.x * 256 + threadIdx.x;
  if (e < E) {
    int src = ei[e], dst = ei[E + e];
    int pos = atomicAdd(&bcur[(dst >> BSH) * BPAD], 1);
    pairs[pos] = make_uint2((unsigned)src, (unsigned)dst);
  }
}

// D: per-bucket local counting sort -> row_ptr + col (writes stay in-bucket)
__global__ __launch_bounds__(256) void k_bplace(const uint2* __restrict__ pairs,
    const int* __restrict__ boff, int* __restrict__ row_ptr,
    int* __restrict__ col, int N) {
  int b = blockIdx.x, tid = threadIdx.x;
  int n0 = b << BSH;
  int nn = min(128, N - n0);
  int beg = boff[b], end = boff[b + 1];
  int cnt = end - beg;
  __shared__ int hist[128];
  __shared__ int cursor[128];
  __shared__ int wtot[2];
  if (tid < 128) hist[tid] = 0;
  __syncthreads();
  for (int i = tid; i < cnt; i += 256)
    atomicAdd(&hist[pairs[beg + i].y & 127], 1);
  __syncthreads();
  int v = 0, incl = 0, w = 0;
  if (tid < 128) {
    v = hist[tid];
    int lane = tid & 63; w = tid >> 6;
    incl = v;
    #pragma unroll
    for (int off = 1; off < 64; off <<= 1) {
      int t = __shfl_up(incl, off, 64);
      if (lane >= off) incl += t;
    }
    if (lane == 63) wtot[w] = incl;
  }
  __syncthreads();
  if (tid < 128) {
    int excl = incl - v + (w ? wtot[0] : 0);
    cursor[tid] = excl;
    if (tid < nn) row_ptr[n0 + tid] = beg + excl;
  }
  __syncthreads();
  for (int i = tid; i < cnt; i += 256) {
    uint2 u = pairs[beg + i];
    int p = atomicAdd(&cursor[u.y & 127], 1);
    col[beg + p] = (int)u.x;
  }
}

// ---------------- weight prep: WT[n][k] = bf16(W[k][n]) for 7 matrices ----------------
__global__ __launch_bounds__(256) void k_prep_w(const float* __restrict__ encW,
    const float* __restrict__ W1, const float* __restrict__ W2,
    unsigned short* __restrict__ WT) {
  int b = blockIdx.x;
  const float* src;
  if (b == 0) src = encW;
  else if (b & 1) src = W1 + (size_t)((b - 1) / 2) * D * D;
  else src = W2 + (size_t)(b / 2 - 1) * D * D;
  unsigned short* dst = WT + (size_t)b * D * D;
  for (int e = threadIdx.x; e < D * D; e += 256) {
    int n = e >> 7, k = e & 127;
    dst[n * D + k] = f2bf(src[k * D + n]);
  }
}

// ---------------- fused epilogue scales ----------------
__global__ __launch_bounds__(128) void k_scales(
    const float* __restrict__ enc_b,
    const float* __restrict__ b1, const float* __restrict__ g1,
    const float* __restrict__ be1, const float* __restrict__ rm1, const float* __restrict__ rv1,
    const float* __restrict__ b2, const float* __restrict__ g2,
    const float* __restrict__ be2, const float* __restrict__ rm2, const float* __restrict__ rv2,
    const float* __restrict__ og, const float* __restrict__ ob,
    const float* __restrict__ orm, const float* __restrict__ orv,
    float4* __restrict__ scales) {
  int g = blockIdx.x, c = threadIdx.x;
  float s1 = 1.f, t1 = 0.f, s2 = 1.f, t2 = 0.f;
  if (g == 0) {
    t1 = enc_b[c];
  } else if (g & 1) {
    int l = (g - 1) / 2, i = l * D + c;
    float inv = rsqrtf(rv1[i] + 1e-5f);
    s1 = g1[i] * inv;
    t1 = (b1[i] - rm1[i]) * s1 + be1[i];
  } else {
    int l = g / 2 - 1, i = l * D + c;
    float inv = rsqrtf(rv2[i] + 1e-5f);
    s1 = g2[i] * inv;
    t1 = (b2[i] - rm2[i]) * s1 + be2[i];
    float inv2 = rsqrtf(orv[i] + 1e-5f);
    s2 = og[i] * inv2;
    t2 = ob[i] - orm[i] * s2;
  }
  scales[g * D + c] = make_float4(s1, t1, s2, t2);
}

// ---------------- GIN aggregate (bf16 in/out) ----------------
__global__ __launch_bounds__(256) void k_aggregate(const unsigned short* __restrict__ h,
    const int* __restrict__ row_ptr, const int* __restrict__ col,
    const float* __restrict__ eps, int layer, unsigned short* __restrict__ m, int n) {
  int node = blockIdx.x * 8 + (threadIdx.x >> 5);
  if (node >= n) return;
  int c = (threadIdx.x & 31) << 2;
  float4 acc = make_float4(0.f, 0.f, 0.f, 0.f);
  int beg = row_ptr[node], end = row_ptr[node + 1];
  int i = beg;
  for (; i + 1 < end; i += 2) {
    int s0 = col[i], s1 = col[i + 1];
    ushort4 v0 = *(const ushort4*)(h + (size_t)s0 * D + c);
    ushort4 v1 = *(const ushort4*)(h + (size_t)s1 * D + c);
    acc.x += bf2f(v0.x) + bf2f(v1.x);
    acc.y += bf2f(v0.y) + bf2f(v1.y);
    acc.z += bf2f(v0.z) + bf2f(v1.z);
    acc.w += bf2f(v0.w) + bf2f(v1.w);
  }
  if (i < end) {
    int s0 = col[i];
    ushort4 v0 = *(const ushort4*)(h + (size_t)s0 * D + c);
    acc.x += bf2f(v0.x); acc.y += bf2f(v0.y);
    acc.z += bf2f(v0.z); acc.w += bf2f(v0.w);
  }
  float ep = 1.0f + eps[layer];
  ushort4 hv = *(const ushort4*)(h + (size_t)node * D + c);
  acc.x = fmaf(ep, bf2f(hv.x), acc.x);
  acc.y = fmaf(ep, bf2f(hv.y), acc.y);
  acc.z = fmaf(ep, bf2f(hv.z), acc.z);
  acc.w = fmaf(ep, bf2f(hv.w), acc.w);
  ushort4 o;
  o.x = f2bf(acc.x); o.y = f2bf(acc.y); o.z = f2bf(acc.z); o.w = f2bf(acc.w);
  *(ushort4*)(m + (size_t)node * D + c) = o;
}

// ---------------- MFMA GEMM [N,128] @ [128,128] + fused affine/ReLU x2 ----------------
__global__ __launch_bounds__(256) void k_mfma(const void* __restrict__ in_, int fp32in,
    const unsigned short* __restrict__ WT, const float4* __restrict__ scales,
    unsigned short* __restrict__ out, int N) {
  int tid = threadIdx.x;
  int wave = tid >> 6, lane = tid & 63;
  int quad = lane >> 4, l16 = lane & 15;
  int rowA = blockIdx.x * 64 + wave * 16 + l16;
  int rc = min(rowA, N - 1);

  bf16x8 afr[4];
  if (fp32in) {
    const float* arow = (const float*)in_ + (size_t)rc * D;
    #pragma unroll
    for (int kk = 0; kk < 4; kk++) {
      int koff = kk * 32 + quad * 8;
      float4 lo = *(const float4*)(arow + koff);
      float4 hi = *(const float4*)(arow + koff + 4);
      afr[kk][0] = f2bf(lo.x); afr[kk][1] = f2bf(lo.y);
      afr[kk][2] = f2bf(lo.z); afr[kk][3] = f2bf(lo.w);
      afr[kk][4] = f2bf(hi.x); afr[kk][5] = f2bf(hi.y);
      afr[kk][6] = f2bf(hi.z); afr[kk][7] = f2bf(hi.w);
    }
  } else {
    const unsigned short* arow = (const unsigned short*)in_ + (size_t)rc * D;
    #pragma unroll
    for (int kk = 0; kk < 4; kk++)
      afr[kk] = *(const bf16x8*)(arow + kk * 32 + quad * 8);
  }

  f32x4 acc[8];
  #pragma unroll
  for (int t = 0; t < 8; t++) acc[t] = (f32x4){0.f, 0.f, 0.f, 0.f};

  #pragma unroll
  for (int kk = 0; kk < 4; kk++) {
    int koff = kk * 32 + quad * 8;
    #pragma unroll
    for (int t = 0; t < 8; t++) {
      bf16x8 bfr = *(const bf16x8*)(WT + (size_t)(16 * t + l16) * D + koff);
      acc[t] = __builtin_amdgcn_mfma_f32_16x16x32_bf16(afr[kk], bfr, acc[t], 0, 0, 0);
    }
  }

  int rbase = blockIdx.x * 64 + wave * 16 + quad * 4;
  #pragma unroll
  for (int t = 0; t < 8; t++) {
    int colc = 16 * t + l16;
    float4 sc = scales[colc];
    #pragma unroll
    for (int reg = 0; reg < 4; reg++) {
      int row = rbase + reg;
      if (row < N) {
        float y = acc[t][reg] * sc.x + sc.y;
        y = fmaxf(y, 0.f);
        y = y * sc.z + sc.w;
        y = fmaxf(y, 0.f);
        out[(size_t)row * D + colc] = f2bf(y);
      }
    }
  }
}

// ---------------- attention MLP: fused LDS-tiled 3-stage GEMM (h bf16) ----------------
__global__ __launch_bounds__(256) void k_attention(const unsigned short* __restrict__ h,
    const float* __restrict__ aW1, const float* __restrict__ ab1,
    const float* __restrict__ aW2, const float* __restrict__ ab2,
    const float* __restrict__ aW3, const float* __restrict__ ab3,
    const float* __restrict__ temp, float* __restrict__ scores, int n) {
  __shared__ float smem[16384];              // 64KB
  float* sH  = smem;                         // [64][128]
  float* sW1 = smem + 8192;                  // [128][64]
  int tid = threadIdx.x;
  int node0 = blockIdx.x * 64;

  for (int i = tid; i < 1024; i += 256) {
    int r = i >> 4, c8 = (i & 15) << 3;
    int nd = min(node0 + r, n - 1);
    uint4 u = *(const uint4*)(h + (size_t)nd * D + c8);
    float* dst = &sH[r * 128 + c8];
    dst[0] = __uint_as_float(u.x << 16); dst[1] = __uint_as_float(u.x & 0xffff0000u);
    dst[2] = __uint_as_float(u.y << 16); dst[3] = __uint_as_float(u.y & 0xffff0000u);
    dst[4] = __uint_as_float(u.z << 16); dst[5] = __uint_as_float(u.z & 0xffff0000u);
    dst[6] = __uint_as_float(u.w << 16); dst[7] = __uint_as_float(u.w & 0xffff0000u);
  }
  for (int i4 = tid; i4 < 2048; i4 += 256)
    *(float4*)&sW1[i4 * 4] = *(const float4*)(aW1 + i4 * 4);
  __syncthreads();

  int tx = tid & 31, ty = tid >> 5;
  int c0 = tx * 2, r0 = ty * 8;
  float acc[8][2];
  #pragma unroll
  for (int i = 0; i < 8; i++) { acc[i][0] = 0.f; acc[i][1] = 0.f; }
  #pragma unroll 4
  for (int kk = 0; kk < 128; kk += 4) {
    float2 b0 = *(float2*)&sW1[(kk + 0) * 64 + c0];
    float2 b1 = *(float2*)&sW1[(kk + 1) * 64 + c0];
    float2 b2 = *(float2*)&sW1[(kk + 2) * 64 + c0];
    float2 b3 = *(float2*)&sW1[(kk + 3) * 64 + c0];
    #pragma unroll
    for (int i = 0; i < 8; i++) {
      float4 a = *(float4*)&sH[(r0 + i) * 128 + kk];
      acc[i][0] += a.x * b0.x + a.y * b1.x + a.z * b2.x + a.w * b3.x;
      acc[i][1] += a.x * b0.y + a.y * b1.y + a.z * b2.y + a.w * b3.y;
    }
  }
  float bb0 = ab1[c0], bb1 = ab1[c0 + 1];
  __syncthreads();

  float* a1B = smem;                          // [64][68]
  float* sW2 = smem + 8192;                   // [64][32]
  float* a2B = smem + 8192 + 2048;            // [64][36]
  #pragma unroll
  for (int i = 0; i < 8; i++) {
    float v0 = acc[i][0] + bb0; v0 = fmaxf(v0, 0.2f * v0);
    float v1 = acc[i][1] + bb1; v1 = fmaxf(v1, 0.2f * v1);
    *(float2*)&a1B[(r0 + i) * 68 + c0] = make_float2(v0, v1);
  }
  for (int i4 = tid; i4 < 512; i4 += 256)
    *(float4*)&sW2[i4 * 4] = *(const float4*)(aW2 + i4 * 4);
  __syncthreads();

  int tx2 = tid & 7, ty2 = tid >> 3;
  int cc0 = tx2 * 4, rr0 = ty2 * 2;
  float acc2[2][4];
  #pragma unroll
  for (int i = 0; i < 2; i++)
    #pragma unroll
    for (int j = 0; j < 4; j++) acc2[i][j] = 0.f;
  #pragma unroll 4
  for (int k = 0; k < 64; k += 4) {
    float4 b0 = *(float4*)&sW2[(k + 0) * 32 + cc0];
    float4 b1 = *(float4*)&sW2[(k + 1) * 32 + cc0];
    float4 b2 = *(float4*)&sW2[(k + 2) * 32 + cc0];
    float4 b3 = *(float4*)&sW2[(k + 3) * 32 + cc0];
    #pragma unroll
    for (int i = 0; i < 2; i++) {
      float4 a = *(float4*)&a1B[(rr0 + i) * 68 + k];
      acc2[i][0] += a.x * b0.x + a.y * b1.x + a.z * b2.x + a.w * b3.x;
      acc2[i][1] += a.x * b0.y + a.y * b1.y + a.z * b2.y + a.w * b3.y;
      acc2[i][2] += a.x * b0.z + a.y * b1.z + a.z * b2.z + a.w * b3.z;
      acc2[i][3] += a.x * b0.w + a.y * b1.w + a.z * b2.w + a.w * b3.w;
    }
  }
  float4 bias2 = *(const float4*)(ab2 + cc0);
  #pragma unroll
  for (int i = 0; i < 2; i++) {
    float4 o;
    o.x = acc2[i][0] + bias2.x; o.x = fmaxf(o.x, 0.2f * o.x);
    o.y = acc2[i][1] + bias2.y; o.y = fmaxf(o.y, 0.2f * o.y);
    o.z = acc2[i][2] + bias2.z; o.z = fmaxf(o.z, 0.2f * o.z);
    o.w = acc2[i][3] + bias2.w; o.w = fmaxf(o.w, 0.2f * o.w);
    *(float4*)&a2B[(rr0 + i) * 36 + cc0] = o;
  }
  __syncthreads();

  if (tid < 64) {
    float s = ab3[0];
    #pragma unroll 8
    for (int k = 0; k < 32; k++) s = fmaf(a2B[tid * 36 + k], aW3[k], s);
    s = fminf(fmaxf(s, -10.f), 10.f);
    int node = node0 + tid;
    if (node < n) scores[node] = 1.0f / (1.0f + __expf(-s * temp[0]));
  }
}

// ---------------- attention-weighted pool (batch sorted, h bf16) ----------------
__global__ __launch_bounds__(128) void k_pool(const unsigned short* __restrict__ h,
    const float* __restrict__ scores, const int* __restrict__ batch,
    float* __restrict__ ge, int n) {
  const int NPB = 32;
  int f = threadIdx.x;
  int n0 = blockIdx.x * NPB;
  if (n0 >= n) return;
  int nend = min(n0 + NPB, n);
  float acc = 0.f;
  int cur = batch[n0];
  for (int i = n0; i < nend; i++) {
    int b = batch[i];
    if (b != cur) {
      atomicAdd(&ge[(size_t)cur * D + f], acc);
      acc = 0.f;
      cur = b;
    }
    acc = fmaf(bf2f(h[(size_t)i * D + f]), scores[i], acc);
  }
  atomicAdd(&ge[(size_t)cur * D + f], acc);
}

// ---------------- classifier: block per graph ----------------
__global__ __launch_bounds__(128) void k_classifier(const float* __restrict__ ge,
    const float* __restrict__ cW1, const float* __restrict__ cb1,
    const float* __restrict__ cW2, const float* __restrict__ cb2,
    float* __restrict__ logits, int B) {
  __shared__ float sg[D];
  __shared__ float st[D];
  int g = blockIdx.x;
  int tid = threadIdx.x;
  sg[tid] = ge[(size_t)g * D + tid];
  __syncthreads();
  float a = cb1[tid];
  #pragma unroll 8
  for (int k = 0; k < D; k++) a = fmaf(sg[k], cW1[k * D + tid], a);
  st[tid] = fmaxf(a, 0.f);
  __syncthreads();
  if (tid < 3) {
    float a2 = cb2[tid];
    for (int k = 0; k < D; k++) a2 = fmaf(st[k], cW2[k * 3 + tid], a2);
    logits[(size_t)g * 3 + tid] = a2;
  }
}

extern "C" void kernel_launch(void* const* d_in, const int* in_sizes, int n_in,
                              void* d_out, int out_size, void* d_ws, size_t ws_size,
                              hipStream_t stream) {
  const float* x     = (const float*)d_in[0];
  const int*   ei    = (const int*)d_in[1];
  const int*   batch = (const int*)d_in[2];
  const float* enc_W = (const float*)d_in[3];
  const float* enc_b = (const float*)d_in[4];
  const float* W1    = (const float*)d_in[5];
  const float* b1    = (const float*)d_in[6];
  const float* g1    = (const float*)d_in[7];
  const float* beta1 = (const float*)d_in[8];
  const float* rm1   = (const float*)d_in[9];
  const float* rv1   = (const float*)d_in[10];
  const float* W2    = (const float*)d_in[11];
  const float* b2    = (const float*)d_in[12];
  const float* g2    = (const float*)d_in[13];
  const float* beta2 = (const float*)d_in[14];
  const float* rm2   = (const float*)d_in[15];
  const float* rv2   = (const float*)d_in[16];
  const float* eps   = (const float*)d_in[17];
  const float* og    = (const float*)d_in[18];
  const float* ob    = (const float*)d_in[19];
  const float* orm   = (const float*)d_in[20];
  const float* orv   = (const float*)d_in[21];
  const float* aW1   = (const float*)d_in[22];
  const float* ab1   = (const float*)d_in[23];
  const float* aW2   = (const float*)d_in[24];
  const float* ab2   = (const float*)d_in[25];
  const float* aW3   = (const float*)d_in[26];
  const float* ab3   = (const float*)d_in[27];
  const float* temp  = (const float*)d_in[28];
  const float* cW1   = (const float*)d_in[29];
  const float* cb1   = (const float*)d_in[30];
  const float* cW2   = (const float*)d_in[31];
  const float* cb2   = (const float*)d_in[32];

  int N = in_sizes[0] / D;
  int E = in_sizes[1] / 2;
  int B = (out_size - N) / (3 + D);
  int nb = (N + 127) >> BSH;     // buckets of 128 nodes (<=512)

  // workspace layout
  unsigned short* hbuf = (unsigned short*)d_ws;
  unsigned short* mbuf = hbuf + (size_t)N * D;
  int* row_ptr = (int*)(mbuf + (size_t)N * D);
  int* colidx  = row_ptr + N + 1;
  int* bcnt    = colidx + E;            // nb*BPAD
  int* boff    = bcnt + nb * BPAD;      // nb+1
  int* bcur    = boff + nb + 1;         // nb*BPAD
  uintptr_t p = (uintptr_t)(bcur + nb * BPAD);
  p = (p + 15) & ~(uintptr_t)15;
  uint2* pairs = (uint2*)p;             // E pairs
  unsigned short* WT = (unsigned short*)(pairs + E);   // 7*128*128 bf16
  float4* sc_all = (float4*)(WT + 7 * D * D);          // 7*128 float4

  float* logits = (float*)d_out;
  float* ge     = logits + (size_t)B * 3;
  float* scores = ge + (size_t)B * D;

  k_prep_w<<<7, 256, 0, stream>>>(enc_W, W1, W2, WT);
  k_scales<<<7, 128, 0, stream>>>(enc_b, b1, g1, beta1, rm1, rv1,
                                  b2, g2, beta2, rm2, rv2, og, ob, orm, orv, sc_all);

  // bucketed CSR build
  hipMemsetAsync(bcnt, 0, (size_t)nb * BPAD * sizeof(int), stream);
  k_bhist<<<256, 256, 0, stream>>>(ei, bcnt, E, nb);
  k_bktscan<<<1, 512, 0, stream>>>(bcnt, boff, bcur, row_ptr, nb, N, E);
  k_bscatter<<<(E + 255) / 256, 256, 0, stream>>>(ei, bcur, pairs, E);
  k_bplace<<<nb, 256, 0, stream>>>(pairs, boff, row_ptr, colidx, N);

  int gblocks = (N + 63) / 64;
  // encoder: h = relu(x@enc_W + enc_b)  (fp32 input path)
  k_mfma<<<gblocks, 256, 0, stream>>>(x, 1, WT, sc_all, hbuf, N);

  for (int l = 0; l < 3; l++) {
    k_aggregate<<<(N + 7) / 8, 256, 0, stream>>>(hbuf, row_ptr, colidx, eps, l, mbuf, N);
    k_mfma<<<gblocks, 256, 0, stream>>>(mbuf, 0, WT + (size_t)(1 + 2 * l) * D * D,
                                        sc_all + (1 + 2 * l) * D, mbuf, N);
    k_mfma<<<gblocks, 256, 0, stream>>>(mbuf, 0, WT + (size_t)(2 + 2 * l) * D * D,
                                        sc_all + (2 + 2 * l) * D, hbuf, N);
  }

  k_attention<<<gblocks, 256, 0, stream>>>(hbuf, aW1, ab1, aW2, ab2, aW3, ab3,
                                           temp, scores, N);
  hipMemsetAsync(ge, 0, (size_t)B * D * sizeof(float), stream);
  k_pool<<<(N + 31) / 32, 128, 0, stream>>>(hbuf, scores, batch, ge, N);
  k_classifier<<<B, 128, 0, stream>>>(ge, cW1, cb1, cW2, cb2, logits, B);
}

// Round 8
// 514.381 us; speedup vs baseline: 2.1918x; 1.1341x over previous
//
#include <hip/hip_runtime.h>
#include <math.h>

#define D 128
#define BSH 7                    // bucket = dst >> 7 (128 nodes/bucket)
#define BPAD 16                  // bucket counters padded to 64B lines

typedef short bf16x8 __attribute__((ext_vector_type(8)));
typedef float f32x4 __attribute__((ext_vector_type(4)));

__device__ inline unsigned short f2bf(float f) {  // RNE fp32->bf16
  unsigned u = __float_as_uint(f);
  return (unsigned short)((u + 0x7fffu + ((u >> 16) & 1u)) >> 16);
}
__device__ inline float bf2f(unsigned short b) {
  return __uint_as_float(((unsigned)b) << 16);
}

// ---------------- bucketed CSR build ----------------
__global__ __launch_bounds__(256) void k_bhist(const int* __restrict__ ei,
    int* __restrict__ bcnt, int E, int nb) {
  __shared__ int h[512];
  for (int i = threadIdx.x; i < 512; i += 256) h[i] = 0;
  __syncthreads();
  for (int e = blockIdx.x * 256 + threadIdx.x; e < E; e += gridDim.x * 256)
    atomicAdd(&h[ei[E + e] >> BSH], 1);
  __syncthreads();
  for (int i = threadIdx.x; i < nb; i += 256)
    if (h[i]) atomicAdd(&bcnt[i * BPAD], h[i]);
}

__global__ __launch_bounds__(512) void k_bktscan(const int* __restrict__ bcnt,
    int* __restrict__ boff, int* __restrict__ bcur, int* __restrict__ row_ptr,
    int nb, int N, int E) {
  int tid = threadIdx.x;
  int v = (tid < nb) ? bcnt[tid * BPAD] : 0;
  int lane = tid & 63, w = tid >> 6;
  int incl = v;
  #pragma unroll
  for (int off = 1; off < 64; off <<= 1) {
    int t = __shfl_up(incl, off, 64);
    if (lane >= off) incl += t;
  }
  __shared__ int ws[8];
  if (lane == 63) ws[w] = incl;
  __syncthreads();
  if (tid == 0) {
    int r = 0;
    #pragma unroll
    for (int i = 0; i < 8; i++) { int t = ws[i]; ws[i] = r; r += t; }
  }
  __syncthreads();
  int excl = ws[w] + incl - v;
  if (tid < nb) { boff[tid] = excl; bcur[tid * BPAD] = excl; }
  if (tid == nb - 1) boff[nb] = excl + v;
  if (tid == 0) row_ptr[N] = E;
}

__global__ __launch_bounds__(256) void k_bscatter(const int* __restrict__ ei,
    int* __restrict__ bcur, uint2* __restrict__ pairs, int E) {
  int e = blockIdx.x * 256 + threadIdx.x;
  if (e < E) {
    int src = ei[e], dst = ei[E + e];
    int pos = atomicAdd(&bcur[(dst >> BSH) * BPAD], 1);
    pairs[pos] = make_uint2((unsigned)src, (unsigned)dst);
  }
}

__global__ __launch_bounds__(256) void k_bplace(const uint2* __restrict__ pairs,
    const int* __restrict__ boff, int* __restrict__ row_ptr,
    int* __restrict__ col, int N) {
  int b = blockIdx.x, tid = threadIdx.x;
  int n0 = b << BSH;
  int nn = min(128, N - n0);
  int beg = boff[b], end = boff[b + 1];
  int cnt = end - beg;
  __shared__ int hist[128];
  __shared__ int cursor[128];
  __shared__ int wtot[2];
  if (tid < 128) hist[tid] = 0;
  __syncthreads();
  for (int i = tid; i < cnt; i += 256)
    atomicAdd(&hist[pairs[beg + i].y & 127], 1);
  __syncthreads();
  int v = 0, incl = 0, w = 0;
  if (tid < 128) {
    v = hist[tid];
    int lane = tid & 63; w = tid >> 6;
    incl = v;
    #pragma unroll
    for (int off = 1; off < 64; off <<= 1) {
      int t = __shfl_up(incl, off, 64);
      if (lane >= off) incl += t;
    }
    if (lane == 63) wtot[w] = incl;
  }
  __syncthreads();
  if (tid < 128) {
    int excl = incl - v + (w ? wtot[0] : 0);
    cursor[tid] = excl;
    if (tid < nn) row_ptr[n0 + tid] = beg + excl;
  }
  __syncthreads();
  for (int i = tid; i < cnt; i += 256) {
    uint2 u = pairs[beg + i];
    int p = atomicAdd(&cursor[u.y & 127], 1);
    col[beg + p] = (int)u.x;
  }
}

// ---------------- weight prep: WT[n][k] = bf16(W[k][n]) for 7 matrices ----------------
__global__ __launch_bounds__(256) void k_prep_w(const float* __restrict__ encW,
    const float* __restrict__ W1, const float* __restrict__ W2,
    unsigned short* __restrict__ WT) {
  int b = blockIdx.x;
  const float* src;
  if (b == 0) src = encW;
  else if (b & 1) src = W1 + (size_t)((b - 1) / 2) * D * D;
  else src = W2 + (size_t)(b / 2 - 1) * D * D;
  unsigned short* dst = WT + (size_t)b * D * D;
  for (int e = threadIdx.x; e < D * D; e += 256) {
    int n = e >> 7, k = e & 127;
    dst[n * D + k] = f2bf(src[k * D + n]);
  }
}

// ---------------- fused epilogue scales ----------------
__global__ __launch_bounds__(128) void k_scales(
    const float* __restrict__ enc_b,
    const float* __restrict__ b1, const float* __restrict__ g1,
    const float* __restrict__ be1, const float* __restrict__ rm1, const float* __restrict__ rv1,
    const float* __restrict__ b2, const float* __restrict__ g2,
    const float* __restrict__ be2, const float* __restrict__ rm2, const float* __restrict__ rv2,
    const float* __restrict__ og, const float* __restrict__ ob,
    const float* __restrict__ orm, const float* __restrict__ orv,
    float4* __restrict__ scales) {
  int g = blockIdx.x, c = threadIdx.x;
  float s1 = 1.f, t1 = 0.f, s2 = 1.f, t2 = 0.f;
  if (g == 0) {
    t1 = enc_b[c];
  } else if (g & 1) {
    int l = (g - 1) / 2, i = l * D + c;
    float inv = rsqrtf(rv1[i] + 1e-5f);
    s1 = g1[i] * inv;
    t1 = (b1[i] - rm1[i]) * s1 + be1[i];
  } else {
    int l = g / 2 - 1, i = l * D + c;
    float inv = rsqrtf(rv2[i] + 1e-5f);
    s1 = g2[i] * inv;
    t1 = (b2[i] - rm2[i]) * s1 + be2[i];
    float inv2 = rsqrtf(orv[i] + 1e-5f);
    s2 = og[i] * inv2;
    t2 = ob[i] - orm[i] * s2;
  }
  scales[g * D + c] = make_float4(s1, t1, s2, t2);
}

// ---------------- GIN aggregate (bf16 in/out), 4-wide unroll ----------------
__global__ __launch_bounds__(256) void k_aggregate(const unsigned short* __restrict__ h,
    const int* __restrict__ row_ptr, const int* __restrict__ col,
    const float* __restrict__ eps, int layer, unsigned short* __restrict__ m, int n) {
  int node = blockIdx.x * 8 + (threadIdx.x >> 5);
  if (node >= n) return;
  int c = (threadIdx.x & 31) << 2;
  float4 acc = make_float4(0.f, 0.f, 0.f, 0.f);
  int beg = row_ptr[node], end = row_ptr[node + 1];
  int i = beg;
  for (; i + 3 < end; i += 4) {
    int s0 = col[i], s1 = col[i + 1], s2 = col[i + 2], s3 = col[i + 3];
    ushort4 v0 = *(const ushort4*)(h + (size_t)s0 * D + c);
    ushort4 v1 = *(const ushort4*)(h + (size_t)s1 * D + c);
    ushort4 v2 = *(const ushort4*)(h + (size_t)s2 * D + c);
    ushort4 v3 = *(const ushort4*)(h + (size_t)s3 * D + c);
    acc.x += (bf2f(v0.x) + bf2f(v1.x)) + (bf2f(v2.x) + bf2f(v3.x));
    acc.y += (bf2f(v0.y) + bf2f(v1.y)) + (bf2f(v2.y) + bf2f(v3.y));
    acc.z += (bf2f(v0.z) + bf2f(v1.z)) + (bf2f(v2.z) + bf2f(v3.z));
    acc.w += (bf2f(v0.w) + bf2f(v1.w)) + (bf2f(v2.w) + bf2f(v3.w));
  }
  for (; i < end; i++) {
    int s0 = col[i];
    ushort4 v0 = *(const ushort4*)(h + (size_t)s0 * D + c);
    acc.x += bf2f(v0.x); acc.y += bf2f(v0.y);
    acc.z += bf2f(v0.z); acc.w += bf2f(v0.w);
  }
  float ep = 1.0f + eps[layer];
  ushort4 hv = *(const ushort4*)(h + (size_t)node * D + c);
  acc.x = fmaf(ep, bf2f(hv.x), acc.x);
  acc.y = fmaf(ep, bf2f(hv.y), acc.y);
  acc.z = fmaf(ep, bf2f(hv.z), acc.z);
  acc.w = fmaf(ep, bf2f(hv.w), acc.w);
  ushort4 o;
  o.x = f2bf(acc.x); o.y = f2bf(acc.y); o.z = f2bf(acc.z); o.w = f2bf(acc.w);
  *(ushort4*)(m + (size_t)node * D + c) = o;
}

// ---------------- MFMA GEMM [N,128] @ [128,128] + fused affine/ReLU x2 ----------------
// Block = 256 thr = 4 waves; wave w owns rows blk*64 + 16w .. +15.
// Epilogue staged through LDS (row stride 136 shorts) then written out as
// 1024 coalesced uint4s (16 threads cover one 256B row contiguously).
#define TSTRIDE 136
__global__ __launch_bounds__(256) void k_mfma(const void* __restrict__ in_, int fp32in,
    const unsigned short* __restrict__ WT, const float4* __restrict__ scales,
    unsigned short* __restrict__ out, int N) {
  __shared__ unsigned short stile[64 * TSTRIDE];   // 17.4 KB
  int tid = threadIdx.x;
  int wave = tid >> 6, lane = tid & 63;
  int quad = lane >> 4, l16 = lane & 15;
  int rowA = blockIdx.x * 64 + wave * 16 + l16;
  int rc = min(rowA, N - 1);

  bf16x8 afr[4];
  if (fp32in) {
    const float* arow = (const float*)in_ + (size_t)rc * D;
    #pragma unroll
    for (int kk = 0; kk < 4; kk++) {
      int koff = kk * 32 + quad * 8;
      float4 lo = *(const float4*)(arow + koff);
      float4 hi = *(const float4*)(arow + koff + 4);
      afr[kk][0] = f2bf(lo.x); afr[kk][1] = f2bf(lo.y);
      afr[kk][2] = f2bf(lo.z); afr[kk][3] = f2bf(lo.w);
      afr[kk][4] = f2bf(hi.x); afr[kk][5] = f2bf(hi.y);
      afr[kk][6] = f2bf(hi.z); afr[kk][7] = f2bf(hi.w);
    }
  } else {
    const unsigned short* arow = (const unsigned short*)in_ + (size_t)rc * D;
    #pragma unroll
    for (int kk = 0; kk < 4; kk++)
      afr[kk] = *(const bf16x8*)(arow + kk * 32 + quad * 8);
  }

  f32x4 acc[8];
  #pragma unroll
  for (int t = 0; t < 8; t++) acc[t] = (f32x4){0.f, 0.f, 0.f, 0.f};

  #pragma unroll
  for (int kk = 0; kk < 4; kk++) {
    int koff = kk * 32 + quad * 8;
    #pragma unroll
    for (int t = 0; t < 8; t++) {
      bf16x8 bfr = *(const bf16x8*)(WT + (size_t)(16 * t + l16) * D + koff);
      acc[t] = __builtin_amdgcn_mfma_f32_16x16x32_bf16(afr[kk], bfr, acc[t], 0, 0, 0);
    }
  }

  // epilogue -> LDS tile (row = wave*16 + quad*4 + reg, col = 16t + l16)
  int rl = wave * 16 + quad * 4;
  #pragma unroll
  for (int t = 0; t < 8; t++) {
    int colc = 16 * t + l16;
    float4 sc = scales[colc];
    #pragma unroll
    for (int reg = 0; reg < 4; reg++) {
      float y = acc[t][reg] * sc.x + sc.y;
      y = fmaxf(y, 0.f);
      y = y * sc.z + sc.w;
      y = fmaxf(y, 0.f);
      stile[(rl + reg) * TSTRIDE + colc] = f2bf(y);
    }
  }
  __syncthreads();

  // coalesced writeout: 64 rows x 128 shorts = 1024 uint4s; 4 per thread
  #pragma unroll
  for (int u = tid; u < 1024; u += 256) {
    int r = u >> 4, cs = (u & 15) * 8;
    int row = blockIdx.x * 64 + r;
    if (row < N)
      *(uint4*)(out + (size_t)row * D + cs) = *(const uint4*)&stile[r * TSTRIDE + cs];
  }
}

// ---------------- attention MLP: fused LDS-tiled 3-stage GEMM (h bf16) ----------------
__global__ __launch_bounds__(256) void k_attention(const unsigned short* __restrict__ h,
    const float* __restrict__ aW1, const float* __restrict__ ab1,
    const float* __restrict__ aW2, const float* __restrict__ ab2,
    const float* __restrict__ aW3, const float* __restrict__ ab3,
    const float* __restrict__ temp, float* __restrict__ scores, int n) {
  __shared__ float smem[16384];              // 64KB
  float* sH  = smem;                         // [64][128]
  float* sW1 = smem + 8192;                  // [128][64]
  int tid = threadIdx.x;
  int node0 = blockIdx.x * 64;

  for (int i = tid; i < 1024; i += 256) {
    int r = i >> 4, c8 = (i & 15) << 3;
    int nd = min(node0 + r, n - 1);
    uint4 u = *(const uint4*)(h + (size_t)nd * D + c8);
    float* dst = &sH[r * 128 + c8];
    dst[0] = __uint_as_float(u.x << 16); dst[1] = __uint_as_float(u.x & 0xffff0000u);
    dst[2] = __uint_as_float(u.y << 16); dst[3] = __uint_as_float(u.y & 0xffff0000u);
    dst[4] = __uint_as_float(u.z << 16); dst[5] = __uint_as_float(u.z & 0xffff0000u);
    dst[6] = __uint_as_float(u.w << 16); dst[7] = __uint_as_float(u.w & 0xffff0000u);
  }
  for (int i4 = tid; i4 < 2048; i4 += 256)
    *(float4*)&sW1[i4 * 4] = *(const float4*)(aW1 + i4 * 4);
  __syncthreads();

  int tx = tid & 31, ty = tid >> 5;
  int c0 = tx * 2, r0 = ty * 8;
  float acc[8][2];
  #pragma unroll
  for (int i = 0; i < 8; i++) { acc[i][0] = 0.f; acc[i][1] = 0.f; }
  #pragma unroll 4
  for (int kk = 0; kk < 128; kk += 4) {
    float2 b0 = *(float2*)&sW1[(kk + 0) * 64 + c0];
    float2 b1 = *(float2*)&sW1[(kk + 1) * 64 + c0];
    float2 b2 = *(float2*)&sW1[(kk + 2) * 64 + c0];
    float2 b3 = *(float2*)&sW1[(kk + 3) * 64 + c0];
    #pragma unroll
    for (int i = 0; i < 8; i++) {
      float4 a = *(float4*)&sH[(r0 + i) * 128 + kk];
      acc[i][0] += a.x * b0.x + a.y * b1.x + a.z * b2.x + a.w * b3.x;
      acc[i][1] += a.x * b0.y + a.y * b1.y + a.z * b2.y + a.w * b3.y;
    }
  }
  float bb0 = ab1[c0], bb1 = ab1[c0 + 1];
  __syncthreads();

  float* a1B = smem;                          // [64][68]
  float* sW2 = smem + 8192;                   // [64][32]
  float* a2B = smem + 8192 + 2048;            // [64][36]
  #pragma unroll
  for (int i = 0; i < 8; i++) {
    float v0 = acc[i][0] + bb0; v0 = fmaxf(v0, 0.2f * v0);
    float v1 = acc[i][1] + bb1; v1 = fmaxf(v1, 0.2f * v1);
    *(float2*)&a1B[(r0 + i) * 68 + c0] = make_float2(v0, v1);
  }
  for (int i4 = tid; i4 < 512; i4 += 256)
    *(float4*)&sW2[i4 * 4] = *(const float4*)(aW2 + i4 * 4);
  __syncthreads();

  int tx2 = tid & 7, ty2 = tid >> 3;
  int cc0 = tx2 * 4, rr0 = ty2 * 2;
  float acc2[2][4];
  #pragma unroll
  for (int i = 0; i < 2; i++)
    #pragma unroll
    for (int j = 0; j < 4; j++) acc2[i][j] = 0.f;
  #pragma unroll 4
  for (int k = 0; k < 64; k += 4) {
    float4 b0 = *(float4*)&sW2[(k + 0) * 32 + cc0];
    float4 b1 = *(float4*)&sW2[(k + 1) * 32 + cc0];
    float4 b2 = *(float4*)&sW2[(k + 2) * 32 + cc0];
    float4 b3 = *(float4*)&sW2[(k + 3) * 32 + cc0];
    #pragma unroll
    for (int i = 0; i < 2; i++) {
      float4 a = *(float4*)&a1B[(rr0 + i) * 68 + k];
      acc2[i][0] += a.x * b0.x + a.y * b1.x + a.z * b2.x + a.w * b3.x;
      acc2[i][1] += a.x * b0.y + a.y * b1.y + a.z * b2.y + a.w * b3.y;
      acc2[i][2] += a.x * b0.z + a.y * b1.z + a.z * b2.z + a.w * b3.z;
      acc2[i][3] += a.x * b0.w + a.y * b1.w + a.z * b2.w + a.w * b3.w;
    }
  }
  float4 bias2 = *(const float4*)(ab2 + cc0);
  #pragma unroll
  for (int i = 0; i < 2; i++) {
    float4 o;
    o.x = acc2[i][0] + bias2.x; o.x = fmaxf(o.x, 0.2f * o.x);
    o.y = acc2[i][1] + bias2.y; o.y = fmaxf(o.y, 0.2f * o.y);
    o.z = acc2[i][2] + bias2.z; o.z = fmaxf(o.z, 0.2f * o.z);
    o.w = acc2[i][3] + bias2.w; o.w = fmaxf(o.w, 0.2f * o.w);
    *(float4*)&a2B[(rr0 + i) * 36 + cc0] = o;
  }
  __syncthreads();

  if (tid < 64) {
    float s = ab3[0];
    #pragma unroll 8
    for (int k = 0; k < 32; k++) s = fmaf(a2B[tid * 36 + k], aW3[k], s);
    s = fminf(fmaxf(s, -10.f), 10.f);
    int node = node0 + tid;
    if (node < n) scores[node] = 1.0f / (1.0f + __expf(-s * temp[0]));
  }
}

// ---------------- attention-weighted pool (batch sorted, h bf16) ----------------
__global__ __launch_bounds__(128) void k_pool(const unsigned short* __restrict__ h,
    const float* __restrict__ scores, const int* __restrict__ batch,
    float* __restrict__ ge, int n) {
  const int NPB = 32;
  int f = threadIdx.x;
  int n0 = blockIdx.x * NPB;
  if (n0 >= n) return;
  int nend = min(n0 + NPB, n);
  float acc = 0.f;
  int cur = batch[n0];
  for (int i = n0; i < nend; i++) {
    int b = batch[i];
    if (b != cur) {
      atomicAdd(&ge[(size_t)cur * D + f], acc);
      acc = 0.f;
      cur = b;
    }
    acc = fmaf(bf2f(h[(size_t)i * D + f]), scores[i], acc);
  }
  atomicAdd(&ge[(size_t)cur * D + f], acc);
}

// ---------------- classifier: block per graph ----------------
__global__ __launch_bounds__(128) void k_classifier(const float* __restrict__ ge,
    const float* __restrict__ cW1, const float* __restrict__ cb1,
    const float* __restrict__ cW2, const float* __restrict__ cb2,
    float* __restrict__ logits, int B) {
  __shared__ float sg[D];
  __shared__ float st[D];
  int g = blockIdx.x;
  int tid = threadIdx.x;
  sg[tid] = ge[(size_t)g * D + tid];
  __syncthreads();
  float a = cb1[tid];
  #pragma unroll 8
  for (int k = 0; k < D; k++) a = fmaf(sg[k], cW1[k * D + tid], a);
  st[tid] = fmaxf(a, 0.f);
  __syncthreads();
  if (tid < 3) {
    float a2 = cb2[tid];
    for (int k = 0; k < D; k++) a2 = fmaf(st[k], cW2[k * 3 + tid], a2);
    logits[(size_t)g * 3 + tid] = a2;
  }
}

extern "C" void kernel_launch(void* const* d_in, const int* in_sizes, int n_in,
                              void* d_out, int out_size, void* d_ws, size_t ws_size,
                              hipStream_t stream) {
  const float* x     = (const float*)d_in[0];
  const int*   ei    = (const int*)d_in[1];
  const int*   batch = (const int*)d_in[2];
  const float* enc_W = (const float*)d_in[3];
  const float* enc_b = (const float*)d_in[4];
  const float* W1    = (const float*)d_in[5];
  const float* b1    = (const float*)d_in[6];
  const float* g1    = (const float*)d_in[7];
  const float* beta1 = (const float*)d_in[8];
  const float* rm1   = (const float*)d_in[9];
  const float* rv1   = (const float*)d_in[10];
  const float* W2    = (const float*)d_in[11];
  const float* b2    = (const float*)d_in[12];
  const float* g2    = (const float*)d_in[13];
  const float* beta2 = (const float*)d_in[14];
  const float* rm2   = (const float*)d_in[15];
  const float* rv2   = (const float*)d_in[16];
  const float* eps   = (const float*)d_in[17];
  const float* og    = (const float*)d_in[18];
  const float* ob    = (const float*)d_in[19];
  const float* orm   = (const float*)d_in[20];
  const float* orv   = (const float*)d_in[21];
  const float* aW1   = (const float*)d_in[22];
  const float* ab1   = (const float*)d_in[23];
  const float* aW2   = (const float*)d_in[24];
  const float* ab2   = (const float*)d_in[25];
  const float* aW3   = (const float*)d_in[26];
  const float* ab3   = (const float*)d_in[27];
  const float* temp  = (const float*)d_in[28];
  const float* cW1   = (const float*)d_in[29];
  const float* cb1   = (const float*)d_in[30];
  const float* cW2   = (const float*)d_in[31];
  const float* cb2   = (const float*)d_in[32];

  int N = in_sizes[0] / D;
  int E = in_sizes[1] / 2;
  int B = (out_size - N) / (3 + D);
  int nb = (N + 127) >> BSH;     // buckets of 128 nodes (<=512)

  // workspace layout
  unsigned short* hbuf = (unsigned short*)d_ws;
  unsigned short* mbuf = hbuf + (size_t)N * D;
  int* row_ptr = (int*)(mbuf + (size_t)N * D);
  int* colidx  = row_ptr + N + 1;
  int* bcnt    = colidx + E;            // nb*BPAD
  int* boff    = bcnt + nb * BPAD;      // nb+1
  int* bcur    = boff + nb + 1;         // nb*BPAD
  uintptr_t p = (uintptr_t)(bcur + nb * BPAD);
  p = (p + 15) & ~(uintptr_t)15;
  uint2* pairs = (uint2*)p;             // E pairs
  unsigned short* WT = (unsigned short*)(pairs + E);   // 7*128*128 bf16
  float4* sc_all = (float4*)(WT + 7 * D * D);          // 7*128 float4

  float* logits = (float*)d_out;
  float* ge     = logits + (size_t)B * 3;
  float* scores = ge + (size_t)B * D;

  k_prep_w<<<7, 256, 0, stream>>>(enc_W, W1, W2, WT);
  k_scales<<<7, 128, 0, stream>>>(enc_b, b1, g1, beta1, rm1, rv1,
                                  b2, g2, beta2, rm2, rv2, og, ob, orm, orv, sc_all);

  // bucketed CSR build
  hipMemsetAsync(bcnt, 0, (size_t)nb * BPAD * sizeof(int), stream);
  k_bhist<<<256, 256, 0, stream>>>(ei, bcnt, E, nb);
  k_bktscan<<<1, 512, 0, stream>>>(bcnt, boff, bcur, row_ptr, nb, N, E);
  k_bscatter<<<(E + 255) / 256, 256, 0, stream>>>(ei, bcur, pairs, E);
  k_bplace<<<nb, 256, 0, stream>>>(pairs, boff, row_ptr, colidx, N);

  int gblocks = (N + 63) / 64;
  // encoder: h = relu(x@enc_W + enc_b)  (fp32 input path)
  k_mfma<<<gblocks, 256, 0, stream>>>(x, 1, WT, sc_all, hbuf, N);

  for (int l = 0; l < 3; l++) {
    k_aggregate<<<(N + 7) / 8, 256, 0, stream>>>(hbuf, row_ptr, colidx, eps, l, mbuf, N);
    k_mfma<<<gblocks, 256, 0, stream>>>(mbuf, 0, WT + (size_t)(1 + 2 * l) * D * D,
                                        sc_all + (1 + 2 * l) * D, mbuf, N);
    k_mfma<<<gblocks, 256, 0, stream>>>(mbuf, 0, WT + (size_t)(2 + 2 * l) * D * D,
                                        sc_all + (2 + 2 * l) * D, hbuf, N);
  }

  k_attention<<<gblocks, 256, 0, stream>>>(hbuf, aW1, ab1, aW2, ab2, aW3, ab3,
                                           temp, scores, N);
  hipMemsetAsync(ge, 0, (size_t)B * D * sizeof(float), stream);
  k_pool<<<(N + 31) / 32, 128, 0, stream>>>(hbuf, scores, batch, ge, N);
  k_classifier<<<B, 128, 0, stream>>>(ge, cW1, cb1, cW2, cb2, logits, B);
}

// Round 9
// 507.608 us; speedup vs baseline: 2.2210x; 1.0133x over previous
//
#include <hip/hip_runtime.h>
#include <math.h>

#define D 128
#define BSH 9                    // bucket = dst >> 9 (512 nodes/bucket)
#define NBMAX 128                // max buckets (N <= 65536)
#define SCAP 64                  // per-bucket LDS staging capacity
#define BPAD 16                  // bucket cursors padded to 64B lines

typedef short bf16x8 __attribute__((ext_vector_type(8)));
typedef float f32x4 __attribute__((ext_vector_type(4)));

__device__ inline unsigned short f2bf(float f) {  // RNE fp32->bf16
  unsigned u = __float_as_uint(f);
  return (unsigned short)((u + 0x7fffu + ((u >> 16) & 1u)) >> 16);
}
__device__ inline float bf2f(unsigned short b) {
  return __uint_as_float(((unsigned)b) << 16);
}

// ---------------- bucketed CSR build (records packed: src<<16 | dst) ----------------
__global__ __launch_bounds__(256) void k_bhist(const int* __restrict__ ei,
    int* __restrict__ bcnt, int E, int nb) {
  __shared__ int h[NBMAX];
  for (int i = threadIdx.x; i < NBMAX; i += 256) h[i] = 0;
  __syncthreads();
  for (int e = blockIdx.x * 256 + threadIdx.x; e < E; e += gridDim.x * 256)
    atomicAdd(&h[ei[E + e] >> BSH], 1);
  __syncthreads();
  for (int i = threadIdx.x; i < nb; i += 256)
    if (h[i]) atomicAdd(&bcnt[i * BPAD], h[i]);
}

__global__ __launch_bounds__(128) void k_bktscan(const int* __restrict__ bcnt,
    int* __restrict__ boff, int* __restrict__ bcur, int* __restrict__ row_ptr,
    int nb, int N, int E) {
  int tid = threadIdx.x;
  int v = (tid < nb) ? bcnt[tid * BPAD] : 0;
  int lane = tid & 63, w = tid >> 6;
  int incl = v;
  #pragma unroll
  for (int off = 1; off < 64; off <<= 1) {
    int t = __shfl_up(incl, off, 64);
    if (lane >= off) incl += t;
  }
  __shared__ int ws[2];
  if (lane == 63) ws[w] = incl;
  __syncthreads();
  int excl = incl - v + (w ? ws[0] : 0);
  if (tid < nb) { boff[tid] = excl; bcur[tid * BPAD] = excl; }
  if (tid == nb - 1) boff[nb] = excl + v;
  if (tid == 0) row_ptr[N] = E;
}

// LDS-staged scatter: per-bucket runs written contiguously by one CU
__global__ __launch_bounds__(256) void k_bscatter(const int* __restrict__ ei,
    int* __restrict__ bcur, unsigned* __restrict__ pairs, int E, int nb) {
  __shared__ unsigned stage[NBMAX * SCAP];   // 32KB
  __shared__ int scnt[NBMAX];
  __shared__ int sbase[NBMAX];
  int tid = threadIdx.x;
  int c0 = blockIdx.x * 2048;
  if (c0 >= E) return;
  int cend = min(c0 + 2048, E);
  for (int i = tid; i < NBMAX; i += 256) scnt[i] = 0;
  __syncthreads();
  for (int e = c0 + tid; e < cend; e += 256) {
    int src = ei[e], dst = ei[E + e];
    unsigned rec = ((unsigned)src << 16) | (unsigned)dst;   // N <= 65536
    int b = dst >> BSH;
    int pos = atomicAdd(&scnt[b], 1);
    if (pos < SCAP) stage[b * SCAP + pos] = rec;
    else {  // overflow fallback (correct for any distribution)
      int gp = atomicAdd(&bcur[b * BPAD], 1);
      pairs[gp] = rec;
    }
  }
  __syncthreads();
  for (int b = tid; b < nb; b += 256) {
    int cnt = min(scnt[b], SCAP);
    sbase[b] = cnt ? atomicAdd(&bcur[b * BPAD], cnt) : 0;
  }
  __syncthreads();
  for (int b = 0; b < nb; b++) {
    int cnt = min(scnt[b], SCAP);
    for (int i = tid; i < cnt; i += 256)
      pairs[sbase[b] + i] = stage[b * SCAP + i];
  }
}

// per-bucket (512 nodes) counting sort -> row_ptr + col
__global__ __launch_bounds__(256) void k_bplace(const unsigned* __restrict__ pairs,
    const int* __restrict__ boff, int* __restrict__ row_ptr,
    int* __restrict__ col, int N) {
  int b = blockIdx.x, tid = threadIdx.x;
  int n0 = b << BSH;
  int nn = min(512, N - n0);
  int beg = boff[b], end = boff[b + 1];
  int cnt = end - beg;
  __shared__ int hist[512];
  __shared__ int cursor[512];
  __shared__ int wt[4];
  for (int i = tid; i < 512; i += 256) hist[i] = 0;
  __syncthreads();
  for (int i = tid; i < cnt; i += 256)
    atomicAdd(&hist[pairs[beg + i] & 511], 1);
  __syncthreads();
  // scan 512 counts: thread tid owns elems 2tid, 2tid+1
  int v0 = hist[2 * tid], v1 = hist[2 * tid + 1];
  int s = v0 + v1;
  int lane = tid & 63, w = tid >> 6;
  int incl = s;
  #pragma unroll
  for (int off = 1; off < 64; off <<= 1) {
    int t = __shfl_up(incl, off, 64);
    if (lane >= off) incl += t;
  }
  if (lane == 63) wt[w] = incl;
  __syncthreads();
  if (tid == 0) {
    int r = 0;
    #pragma unroll
    for (int i = 0; i < 4; i++) { int t = wt[i]; wt[i] = r; r += t; }
  }
  __syncthreads();
  int excl = wt[w] + incl - s;
  cursor[2 * tid] = excl;
  cursor[2 * tid + 1] = excl + v0;
  if (2 * tid < nn)     row_ptr[n0 + 2 * tid] = beg + excl;
  if (2 * tid + 1 < nn) row_ptr[n0 + 2 * tid + 1] = beg + excl + v0;
  __syncthreads();
  for (int i = tid; i < cnt; i += 256) {
    unsigned u = pairs[beg + i];
    int p = atomicAdd(&cursor[u & 511], 1);
    col[beg + p] = (int)(u >> 16);
  }
}

// ---------------- weight prep: WT[n][k] = bf16(W[k][n]) for 7 matrices ----------------
__global__ __launch_bounds__(256) void k_prep_w(const float* __restrict__ encW,
    const float* __restrict__ W1, const float* __restrict__ W2,
    unsigned short* __restrict__ WT) {
  int b = blockIdx.x;
  const float* src;
  if (b == 0) src = encW;
  else if (b & 1) src = W1 + (size_t)((b - 1) / 2) * D * D;
  else src = W2 + (size_t)(b / 2 - 1) * D * D;
  unsigned short* dst = WT + (size_t)b * D * D;
  for (int e = threadIdx.x; e < D * D; e += 256) {
    int n = e >> 7, k = e & 127;
    dst[n * D + k] = f2bf(src[k * D + n]);
  }
}

// ---------------- fused epilogue scales ----------------
__global__ __launch_bounds__(128) void k_scales(
    const float* __restrict__ enc_b,
    const float* __restrict__ b1, const float* __restrict__ g1,
    const float* __restrict__ be1, const float* __restrict__ rm1, const float* __restrict__ rv1,
    const float* __restrict__ b2, const float* __restrict__ g2,
    const float* __restrict__ be2, const float* __restrict__ rm2, const float* __restrict__ rv2,
    const float* __restrict__ og, const float* __restrict__ ob,
    const float* __restrict__ orm, const float* __restrict__ orv,
    float4* __restrict__ scales) {
  int g = blockIdx.x, c = threadIdx.x;
  float s1 = 1.f, t1 = 0.f, s2 = 1.f, t2 = 0.f;
  if (g == 0) {
    t1 = enc_b[c];
  } else if (g & 1) {
    int l = (g - 1) / 2, i = l * D + c;
    float inv = rsqrtf(rv1[i] + 1e-5f);
    s1 = g1[i] * inv;
    t1 = (b1[i] - rm1[i]) * s1 + be1[i];
  } else {
    int l = g / 2 - 1, i = l * D + c;
    float inv = rsqrtf(rv2[i] + 1e-5f);
    s1 = g2[i] * inv;
    t1 = (b2[i] - rm2[i]) * s1 + be2[i];
    float inv2 = rsqrtf(orv[i] + 1e-5f);
    s2 = og[i] * inv2;
    t2 = ob[i] - orm[i] * s2;
  }
  scales[g * D + c] = make_float4(s1, t1, s2, t2);
}

// ---------------- GIN aggregate (bf16 in/out), 4-wide unroll ----------------
__global__ __launch_bounds__(256) void k_aggregate(const unsigned short* __restrict__ h,
    const int* __restrict__ row_ptr, const int* __restrict__ col,
    const float* __restrict__ eps, int layer, unsigned short* __restrict__ m, int n) {
  int node = blockIdx.x * 8 + (threadIdx.x >> 5);
  if (node >= n) return;
  int c = (threadIdx.x & 31) << 2;
  float4 acc = make_float4(0.f, 0.f, 0.f, 0.f);
  int beg = row_ptr[node], end = row_ptr[node + 1];
  int i = beg;
  for (; i + 3 < end; i += 4) {
    int s0 = col[i], s1 = col[i + 1], s2 = col[i + 2], s3 = col[i + 3];
    ushort4 v0 = *(const ushort4*)(h + (size_t)s0 * D + c);
    ushort4 v1 = *(const ushort4*)(h + (size_t)s1 * D + c);
    ushort4 v2 = *(const ushort4*)(h + (size_t)s2 * D + c);
    ushort4 v3 = *(const ushort4*)(h + (size_t)s3 * D + c);
    acc.x += (bf2f(v0.x) + bf2f(v1.x)) + (bf2f(v2.x) + bf2f(v3.x));
    acc.y += (bf2f(v0.y) + bf2f(v1.y)) + (bf2f(v2.y) + bf2f(v3.y));
    acc.z += (bf2f(v0.z) + bf2f(v1.z)) + (bf2f(v2.z) + bf2f(v3.z));
    acc.w += (bf2f(v0.w) + bf2f(v1.w)) + (bf2f(v2.w) + bf2f(v3.w));
  }
  for (; i < end; i++) {
    int s0 = col[i];
    ushort4 v0 = *(const ushort4*)(h + (size_t)s0 * D + c);
    acc.x += bf2f(v0.x); acc.y += bf2f(v0.y);
    acc.z += bf2f(v0.z); acc.w += bf2f(v0.w);
  }
  float ep = 1.0f + eps[layer];
  ushort4 hv = *(const ushort4*)(h + (size_t)node * D + c);
  acc.x = fmaf(ep, bf2f(hv.x), acc.x);
  acc.y = fmaf(ep, bf2f(hv.y), acc.y);
  acc.z = fmaf(ep, bf2f(hv.z), acc.z);
  acc.w = fmaf(ep, bf2f(hv.w), acc.w);
  ushort4 o;
  o.x = f2bf(acc.x); o.y = f2bf(acc.y); o.z = f2bf(acc.z); o.w = f2bf(acc.w);
  *(ushort4*)(m + (size_t)node * D + c) = o;
}

// ---------------- MFMA GEMM [N,128] @ [128,128] + fused affine/ReLU x2 ----------------
#define TSTRIDE 136
__global__ __launch_bounds__(256) void k_mfma(const void* __restrict__ in_, int fp32in,
    const unsigned short* __restrict__ WT, const float4* __restrict__ scales,
    unsigned short* __restrict__ out, int N) {
  __shared__ unsigned short stile[64 * TSTRIDE];   // 17.4 KB
  int tid = threadIdx.x;
  int wave = tid >> 6, lane = tid & 63;
  int quad = lane >> 4, l16 = lane & 15;
  int rowA = blockIdx.x * 64 + wave * 16 + l16;
  int rc = min(rowA, N - 1);

  bf16x8 afr[4];
  if (fp32in) {
    const float* arow = (const float*)in_ + (size_t)rc * D;
    #pragma unroll
    for (int kk = 0; kk < 4; kk++) {
      int koff = kk * 32 + quad * 8;
      float4 lo = *(const float4*)(arow + koff);
      float4 hi = *(const float4*)(arow + koff + 4);
      afr[kk][0] = f2bf(lo.x); afr[kk][1] = f2bf(lo.y);
      afr[kk][2] = f2bf(lo.z); afr[kk][3] = f2bf(lo.w);
      afr[kk][4] = f2bf(hi.x); afr[kk][5] = f2bf(hi.y);
      afr[kk][6] = f2bf(hi.z); afr[kk][7] = f2bf(hi.w);
    }
  } else {
    const unsigned short* arow = (const unsigned short*)in_ + (size_t)rc * D;
    #pragma unroll
    for (int kk = 0; kk < 4; kk++)
      afr[kk] = *(const bf16x8*)(arow + kk * 32 + quad * 8);
  }

  f32x4 acc[8];
  #pragma unroll
  for (int t = 0; t < 8; t++) acc[t] = (f32x4){0.f, 0.f, 0.f, 0.f};

  #pragma unroll
  for (int kk = 0; kk < 4; kk++) {
    int koff = kk * 32 + quad * 8;
    #pragma unroll
    for (int t = 0; t < 8; t++) {
      bf16x8 bfr = *(const bf16x8*)(WT + (size_t)(16 * t + l16) * D + koff);
      acc[t] = __builtin_amdgcn_mfma_f32_16x16x32_bf16(afr[kk], bfr, acc[t], 0, 0, 0);
    }
  }

  // epilogue -> LDS tile
  int rl = wave * 16 + quad * 4;
  #pragma unroll
  for (int t = 0; t < 8; t++) {
    int colc = 16 * t + l16;
    float4 sc = scales[colc];
    #pragma unroll
    for (int reg = 0; reg < 4; reg++) {
      float y = acc[t][reg] * sc.x + sc.y;
      y = fmaxf(y, 0.f);
      y = y * sc.z + sc.w;
      y = fmaxf(y, 0.f);
      stile[(rl + reg) * TSTRIDE + colc] = f2bf(y);
    }
  }
  __syncthreads();

  // coalesced writeout: 64 rows x 128 shorts = 1024 uint4s
  #pragma unroll
  for (int u = tid; u < 1024; u += 256) {
    int r = u >> 4, cs = (u & 15) * 8;
    int row = blockIdx.x * 64 + r;
    if (row < N)
      *(uint4*)(out + (size_t)row * D + cs) = *(const uint4*)&stile[r * TSTRIDE + cs];
  }
}

// ---------------- attention MLP: fused LDS-tiled 3-stage GEMM (h bf16) ----------------
__global__ __launch_bounds__(256) void k_attention(const unsigned short* __restrict__ h,
    const float* __restrict__ aW1, const float* __restrict__ ab1,
    const float* __restrict__ aW2, const float* __restrict__ ab2,
    const float* __restrict__ aW3, const float* __restrict__ ab3,
    const float* __restrict__ temp, float* __restrict__ scores, int n) {
  __shared__ float smem[16384];              // 64KB
  float* sH  = smem;                         // [64][128]
  float* sW1 = smem + 8192;                  // [128][64]
  int tid = threadIdx.x;
  int node0 = blockIdx.x * 64;

  for (int i = tid; i < 1024; i += 256) {
    int r = i >> 4, c8 = (i & 15) << 3;
    int nd = min(node0 + r, n - 1);
    uint4 u = *(const uint4*)(h + (size_t)nd * D + c8);
    float* dst = &sH[r * 128 + c8];
    dst[0] = __uint_as_float(u.x << 16); dst[1] = __uint_as_float(u.x & 0xffff0000u);
    dst[2] = __uint_as_float(u.y << 16); dst[3] = __uint_as_float(u.y & 0xffff0000u);
    dst[4] = __uint_as_float(u.z << 16); dst[5] = __uint_as_float(u.z & 0xffff0000u);
    dst[6] = __uint_as_float(u.w << 16); dst[7] = __uint_as_float(u.w & 0xffff0000u);
  }
  for (int i4 = tid; i4 < 2048; i4 += 256)
    *(float4*)&sW1[i4 * 4] = *(const float4*)(aW1 + i4 * 4);
  __syncthreads();

  int tx = tid & 31, ty = tid >> 5;
  int c0 = tx * 2, r0 = ty * 8;
  float acc[8][2];
  #pragma unroll
  for (int i = 0; i < 8; i++) { acc[i][0] = 0.f; acc[i][1] = 0.f; }
  #pragma unroll 4
  for (int kk = 0; kk < 128; kk += 4) {
    float2 b0 = *(float2*)&sW1[(kk + 0) * 64 + c0];
    float2 b1 = *(float2*)&sW1[(kk + 1) * 64 + c0];
    float2 b2 = *(float2*)&sW1[(kk + 2) * 64 + c0];
    float2 b3 = *(float2*)&sW1[(kk + 3) * 64 + c0];
    #pragma unroll
    for (int i = 0; i < 8; i++) {
      float4 a = *(float4*)&sH[(r0 + i) * 128 + kk];
      acc[i][0] += a.x * b0.x + a.y * b1.x + a.z * b2.x + a.w * b3.x;
      acc[i][1] += a.x * b0.y + a.y * b1.y + a.z * b2.y + a.w * b3.y;
    }
  }
  float bb0 = ab1[c0], bb1 = ab1[c0 + 1];
  __syncthreads();

  float* a1B = smem;                          // [64][68]
  float* sW2 = smem + 8192;                   // [64][32]
  float* a2B = smem + 8192 + 2048;            // [64][36]
  #pragma unroll
  for (int i = 0; i < 8; i++) {
    float v0 = acc[i][0] + bb0; v0 = fmaxf(v0, 0.2f * v0);
    float v1 = acc[i][1] + bb1; v1 = fmaxf(v1, 0.2f * v1);
    *(float2*)&a1B[(r0 + i) * 68 + c0] = make_float2(v0, v1);
  }
  for (int i4 = tid; i4 < 512; i4 += 256)
    *(float4*)&sW2[i4 * 4] = *(const float4*)(aW2 + i4 * 4);
  __syncthreads();

  int tx2 = tid & 7, ty2 = tid >> 3;
  int cc0 = tx2 * 4, rr0 = ty2 * 2;
  float acc2[2][4];
  #pragma unroll
  for (int i = 0; i < 2; i++)
    #pragma unroll
    for (int j = 0; j < 4; j++) acc2[i][j] = 0.f;
  #pragma unroll 4
  for (int k = 0; k < 64; k += 4) {
    float4 b0 = *(float4*)&sW2[(k + 0) * 32 + cc0];
    float4 b1 = *(float4*)&sW2[(k + 1) * 32 + cc0];
    float4 b2 = *(float4*)&sW2[(k + 2) * 32 + cc0];
    float4 b3 = *(float4*)&sW2[(k + 3) * 32 + cc0];
    #pragma unroll
    for (int i = 0; i < 2; i++) {
      float4 a = *(float4*)&a1B[(rr0 + i) * 68 + k];
      acc2[i][0] += a.x * b0.x + a.y * b1.x + a.z * b2.x + a.w * b3.x;
      acc2[i][1] += a.x * b0.y + a.y * b1.y + a.z * b2.y + a.w * b3.y;
      acc2[i][2] += a.x * b0.z + a.y * b1.z + a.z * b2.z + a.w * b3.z;
      acc2[i][3] += a.x * b0.w + a.y * b1.w + a.z * b2.w + a.w * b3.w;
    }
  }
  float4 bias2 = *(const float4*)(ab2 + cc0);
  #pragma unroll
  for (int i = 0; i < 2; i++) {
    float4 o;
    o.x = acc2[i][0] + bias2.x; o.x = fmaxf(o.x, 0.2f * o.x);
    o.y = acc2[i][1] + bias2.y; o.y = fmaxf(o.y, 0.2f * o.y);
    o.z = acc2[i][2] + bias2.z; o.z = fmaxf(o.z, 0.2f * o.z);
    o.w = acc2[i][3] + bias2.w; o.w = fmaxf(o.w, 0.2f * o.w);
    *(float4*)&a2B[(rr0 + i) * 36 + cc0] = o;
  }
  __syncthreads();

  if (tid < 64) {
    float s = ab3[0];
    #pragma unroll 8
    for (int k = 0; k < 32; k++) s = fmaf(a2B[tid * 36 + k], aW3[k], s);
    s = fminf(fmaxf(s, -10.f), 10.f);
    int node = node0 + tid;
    if (node < n) scores[node] = 1.0f / (1.0f + __expf(-s * temp[0]));
  }
}

// ---------------- attention-weighted pool (batch sorted, h bf16) ----------------
__global__ __launch_bounds__(128) void k_pool(const unsigned short* __restrict__ h,
    const float* __restrict__ scores, const int* __restrict__ batch,
    float* __restrict__ ge, int n) {
  const int NPB = 32;
  int f = threadIdx.x;
  int n0 = blockIdx.x * NPB;
  if (n0 >= n) return;
  int nend = min(n0 + NPB, n);
  float acc = 0.f;
  int cur = batch[n0];
  for (int i = n0; i < nend; i++) {
    int b = batch[i];
    if (b != cur) {
      atomicAdd(&ge[(size_t)cur * D + f], acc);
      acc = 0.f;
      cur = b;
    }
    acc = fmaf(bf2f(h[(size_t)i * D + f]), scores[i], acc);
  }
  atomicAdd(&ge[(size_t)cur * D + f], acc);
}

// ---------------- classifier: block per graph ----------------
__global__ __launch_bounds__(128) void k_classifier(const float* __restrict__ ge,
    const float* __restrict__ cW1, const float* __restrict__ cb1,
    const float* __restrict__ cW2, const float* __restrict__ cb2,
    float* __restrict__ logits, int B) {
  __shared__ float sg[D];
  __shared__ float st[D];
  int g = blockIdx.x;
  int tid = threadIdx.x;
  sg[tid] = ge[(size_t)g * D + tid];
  __syncthreads();
  float a = cb1[tid];
  #pragma unroll 8
  for (int k = 0; k < D; k++) a = fmaf(sg[k], cW1[k * D + tid], a);
  st[tid] = fmaxf(a, 0.f);
  __syncthreads();
  if (tid < 3) {
    float a2 = cb2[tid];
    for (int k = 0; k < D; k++) a2 = fmaf(st[k], cW2[k * 3 + tid], a2);
    logits[(size_t)g * 3 + tid] = a2;
  }
}

extern "C" void kernel_launch(void* const* d_in, const int* in_sizes, int n_in,
                              void* d_out, int out_size, void* d_ws, size_t ws_size,
                              hipStream_t stream) {
  const float* x     = (const float*)d_in[0];
  const int*   ei    = (const int*)d_in[1];
  const int*   batch = (const int*)d_in[2];
  const float* enc_W = (const float*)d_in[3];
  const float* enc_b = (const float*)d_in[4];
  const float* W1    = (const float*)d_in[5];
  const float* b1    = (const float*)d_in[6];
  const float* g1    = (const float*)d_in[7];
  const float* beta1 = (const float*)d_in[8];
  const float* rm1   = (const float*)d_in[9];
  const float* rv1   = (const float*)d_in[10];
  const float* W2    = (const float*)d_in[11];
  const float* b2    = (const float*)d_in[12];
  const float* g2    = (const float*)d_in[13];
  const float* beta2 = (const float*)d_in[14];
  const float* rm2   = (const float*)d_in[15];
  const float* rv2   = (const float*)d_in[16];
  const float* eps   = (const float*)d_in[17];
  const float* og    = (const float*)d_in[18];
  const float* ob    = (const float*)d_in[19];
  const float* orm   = (const float*)d_in[20];
  const float* orv   = (const float*)d_in[21];
  const float* aW1   = (const float*)d_in[22];
  const float* ab1   = (const float*)d_in[23];
  const float* aW2   = (const float*)d_in[24];
  const float* ab2   = (const float*)d_in[25];
  const float* aW3   = (const float*)d_in[26];
  const float* ab3   = (const float*)d_in[27];
  const float* temp  = (const float*)d_in[28];
  const float* cW1   = (const float*)d_in[29];
  const float* cb1   = (const float*)d_in[30];
  const float* cW2   = (const float*)d_in[31];
  const float* cb2   = (const float*)d_in[32];

  int N = in_sizes[0] / D;
  int E = in_sizes[1] / 2;
  int B = (out_size - N) / (3 + D);
  int nb = (N + 511) >> BSH;     // buckets of 512 nodes (<=128 for N<=65536)

  // workspace layout
  unsigned short* hbuf = (unsigned short*)d_ws;
  unsigned short* mbuf = hbuf + (size_t)N * D;
  int* row_ptr = (int*)(mbuf + (size_t)N * D);
  int* colidx  = row_ptr + N + 1;
  int* bcnt    = colidx + E;            // nb*BPAD
  int* boff    = bcnt + nb * BPAD;      // nb+1
  int* bcur    = boff + nb + 1;         // nb*BPAD
  uintptr_t p = (uintptr_t)(bcur + nb * BPAD);
  p = (p + 15) & ~(uintptr_t)15;
  unsigned* pairs = (unsigned*)p;       // E packed records
  unsigned short* WT = (unsigned short*)(pairs + E);   // 7*128*128 bf16
  float4* sc_all = (float4*)(WT + 7 * D * D);          // 7*128 float4

  float* logits = (float*)d_out;
  float* ge     = logits + (size_t)B * 3;
  float* scores = ge + (size_t)B * D;

  k_prep_w<<<7, 256, 0, stream>>>(enc_W, W1, W2, WT);
  k_scales<<<7, 128, 0, stream>>>(enc_b, b1, g1, beta1, rm1, rv1,
                                  b2, g2, beta2, rm2, rv2, og, ob, orm, orv, sc_all);

  // bucketed CSR build (packed 4B records, LDS-staged scatter)
  hipMemsetAsync(bcnt, 0, (size_t)nb * BPAD * sizeof(int), stream);
  k_bhist<<<256, 256, 0, stream>>>(ei, bcnt, E, nb);
  k_bktscan<<<1, 128, 0, stream>>>(bcnt, boff, bcur, row_ptr, nb, N, E);
  k_bscatter<<<(E + 2047) / 2048, 256, 0, stream>>>(ei, bcur, pairs, E, nb);
  k_bplace<<<nb, 256, 0, stream>>>(pairs, boff, row_ptr, colidx, N);

  int gblocks = (N + 63) / 64;
  // encoder: h = relu(x@enc_W + enc_b)  (fp32 input path)
  k_mfma<<<gblocks, 256, 0, stream>>>(x, 1, WT, sc_all, hbuf, N);

  for (int l = 0; l < 3; l++) {
    k_aggregate<<<(N + 7) / 8, 256, 0, stream>>>(hbuf, row_ptr, colidx, eps, l, mbuf, N);
    k_mfma<<<gblocks, 256, 0, stream>>>(mbuf, 0, WT + (size_t)(1 + 2 * l) * D * D,
                                        sc_all + (1 + 2 * l) * D, mbuf, N);
    k_mfma<<<gblocks, 256, 0, stream>>>(mbuf, 0, WT + (size_t)(2 + 2 * l) * D * D,
                                        sc_all + (2 + 2 * l) * D, hbuf, N);
  }

  k_attention<<<gblocks, 256, 0, stream>>>(hbuf, aW1, ab1, aW2, ab2, aW3, ab3,
                                           temp, scores, N);
  hipMemsetAsync(ge, 0, (size_t)B * D * sizeof(float), stream);
  k_pool<<<(N + 31) / 32, 128, 0, stream>>>(hbuf, scores, batch, ge, N);
  k_classifier<<<B, 128, 0, stream>>>(ge, cW1, cb1, cW2, cb2, logits, B);
}

// Round 10
// 482.508 us; speedup vs baseline: 2.3365x; 1.0520x over previous
//
#include <hip/hip_runtime.h>
#include <math.h>

#define D 128
#define BSH 9                    // bucket = dst >> 9 (512 nodes/bucket)
#define NBMAX 128                // max buckets (N <= 65536)
#define SCAP 64                  // per-bucket LDS staging capacity
#define BPAD 16                  // bucket cursors padded to 64B lines

typedef short bf16x8 __attribute__((ext_vector_type(8)));
typedef float f32x4 __attribute__((ext_vector_type(4)));

__device__ inline unsigned short f2bf(float f) {  // RNE fp32->bf16
  unsigned u = __float_as_uint(f);
  return (unsigned short)((u + 0x7fffu + ((u >> 16) & 1u)) >> 16);
}
__device__ inline float bf2f(unsigned short b) {
  return __uint_as_float(((unsigned)b) << 16);
}

// ---------------- bucketed CSR build (records packed: src<<16 | dst) ----------------
__global__ __launch_bounds__(256) void k_bhist(const int* __restrict__ ei,
    int* __restrict__ bcnt, int E, int nb) {
  __shared__ int h[NBMAX];
  for (int i = threadIdx.x; i < NBMAX; i += 256) h[i] = 0;
  __syncthreads();
  for (int e = blockIdx.x * 256 + threadIdx.x; e < E; e += gridDim.x * 256)
    atomicAdd(&h[ei[E + e] >> BSH], 1);
  __syncthreads();
  for (int i = threadIdx.x; i < nb; i += 256)
    if (h[i]) atomicAdd(&bcnt[i * BPAD], h[i]);
}

__global__ __launch_bounds__(128) void k_bktscan(const int* __restrict__ bcnt,
    int* __restrict__ boff, int* __restrict__ bcur, int* __restrict__ row_ptr,
    int nb, int N, int E) {
  int tid = threadIdx.x;
  int v = (tid < nb) ? bcnt[tid * BPAD] : 0;
  int lane = tid & 63, w = tid >> 6;
  int incl = v;
  #pragma unroll
  for (int off = 1; off < 64; off <<= 1) {
    int t = __shfl_up(incl, off, 64);
    if (lane >= off) incl += t;
  }
  __shared__ int ws[2];
  if (lane == 63) ws[w] = incl;
  __syncthreads();
  int excl = incl - v + (w ? ws[0] : 0);
  if (tid < nb) { boff[tid] = excl; bcur[tid * BPAD] = excl; }
  if (tid == nb - 1) boff[nb] = excl + v;
  if (tid == 0) row_ptr[N] = E;
}

__global__ __launch_bounds__(256) void k_bscatter(const int* __restrict__ ei,
    int* __restrict__ bcur, unsigned* __restrict__ pairs, int E, int nb) {
  __shared__ unsigned stage[NBMAX * SCAP];   // 32KB
  __shared__ int scnt[NBMAX];
  __shared__ int sbase[NBMAX];
  int tid = threadIdx.x;
  int c0 = blockIdx.x * 2048;
  if (c0 >= E) return;
  int cend = min(c0 + 2048, E);
  for (int i = tid; i < NBMAX; i += 256) scnt[i] = 0;
  __syncthreads();
  for (int e = c0 + tid; e < cend; e += 256) {
    int src = ei[e], dst = ei[E + e];
    unsigned rec = ((unsigned)src << 16) | (unsigned)dst;   // N <= 65536
    int b = dst >> BSH;
    int pos = atomicAdd(&scnt[b], 1);
    if (pos < SCAP) stage[b * SCAP + pos] = rec;
    else {
      int gp = atomicAdd(&bcur[b * BPAD], 1);
      pairs[gp] = rec;
    }
  }
  __syncthreads();
  for (int b = tid; b < nb; b += 256) {
    int cnt = min(scnt[b], SCAP);
    sbase[b] = cnt ? atomicAdd(&bcur[b * BPAD], cnt) : 0;
  }
  __syncthreads();
  for (int b = 0; b < nb; b++) {
    int cnt = min(scnt[b], SCAP);
    for (int i = tid; i < cnt; i += 256)
      pairs[sbase[b] + i] = stage[b * SCAP + i];
  }
}

__global__ __launch_bounds__(256) void k_bplace(const unsigned* __restrict__ pairs,
    const int* __restrict__ boff, int* __restrict__ row_ptr,
    int* __restrict__ col, int N) {
  int b = blockIdx.x, tid = threadIdx.x;
  int n0 = b << BSH;
  int nn = min(512, N - n0);
  int beg = boff[b], end = boff[b + 1];
  int cnt = end - beg;
  __shared__ int hist[512];
  __shared__ int cursor[512];
  __shared__ int wt[4];
  for (int i = tid; i < 512; i += 256) hist[i] = 0;
  __syncthreads();
  for (int i = tid; i < cnt; i += 256)
    atomicAdd(&hist[pairs[beg + i] & 511], 1);
  __syncthreads();
  int v0 = hist[2 * tid], v1 = hist[2 * tid + 1];
  int s = v0 + v1;
  int lane = tid & 63, w = tid >> 6;
  int incl = s;
  #pragma unroll
  for (int off = 1; off < 64; off <<= 1) {
    int t = __shfl_up(incl, off, 64);
    if (lane >= off) incl += t;
  }
  if (lane == 63) wt[w] = incl;
  __syncthreads();
  if (tid == 0) {
    int r = 0;
    #pragma unroll
    for (int i = 0; i < 4; i++) { int t = wt[i]; wt[i] = r; r += t; }
  }
  __syncthreads();
  int excl = wt[w] + incl - s;
  cursor[2 * tid] = excl;
  cursor[2 * tid + 1] = excl + v0;
  if (2 * tid < nn)     row_ptr[n0 + 2 * tid] = beg + excl;
  if (2 * tid + 1 < nn) row_ptr[n0 + 2 * tid + 1] = beg + excl + v0;
  __syncthreads();
  for (int i = tid; i < cnt; i += 256) {
    unsigned u = pairs[beg + i];
    int p = atomicAdd(&cursor[u & 511], 1);
    col[beg + p] = (int)(u >> 16);
  }
}

// ---------------- weight prep: WT[n][k] = bf16(W[k][n]) for 7 matrices ----------------
__global__ __launch_bounds__(256) void k_prep_w(const float* __restrict__ encW,
    const float* __restrict__ W1, const float* __restrict__ W2,
    unsigned short* __restrict__ WT) {
  int b = blockIdx.x;
  const float* src;
  if (b == 0) src = encW;
  else if (b & 1) src = W1 + (size_t)((b - 1) / 2) * D * D;
  else src = W2 + (size_t)(b / 2 - 1) * D * D;
  unsigned short* dst = WT + (size_t)b * D * D;
  for (int e = threadIdx.x; e < D * D; e += 256) {
    int n = e >> 7, k = e & 127;
    dst[n * D + k] = f2bf(src[k * D + n]);
  }
}

// ---------------- fused epilogue scales ----------------
__global__ __launch_bounds__(128) void k_scales(
    const float* __restrict__ enc_b,
    const float* __restrict__ b1, const float* __restrict__ g1,
    const float* __restrict__ be1, const float* __restrict__ rm1, const float* __restrict__ rv1,
    const float* __restrict__ b2, const float* __restrict__ g2,
    const float* __restrict__ be2, const float* __restrict__ rm2, const float* __restrict__ rv2,
    const float* __restrict__ og, const float* __restrict__ ob,
    const float* __restrict__ orm, const float* __restrict__ orv,
    float4* __restrict__ scales) {
  int g = blockIdx.x, c = threadIdx.x;
  float s1 = 1.f, t1 = 0.f, s2 = 1.f, t2 = 0.f;
  if (g == 0) {
    t1 = enc_b[c];
  } else if (g & 1) {
    int l = (g - 1) / 2, i = l * D + c;
    float inv = rsqrtf(rv1[i] + 1e-5f);
    s1 = g1[i] * inv;
    t1 = (b1[i] - rm1[i]) * s1 + be1[i];
  } else {
    int l = g / 2 - 1, i = l * D + c;
    float inv = rsqrtf(rv2[i] + 1e-5f);
    s1 = g2[i] * inv;
    t1 = (b2[i] - rm2[i]) * s1 + be2[i];
    float inv2 = rsqrtf(orv[i] + 1e-5f);
    s2 = og[i] * inv2;
    t2 = ob[i] - orm[i] * s2;
  }
  scales[g * D + c] = make_float4(s1, t1, s2, t2);
}

// ---------------- GIN aggregate (bf16): 16 lanes/node x 16B loads ----------------
__global__ __launch_bounds__(256) void k_aggregate(const unsigned short* __restrict__ h,
    const int* __restrict__ row_ptr, const int* __restrict__ col,
    const float* __restrict__ eps, int layer, unsigned short* __restrict__ m, int n) {
  int node = blockIdx.x * 16 + (threadIdx.x >> 4);
  if (node >= n) return;
  int c = (threadIdx.x & 15) << 3;   // 8 bf16 cols per lane (16B loads)
  float acc[8];
  #pragma unroll
  for (int j = 0; j < 8; j++) acc[j] = 0.f;
  int beg = row_ptr[node], end = row_ptr[node + 1];
  int i = beg;
  for (; i + 3 < end; i += 4) {
    int s0 = col[i], s1 = col[i + 1], s2 = col[i + 2], s3 = col[i + 3];
    uint4 v0 = *(const uint4*)(h + (size_t)s0 * D + c);
    uint4 v1 = *(const uint4*)(h + (size_t)s1 * D + c);
    uint4 v2 = *(const uint4*)(h + (size_t)s2 * D + c);
    uint4 v3 = *(const uint4*)(h + (size_t)s3 * D + c);
    acc[0] += __uint_as_float(v0.x << 16) + __uint_as_float(v1.x << 16)
            + __uint_as_float(v2.x << 16) + __uint_as_float(v3.x << 16);
    acc[1] += __uint_as_float(v0.x & 0xffff0000u) + __uint_as_float(v1.x & 0xffff0000u)
            + __uint_as_float(v2.x & 0xffff0000u) + __uint_as_float(v3.x & 0xffff0000u);
    acc[2] += __uint_as_float(v0.y << 16) + __uint_as_float(v1.y << 16)
            + __uint_as_float(v2.y << 16) + __uint_as_float(v3.y << 16);
    acc[3] += __uint_as_float(v0.y & 0xffff0000u) + __uint_as_float(v1.y & 0xffff0000u)
            + __uint_as_float(v2.y & 0xffff0000u) + __uint_as_float(v3.y & 0xffff0000u);
    acc[4] += __uint_as_float(v0.z << 16) + __uint_as_float(v1.z << 16)
            + __uint_as_float(v2.z << 16) + __uint_as_float(v3.z << 16);
    acc[5] += __uint_as_float(v0.z & 0xffff0000u) + __uint_as_float(v1.z & 0xffff0000u)
            + __uint_as_float(v2.z & 0xffff0000u) + __uint_as_float(v3.z & 0xffff0000u);
    acc[6] += __uint_as_float(v0.w << 16) + __uint_as_float(v1.w << 16)
            + __uint_as_float(v2.w << 16) + __uint_as_float(v3.w << 16);
    acc[7] += __uint_as_float(v0.w & 0xffff0000u) + __uint_as_float(v1.w & 0xffff0000u)
            + __uint_as_float(v2.w & 0xffff0000u) + __uint_as_float(v3.w & 0xffff0000u);
  }
  for (; i < end; i++) {
    uint4 v0 = *(const uint4*)(h + (size_t)col[i] * D + c);
    acc[0] += __uint_as_float(v0.x << 16);
    acc[1] += __uint_as_float(v0.x & 0xffff0000u);
    acc[2] += __uint_as_float(v0.y << 16);
    acc[3] += __uint_as_float(v0.y & 0xffff0000u);
    acc[4] += __uint_as_float(v0.z << 16);
    acc[5] += __uint_as_float(v0.z & 0xffff0000u);
    acc[6] += __uint_as_float(v0.w << 16);
    acc[7] += __uint_as_float(v0.w & 0xffff0000u);
  }
  float ep = 1.0f + eps[layer];
  uint4 hv = *(const uint4*)(h + (size_t)node * D + c);
  acc[0] = fmaf(ep, __uint_as_float(hv.x << 16), acc[0]);
  acc[1] = fmaf(ep, __uint_as_float(hv.x & 0xffff0000u), acc[1]);
  acc[2] = fmaf(ep, __uint_as_float(hv.y << 16), acc[2]);
  acc[3] = fmaf(ep, __uint_as_float(hv.y & 0xffff0000u), acc[3]);
  acc[4] = fmaf(ep, __uint_as_float(hv.z << 16), acc[4]);
  acc[5] = fmaf(ep, __uint_as_float(hv.z & 0xffff0000u), acc[5]);
  acc[6] = fmaf(ep, __uint_as_float(hv.w << 16), acc[6]);
  acc[7] = fmaf(ep, __uint_as_float(hv.w & 0xffff0000u), acc[7]);
  uint4 o;
  o.x = (unsigned)f2bf(acc[0]) | ((unsigned)f2bf(acc[1]) << 16);
  o.y = (unsigned)f2bf(acc[2]) | ((unsigned)f2bf(acc[3]) << 16);
  o.z = (unsigned)f2bf(acc[4]) | ((unsigned)f2bf(acc[5]) << 16);
  o.w = (unsigned)f2bf(acc[6]) | ((unsigned)f2bf(acc[7]) << 16);
  *(uint4*)(m + (size_t)node * D + c) = o;
}

#define TSTRIDE 136

// shared device helpers for the MFMA kernels
__device__ inline void mfma_gemm(const bf16x8* afr,
    const unsigned short* __restrict__ WT, int l16, int quad, f32x4* acc) {
  #pragma unroll
  for (int t = 0; t < 8; t++) acc[t] = (f32x4){0.f, 0.f, 0.f, 0.f};
  #pragma unroll
  for (int kk = 0; kk < 4; kk++) {
    int koff = kk * 32 + quad * 8;
    #pragma unroll
    for (int t = 0; t < 8; t++) {
      bf16x8 bfr = *(const bf16x8*)(WT + (size_t)(16 * t + l16) * D + koff);
      acc[t] = __builtin_amdgcn_mfma_f32_16x16x32_bf16(afr[kk], bfr, acc[t], 0, 0, 0);
    }
  }
}

__device__ inline void epilogue_to_lds(const f32x4* acc,
    const float4* __restrict__ scales, unsigned short* stile,
    int rl, int l16) {
  #pragma unroll
  for (int t = 0; t < 8; t++) {
    int colc = 16 * t + l16;
    float4 sc = scales[colc];
    #pragma unroll
    for (int reg = 0; reg < 4; reg++) {
      float y = acc[t][reg] * sc.x + sc.y;
      y = fmaxf(y, 0.f);
      y = y * sc.z + sc.w;
      y = fmaxf(y, 0.f);
      stile[(rl + reg) * TSTRIDE + colc] = f2bf(y);
    }
  }
}

// ---------------- encoder MFMA GEMM (fp32 in) ----------------
__global__ __launch_bounds__(256) void k_mfma(const float* __restrict__ in,
    const unsigned short* __restrict__ WT, const float4* __restrict__ scales,
    unsigned short* __restrict__ out, int N) {
  __shared__ unsigned short stile[64 * TSTRIDE];
  int tid = threadIdx.x;
  int wave = tid >> 6, lane = tid & 63;
  int quad = lane >> 4, l16 = lane & 15;
  int rc = min(blockIdx.x * 64 + wave * 16 + l16, N - 1);
  const float* arow = in + (size_t)rc * D;
  bf16x8 afr[4];
  #pragma unroll
  for (int kk = 0; kk < 4; kk++) {
    int koff = kk * 32 + quad * 8;
    float4 lo = *(const float4*)(arow + koff);
    float4 hi = *(const float4*)(arow + koff + 4);
    afr[kk][0] = f2bf(lo.x); afr[kk][1] = f2bf(lo.y);
    afr[kk][2] = f2bf(lo.z); afr[kk][3] = f2bf(lo.w);
    afr[kk][4] = f2bf(hi.x); afr[kk][5] = f2bf(hi.y);
    afr[kk][6] = f2bf(hi.z); afr[kk][7] = f2bf(hi.w);
  }
  f32x4 acc[8];
  mfma_gemm(afr, WT, l16, quad, acc);
  epilogue_to_lds(acc, scales, stile, wave * 16 + quad * 4, l16);
  __syncthreads();
  #pragma unroll
  for (int u = tid; u < 1024; u += 256) {
    int r = u >> 4, cs = (u & 15) * 8;
    int row = blockIdx.x * 64 + r;
    if (row < N)
      *(uint4*)(out + (size_t)row * D + cs) = *(const uint4*)&stile[r * TSTRIDE + cs];
  }
}

// ---------------- fused layer GEMM pair: out = relu(bn_o(relu(bn2( relu(bn1(in@W1))@W2 )))) ----------------
__global__ __launch_bounds__(256) void k_mfma2(const unsigned short* __restrict__ in,
    const unsigned short* __restrict__ WT1, const unsigned short* __restrict__ WT2,
    const float4* __restrict__ sc1, const float4* __restrict__ sc2,
    unsigned short* __restrict__ out, int N) {
  __shared__ unsigned short stile[64 * TSTRIDE];
  int tid = threadIdx.x;
  int wave = tid >> 6, lane = tid & 63;
  int quad = lane >> 4, l16 = lane & 15;
  int rc = min(blockIdx.x * 64 + wave * 16 + l16, N - 1);
  const unsigned short* arow = in + (size_t)rc * D;
  bf16x8 afr[4];
  #pragma unroll
  for (int kk = 0; kk < 4; kk++)
    afr[kk] = *(const bf16x8*)(arow + kk * 32 + quad * 8);

  f32x4 acc[8];
  mfma_gemm(afr, WT1, l16, quad, acc);
  int rl = wave * 16 + quad * 4;
  epilogue_to_lds(acc, sc1, stile, rl, l16);
  __syncthreads();

  // reload A-fragments (intermediate, bf16) from LDS
  const unsigned short* lrow = &stile[(wave * 16 + l16) * TSTRIDE];
  #pragma unroll
  for (int kk = 0; kk < 4; kk++)
    afr[kk] = *(const bf16x8*)(lrow + kk * 32 + quad * 8);
  __syncthreads();   // reads done before stile is overwritten

  mfma_gemm(afr, WT2, l16, quad, acc);
  epilogue_to_lds(acc, sc2, stile, rl, l16);
  __syncthreads();

  #pragma unroll
  for (int u = tid; u < 1024; u += 256) {
    int r = u >> 4, cs = (u & 15) * 8;
    int row = blockIdx.x * 64 + r;
    if (row < N)
      *(uint4*)(out + (size_t)row * D + cs) = *(const uint4*)&stile[r * TSTRIDE + cs];
  }
}

// ---------------- attention MLP: fused LDS-tiled 3-stage GEMM (h bf16) ----------------
__global__ __launch_bounds__(256) void k_attention(const unsigned short* __restrict__ h,
    const float* __restrict__ aW1, const float* __restrict__ ab1,
    const float* __restrict__ aW2, const float* __restrict__ ab2,
    const float* __restrict__ aW3, const float* __restrict__ ab3,
    const float* __restrict__ temp, float* __restrict__ scores, int n) {
  __shared__ float smem[16384];              // 64KB
  float* sH  = smem;                         // [64][128]
  float* sW1 = smem + 8192;                  // [128][64]
  int tid = threadIdx.x;
  int node0 = blockIdx.x * 64;

  for (int i = tid; i < 1024; i += 256) {
    int r = i >> 4, c8 = (i & 15) << 3;
    int nd = min(node0 + r, n - 1);
    uint4 u = *(const uint4*)(h + (size_t)nd * D + c8);
    float* dst = &sH[r * 128 + c8];
    dst[0] = __uint_as_float(u.x << 16); dst[1] = __uint_as_float(u.x & 0xffff0000u);
    dst[2] = __uint_as_float(u.y << 16); dst[3] = __uint_as_float(u.y & 0xffff0000u);
    dst[4] = __uint_as_float(u.z << 16); dst[5] = __uint_as_float(u.z & 0xffff0000u);
    dst[6] = __uint_as_float(u.w << 16); dst[7] = __uint_as_float(u.w & 0xffff0000u);
  }
  for (int i4 = tid; i4 < 2048; i4 += 256)
    *(float4*)&sW1[i4 * 4] = *(const float4*)(aW1 + i4 * 4);
  __syncthreads();

  int tx = tid & 31, ty = tid >> 5;
  int c0 = tx * 2, r0 = ty * 8;
  float acc[8][2];
  #pragma unroll
  for (int i = 0; i < 8; i++) { acc[i][0] = 0.f; acc[i][1] = 0.f; }
  #pragma unroll 4
  for (int kk = 0; kk < 128; kk += 4) {
    float2 b0 = *(float2*)&sW1[(kk + 0) * 64 + c0];
    float2 b1 = *(float2*)&sW1[(kk + 1) * 64 + c0];
    float2 b2 = *(float2*)&sW1[(kk + 2) * 64 + c0];
    float2 b3 = *(float2*)&sW1[(kk + 3) * 64 + c0];
    #pragma unroll
    for (int i = 0; i < 8; i++) {
      float4 a = *(float4*)&sH[(r0 + i) * 128 + kk];
      acc[i][0] += a.x * b0.x + a.y * b1.x + a.z * b2.x + a.w * b3.x;
      acc[i][1] += a.x * b0.y + a.y * b1.y + a.z * b2.y + a.w * b3.y;
    }
  }
  float bb0 = ab1[c0], bb1 = ab1[c0 + 1];
  __syncthreads();

  float* a1B = smem;                          // [64][68]
  float* sW2 = smem + 8192;                   // [64][32]
  float* a2B = smem + 8192 + 2048;            // [64][36]
  #pragma unroll
  for (int i = 0; i < 8; i++) {
    float v0 = acc[i][0] + bb0; v0 = fmaxf(v0, 0.2f * v0);
    float v1 = acc[i][1] + bb1; v1 = fmaxf(v1, 0.2f * v1);
    *(float2*)&a1B[(r0 + i) * 68 + c0] = make_float2(v0, v1);
  }
  for (int i4 = tid; i4 < 512; i4 += 256)
    *(float4*)&sW2[i4 * 4] = *(const float4*)(aW2 + i4 * 4);
  __syncthreads();

  int tx2 = tid & 7, ty2 = tid >> 3;
  int cc0 = tx2 * 4, rr0 = ty2 * 2;
  float acc2[2][4];
  #pragma unroll
  for (int i = 0; i < 2; i++)
    #pragma unroll
    for (int j = 0; j < 4; j++) acc2[i][j] = 0.f;
  #pragma unroll 4
  for (int k = 0; k < 64; k += 4) {
    float4 b0 = *(float4*)&sW2[(k + 0) * 32 + cc0];
    float4 b1 = *(float4*)&sW2[(k + 1) * 32 + cc0];
    float4 b2 = *(float4*)&sW2[(k + 2) * 32 + cc0];
    float4 b3 = *(float4*)&sW2[(k + 3) * 32 + cc0];
    #pragma unroll
    for (int i = 0; i < 2; i++) {
      float4 a = *(float4*)&a1B[(rr0 + i) * 68 + k];
      acc2[i][0] += a.x * b0.x + a.y * b1.x + a.z * b2.x + a.w * b3.x;
      acc2[i][1] += a.x * b0.y + a.y * b1.y + a.z * b2.y + a.w * b3.y;
      acc2[i][2] += a.x * b0.z + a.y * b1.z + a.z * b2.z + a.w * b3.z;
      acc2[i][3] += a.x * b0.w + a.y * b1.w + a.z * b2.w + a.w * b3.w;
    }
  }
  float4 bias2 = *(const float4*)(ab2 + cc0);
  #pragma unroll
  for (int i = 0; i < 2; i++) {
    float4 o;
    o.x = acc2[i][0] + bias2.x; o.x = fmaxf(o.x, 0.2f * o.x);
    o.y = acc2[i][1] + bias2.y; o.y = fmaxf(o.y, 0.2f * o.y);
    o.z = acc2[i][2] + bias2.z; o.z = fmaxf(o.z, 0.2f * o.z);
    o.w = acc2[i][3] + bias2.w; o.w = fmaxf(o.w, 0.2f * o.w);
    *(float4*)&a2B[(rr0 + i) * 36 + cc0] = o;
  }
  __syncthreads();

  if (tid < 64) {
    float s = ab3[0];
    #pragma unroll 8
    for (int k = 0; k < 32; k++) s = fmaf(a2B[tid * 36 + k], aW3[k], s);
    s = fminf(fmaxf(s, -10.f), 10.f);
    int node = node0 + tid;
    if (node < n) scores[node] = 1.0f / (1.0f + __expf(-s * temp[0]));
  }
}

// ---------------- attention-weighted pool (batch sorted, h bf16) ----------------
__global__ __launch_bounds__(128) void k_pool(const unsigned short* __restrict__ h,
    const float* __restrict__ scores, const int* __restrict__ batch,
    float* __restrict__ ge, int n) {
  const int NPB = 32;
  int f = threadIdx.x;
  int n0 = blockIdx.x * NPB;
  if (n0 >= n) return;
  int nend = min(n0 + NPB, n);
  float acc = 0.f;
  int cur = batch[n0];
  for (int i = n0; i < nend; i++) {
    int b = batch[i];
    if (b != cur) {
      atomicAdd(&ge[(size_t)cur * D + f], acc);
      acc = 0.f;
      cur = b;
    }
    acc = fmaf(bf2f(h[(size_t)i * D + f]), scores[i], acc);
  }
  atomicAdd(&ge[(size_t)cur * D + f], acc);
}

// ---------------- classifier: block per graph ----------------
__global__ __launch_bounds__(128) void k_classifier(const float* __restrict__ ge,
    const float* __restrict__ cW1, const float* __restrict__ cb1,
    const float* __restrict__ cW2, const float* __restrict__ cb2,
    float* __restrict__ logits, int B) {
  __shared__ float sg[D];
  __shared__ float st[D];
  int g = blockIdx.x;
  int tid = threadIdx.x;
  sg[tid] = ge[(size_t)g * D + tid];
  __syncthreads();
  float a = cb1[tid];
  #pragma unroll 8
  for (int k = 0; k < D; k++) a = fmaf(sg[k], cW1[k * D + tid], a);
  st[tid] = fmaxf(a, 0.f);
  __syncthreads();
  if (tid < 3) {
    float a2 = cb2[tid];
    for (int k = 0; k < D; k++) a2 = fmaf(st[k], cW2[k * 3 + tid], a2);
    logits[(size_t)g * 3 + tid] = a2;
  }
}

extern "C" void kernel_launch(void* const* d_in, const int* in_sizes, int n_in,
                              void* d_out, int out_size, void* d_ws, size_t ws_size,
                              hipStream_t stream) {
  const float* x     = (const float*)d_in[0];
  const int*   ei    = (const int*)d_in[1];
  const int*   batch = (const int*)d_in[2];
  const float* enc_W = (const float*)d_in[3];
  const float* enc_b = (const float*)d_in[4];
  const float* W1    = (const float*)d_in[5];
  const float* b1    = (const float*)d_in[6];
  const float* g1    = (const float*)d_in[7];
  const float* beta1 = (const float*)d_in[8];
  const float* rm1   = (const float*)d_in[9];
  const float* rv1   = (const float*)d_in[10];
  const float* W2    = (const float*)d_in[11];
  const float* b2    = (const float*)d_in[12];
  const float* g2    = (const float*)d_in[13];
  const float* beta2 = (const float*)d_in[14];
  const float* rm2   = (const float*)d_in[15];
  const float* rv2   = (const float*)d_in[16];
  const float* eps   = (const float*)d_in[17];
  const float* og    = (const float*)d_in[18];
  const float* ob    = (const float*)d_in[19];
  const float* orm   = (const float*)d_in[20];
  const float* orv   = (const float*)d_in[21];
  const float* aW1   = (const float*)d_in[22];
  const float* ab1   = (const float*)d_in[23];
  const float* aW2   = (const float*)d_in[24];
  const float* ab2   = (const float*)d_in[25];
  const float* aW3   = (const float*)d_in[26];
  const float* ab3   = (const float*)d_in[27];
  const float* temp  = (const float*)d_in[28];
  const float* cW1   = (const float*)d_in[29];
  const float* cb1   = (const float*)d_in[30];
  const float* cW2   = (const float*)d_in[31];
  const float* cb2   = (const float*)d_in[32];

  int N = in_sizes[0] / D;
  int E = in_sizes[1] / 2;
  int B = (out_size - N) / (3 + D);
  int nb = (N + 511) >> BSH;     // buckets of 512 nodes (<=128 for N<=65536)

  // workspace layout
  unsigned short* hbuf = (unsigned short*)d_ws;
  unsigned short* mbuf = hbuf + (size_t)N * D;
  int* row_ptr = (int*)(mbuf + (size_t)N * D);
  int* colidx  = row_ptr + N + 1;
  int* bcnt    = colidx + E;            // nb*BPAD
  int* boff    = bcnt + nb * BPAD;      // nb+1
  int* bcur    = boff + nb + 1;         // nb*BPAD
  uintptr_t p = (uintptr_t)(bcur + nb * BPAD);
  p = (p + 15) & ~(uintptr_t)15;
  unsigned* pairs = (unsigned*)p;       // E packed records
  unsigned short* WT = (unsigned short*)(pairs + E);   // 7*128*128 bf16
  float4* sc_all = (float4*)(WT + 7 * D * D);          // 7*128 float4

  float* logits = (float*)d_out;
  float* ge     = logits + (size_t)B * 3;
  float* scores = ge + (size_t)B * D;

  k_prep_w<<<7, 256, 0, stream>>>(enc_W, W1, W2, WT);
  k_scales<<<7, 128, 0, stream>>>(enc_b, b1, g1, beta1, rm1, rv1,
                                  b2, g2, beta2, rm2, rv2, og, ob, orm, orv, sc_all);

  // bucketed CSR build (packed 4B records, LDS-staged scatter)
  hipMemsetAsync(bcnt, 0, (size_t)nb * BPAD * sizeof(int), stream);
  k_bhist<<<256, 256, 0, stream>>>(ei, bcnt, E, nb);
  k_bktscan<<<1, 128, 0, stream>>>(bcnt, boff, bcur, row_ptr, nb, N, E);
  k_bscatter<<<(E + 2047) / 2048, 256, 0, stream>>>(ei, bcur, pairs, E, nb);
  k_bplace<<<nb, 256, 0, stream>>>(pairs, boff, row_ptr, colidx, N);

  int gblocks = (N + 63) / 64;
  // encoder: h = relu(x@enc_W + enc_b)
  k_mfma<<<gblocks, 256, 0, stream>>>(x, WT, sc_all, hbuf, N);

  for (int l = 0; l < 3; l++) {
    k_aggregate<<<(N + 15) / 16, 256, 0, stream>>>(hbuf, row_ptr, colidx, eps, l, mbuf, N);
    // fused: h = relu(bn_o(relu(bn2( relu(bn1(m@W1))@W2 ))))
    k_mfma2<<<gblocks, 256, 0, stream>>>(mbuf,
        WT + (size_t)(1 + 2 * l) * D * D, WT + (size_t)(2 + 2 * l) * D * D,
        sc_all + (1 + 2 * l) * D, sc_all + (2 + 2 * l) * D, hbuf, N);
  }

  k_attention<<<gblocks, 256, 0, stream>>>(hbuf, aW1, ab1, aW2, ab2, aW3, ab3,
                                           temp, scores, N);
  hipMemsetAsync(ge, 0, (size_t)B * D * sizeof(float), stream);
  k_pool<<<(N + 31) / 32, 128, 0, stream>>>(hbuf, scores, batch, ge, N);
  k_classifier<<<B, 128, 0, stream>>>(ge, cW1, cb1, cW2, cb2, logits, B);
}

// Round 11
// 461.310 us; speedup vs baseline: 2.4439x; 1.0460x over previous
//
#include <hip/hip_runtime.h>
#include <math.h>

#define D 128
#define BSH 9                    // bucket = dst >> 9 (512 nodes/bucket)
#define NBMAX 128                // max buckets (N <= 65536)
#define SCAP 64                  // per-bucket LDS staging capacity
#define BPAD 16                  // bucket cursors padded to 64B lines

typedef short bf16x8 __attribute__((ext_vector_type(8)));
typedef float f32x4 __attribute__((ext_vector_type(4)));

__device__ inline unsigned short f2bf(float f) {  // RNE fp32->bf16
  unsigned u = __float_as_uint(f);
  return (unsigned short)((u + 0x7fffu + ((u >> 16) & 1u)) >> 16);
}
__device__ inline float bf2f(unsigned short b) {
  return __uint_as_float(((unsigned)b) << 16);
}

// ---------------- bucketed CSR build (records packed: src<<16 | dst) ----------------
__global__ __launch_bounds__(256) void k_bhist(const int* __restrict__ ei,
    int* __restrict__ bcnt, int E, int nb) {
  __shared__ int h[NBMAX];
  for (int i = threadIdx.x; i < NBMAX; i += 256) h[i] = 0;
  __syncthreads();
  for (int e = blockIdx.x * 256 + threadIdx.x; e < E; e += gridDim.x * 256)
    atomicAdd(&h[ei[E + e] >> BSH], 1);
  __syncthreads();
  for (int i = threadIdx.x; i < nb; i += 256)
    if (h[i]) atomicAdd(&bcnt[i * BPAD], h[i]);
}

__global__ __launch_bounds__(128) void k_bktscan(const int* __restrict__ bcnt,
    int* __restrict__ boff, int* __restrict__ bcur, int* __restrict__ row_ptr,
    int nb, int N, int E) {
  int tid = threadIdx.x;
  int v = (tid < nb) ? bcnt[tid * BPAD] : 0;
  int lane = tid & 63, w = tid >> 6;
  int incl = v;
  #pragma unroll
  for (int off = 1; off < 64; off <<= 1) {
    int t = __shfl_up(incl, off, 64);
    if (lane >= off) incl += t;
  }
  __shared__ int ws[2];
  if (lane == 63) ws[w] = incl;
  __syncthreads();
  int excl = incl - v + (w ? ws[0] : 0);
  if (tid < nb) { boff[tid] = excl; bcur[tid * BPAD] = excl; }
  if (tid == nb - 1) boff[nb] = excl + v;
  if (tid == 0) row_ptr[N] = E;
}

__global__ __launch_bounds__(256) void k_bscatter(const int* __restrict__ ei,
    int* __restrict__ bcur, unsigned* __restrict__ pairs, int E, int nb) {
  __shared__ unsigned stage[NBMAX * SCAP];   // 32KB
  __shared__ int scnt[NBMAX];
  __shared__ int sbase[NBMAX];
  __shared__ int pref[NBMAX + 1];
  int tid = threadIdx.x;
  int c0 = blockIdx.x * 2048;
  if (c0 >= E) return;
  int cend = min(c0 + 2048, E);
  for (int i = tid; i < NBMAX; i += 256) scnt[i] = 0;
  __syncthreads();
  for (int e = c0 + tid; e < cend; e += 256) {
    int src = ei[e], dst = ei[E + e];
    unsigned rec = ((unsigned)src << 16) | (unsigned)dst;   // N <= 65536
    int b = dst >> BSH;
    int pos = atomicAdd(&scnt[b], 1);
    if (pos < SCAP) stage[b * SCAP + pos] = rec;
    else {
      int gp = atomicAdd(&bcur[b * BPAD], 1);
      pairs[gp] = rec;
    }
  }
  __syncthreads();
  for (int b = tid; b < nb; b += 256) {
    int cnt = min(scnt[b], SCAP);
    sbase[b] = cnt ? atomicAdd(&bcur[b * BPAD], cnt) : 0;
  }
  __syncthreads();
  if (tid == 0) {          // serial scan of <=128 ints (trivial)
    int r = 0;
    for (int b = 0; b < nb; b++) { pref[b] = r; r += min(scnt[b], SCAP); }
    pref[nb] = r;
  }
  __syncthreads();
  int T = pref[nb];
  for (int j = tid; j < T; j += 256) {   // flat parallel copy, binary search bucket
    int lo = 0, hi = nb;
    while (hi - lo > 1) { int mid = (lo + hi) >> 1; if (pref[mid] <= j) lo = mid; else hi = mid; }
    int i = j - pref[lo];
    pairs[sbase[lo] + i] = stage[lo * SCAP + i];
  }
}

__global__ __launch_bounds__(256) void k_bplace(const unsigned* __restrict__ pairs,
    const int* __restrict__ boff, int* __restrict__ row_ptr,
    int* __restrict__ col, int N) {
  int b = blockIdx.x, tid = threadIdx.x;
  int n0 = b << BSH;
  int nn = min(512, N - n0);
  int beg = boff[b], end = boff[b + 1];
  int cnt = end - beg;
  __shared__ int hist[512];
  __shared__ int cursor[512];
  __shared__ int wt[4];
  for (int i = tid; i < 512; i += 256) hist[i] = 0;
  __syncthreads();
  for (int i = tid; i < cnt; i += 256)
    atomicAdd(&hist[pairs[beg + i] & 511], 1);
  __syncthreads();
  int v0 = hist[2 * tid], v1 = hist[2 * tid + 1];
  int s = v0 + v1;
  int lane = tid & 63, w = tid >> 6;
  int incl = s;
  #pragma unroll
  for (int off = 1; off < 64; off <<= 1) {
    int t = __shfl_up(incl, off, 64);
    if (lane >= off) incl += t;
  }
  if (lane == 63) wt[w] = incl;
  __syncthreads();
  if (tid == 0) {
    int r = 0;
    #pragma unroll
    for (int i = 0; i < 4; i++) { int t = wt[i]; wt[i] = r; r += t; }
  }
  __syncthreads();
  int excl = wt[w] + incl - s;
  cursor[2 * tid] = excl;
  cursor[2 * tid + 1] = excl + v0;
  if (2 * tid < nn)     row_ptr[n0 + 2 * tid] = beg + excl;
  if (2 * tid + 1 < nn) row_ptr[n0 + 2 * tid + 1] = beg + excl + v0;
  __syncthreads();
  for (int i = tid; i < cnt; i += 256) {
    unsigned u = pairs[beg + i];
    int p = atomicAdd(&cursor[u & 511], 1);
    col[beg + p] = (int)(u >> 16);
  }
}

// ---------------- weight prep: WT[n][k] = bf16(W[k][n]) for 7 matrices ----------------
__global__ __launch_bounds__(256) void k_prep_w(const float* __restrict__ encW,
    const float* __restrict__ W1, const float* __restrict__ W2,
    unsigned short* __restrict__ WT) {
  int b = blockIdx.x;
  const float* src;
  if (b == 0) src = encW;
  else if (b & 1) src = W1 + (size_t)((b - 1) / 2) * D * D;
  else src = W2 + (size_t)(b / 2 - 1) * D * D;
  unsigned short* dst = WT + (size_t)b * D * D;
  for (int e = threadIdx.x; e < D * D; e += 256) {
    int n = e >> 7, k = e & 127;
    dst[n * D + k] = f2bf(src[k * D + n]);
  }
}

// ---------------- fused epilogue scales ----------------
__global__ __launch_bounds__(128) void k_scales(
    const float* __restrict__ enc_b,
    const float* __restrict__ b1, const float* __restrict__ g1,
    const float* __restrict__ be1, const float* __restrict__ rm1, const float* __restrict__ rv1,
    const float* __restrict__ b2, const float* __restrict__ g2,
    const float* __restrict__ be2, const float* __restrict__ rm2, const float* __restrict__ rv2,
    const float* __restrict__ og, const float* __restrict__ ob,
    const float* __restrict__ orm, const float* __restrict__ orv,
    float4* __restrict__ scales) {
  int g = blockIdx.x, c = threadIdx.x;
  float s1 = 1.f, t1 = 0.f, s2 = 1.f, t2 = 0.f;
  if (g == 0) {
    t1 = enc_b[c];
  } else if (g & 1) {
    int l = (g - 1) / 2, i = l * D + c;
    float inv = rsqrtf(rv1[i] + 1e-5f);
    s1 = g1[i] * inv;
    t1 = (b1[i] - rm1[i]) * s1 + be1[i];
  } else {
    int l = g / 2 - 1, i = l * D + c;
    float inv = rsqrtf(rv2[i] + 1e-5f);
    s1 = g2[i] * inv;
    t1 = (b2[i] - rm2[i]) * s1 + be2[i];
    float inv2 = rsqrtf(orv[i] + 1e-5f);
    s2 = og[i] * inv2;
    t2 = ob[i] - orm[i] * s2;
  }
  scales[g * D + c] = make_float4(s1, t1, s2, t2);
}

#define TSTRIDE 136

// shared device helpers for the MFMA kernels
__device__ inline void mfma_gemm(const bf16x8* afr,
    const unsigned short* __restrict__ WT, int l16, int quad, f32x4* acc) {
  #pragma unroll
  for (int t = 0; t < 8; t++) acc[t] = (f32x4){0.f, 0.f, 0.f, 0.f};
  #pragma unroll
  for (int kk = 0; kk < 4; kk++) {
    int koff = kk * 32 + quad * 8;
    #pragma unroll
    for (int t = 0; t < 8; t++) {
      bf16x8 bfr = *(const bf16x8*)(WT + (size_t)(16 * t + l16) * D + koff);
      acc[t] = __builtin_amdgcn_mfma_f32_16x16x32_bf16(afr[kk], bfr, acc[t], 0, 0, 0);
    }
  }
}

__device__ inline void epilogue_to_lds(const f32x4* acc,
    const float4* __restrict__ scales, unsigned short* stile,
    int rl, int l16) {
  #pragma unroll
  for (int t = 0; t < 8; t++) {
    int colc = 16 * t + l16;
    float4 sc = scales[colc];
    #pragma unroll
    for (int reg = 0; reg < 4; reg++) {
      float y = acc[t][reg] * sc.x + sc.y;
      y = fmaxf(y, 0.f);
      y = y * sc.z + sc.w;
      y = fmaxf(y, 0.f);
      stile[(rl + reg) * TSTRIDE + colc] = f2bf(y);
    }
  }
}

// ---------------- encoder MFMA GEMM (fp32 in) ----------------
__global__ __launch_bounds__(256) void k_mfma(const float* __restrict__ in,
    const unsigned short* __restrict__ WT, const float4* __restrict__ scales,
    unsigned short* __restrict__ out, int N) {
  __shared__ unsigned short stile[64 * TSTRIDE];
  int tid = threadIdx.x;
  int wave = tid >> 6, lane = tid & 63;
  int quad = lane >> 4, l16 = lane & 15;
  int rc = min(blockIdx.x * 64 + wave * 16 + l16, N - 1);
  const float* arow = in + (size_t)rc * D;
  bf16x8 afr[4];
  #pragma unroll
  for (int kk = 0; kk < 4; kk++) {
    int koff = kk * 32 + quad * 8;
    float4 lo = *(const float4*)(arow + koff);
    float4 hi = *(const float4*)(arow + koff + 4);
    afr[kk][0] = f2bf(lo.x); afr[kk][1] = f2bf(lo.y);
    afr[kk][2] = f2bf(lo.z); afr[kk][3] = f2bf(lo.w);
    afr[kk][4] = f2bf(hi.x); afr[kk][5] = f2bf(hi.y);
    afr[kk][6] = f2bf(hi.z); afr[kk][7] = f2bf(hi.w);
  }
  f32x4 acc[8];
  mfma_gemm(afr, WT, l16, quad, acc);
  epilogue_to_lds(acc, scales, stile, wave * 16 + quad * 4, l16);
  __syncthreads();
  #pragma unroll
  for (int u = tid; u < 1024; u += 256) {
    int r = u >> 4, cs = (u & 15) * 8;
    int row = blockIdx.x * 64 + r;
    if (row < N)
      *(uint4*)(out + (size_t)row * D + cs) = *(const uint4*)&stile[r * TSTRIDE + cs];
  }
}

// ---------------- fused GIN layer: aggregate + GEMM pair, m never hits global ----------------
// out = relu(bn_o(relu(bn2( relu(bn1( ((1+eps)h + sum h[src]) @W1 ))@W2 ))))
// NOT in-place: reads all of h (random gather), writes `out` (ping-pong buffer).
__global__ __launch_bounds__(256) void k_layer(const unsigned short* __restrict__ h,
    const int* __restrict__ row_ptr, const int* __restrict__ col,
    const float* __restrict__ eps, int layer,
    const unsigned short* __restrict__ WT1, const unsigned short* __restrict__ WT2,
    const float4* __restrict__ sc1, const float4* __restrict__ sc2,
    unsigned short* __restrict__ out, int N) {
  __shared__ unsigned short stile[64 * TSTRIDE];
  int tid = threadIdx.x;
  float ep = 1.0f + eps[layer];
  int rloc = tid >> 4;           // 16 lanes per node
  int c = (tid & 15) << 3;       // 8 bf16 cols per lane (16B loads)

  // phase A: aggregate 64 nodes (4 sub-batches of 16) -> stile (bf16 m-tile)
  for (int sub = 0; sub < 4; sub++) {
    int nl = sub * 16 + rloc;
    int node = blockIdx.x * 64 + nl;
    float acc[8];
    #pragma unroll
    for (int j = 0; j < 8; j++) acc[j] = 0.f;
    if (node < N) {
      int beg = row_ptr[node], end = row_ptr[node + 1];
      int i = beg;
      for (; i + 3 < end; i += 4) {
        int s0 = col[i], s1 = col[i + 1], s2 = col[i + 2], s3 = col[i + 3];
        uint4 v0 = *(const uint4*)(h + (size_t)s0 * D + c);
        uint4 v1 = *(const uint4*)(h + (size_t)s1 * D + c);
        uint4 v2 = *(const uint4*)(h + (size_t)s2 * D + c);
        uint4 v3 = *(const uint4*)(h + (size_t)s3 * D + c);
        acc[0] += __uint_as_float(v0.x << 16) + __uint_as_float(v1.x << 16)
                + __uint_as_float(v2.x << 16) + __uint_as_float(v3.x << 16);
        acc[1] += __uint_as_float(v0.x & 0xffff0000u) + __uint_as_float(v1.x & 0xffff0000u)
                + __uint_as_float(v2.x & 0xffff0000u) + __uint_as_float(v3.x & 0xffff0000u);
        acc[2] += __uint_as_float(v0.y << 16) + __uint_as_float(v1.y << 16)
                + __uint_as_float(v2.y << 16) + __uint_as_float(v3.y << 16);
        acc[3] += __uint_as_float(v0.y & 0xffff0000u) + __uint_as_float(v1.y & 0xffff0000u)
                + __uint_as_float(v2.y & 0xffff0000u) + __uint_as_float(v3.y & 0xffff0000u);
        acc[4] += __uint_as_float(v0.z << 16) + __uint_as_float(v1.z << 16)
                + __uint_as_float(v2.z << 16) + __uint_as_float(v3.z << 16);
        acc[5] += __uint_as_float(v0.z & 0xffff0000u) + __uint_as_float(v1.z & 0xffff0000u)
                + __uint_as_float(v2.z & 0xffff0000u) + __uint_as_float(v3.z & 0xffff0000u);
        acc[6] += __uint_as_float(v0.w << 16) + __uint_as_float(v1.w << 16)
                + __uint_as_float(v2.w << 16) + __uint_as_float(v3.w << 16);
        acc[7] += __uint_as_float(v0.w & 0xffff0000u) + __uint_as_float(v1.w & 0xffff0000u)
                + __uint_as_float(v2.w & 0xffff0000u) + __uint_as_float(v3.w & 0xffff0000u);
      }
      for (; i < end; i++) {
        uint4 v0 = *(const uint4*)(h + (size_t)col[i] * D + c);
        acc[0] += __uint_as_float(v0.x << 16);
        acc[1] += __uint_as_float(v0.x & 0xffff0000u);
        acc[2] += __uint_as_float(v0.y << 16);
        acc[3] += __uint_as_float(v0.y & 0xffff0000u);
        acc[4] += __uint_as_float(v0.z << 16);
        acc[5] += __uint_as_float(v0.z & 0xffff0000u);
        acc[6] += __uint_as_float(v0.w << 16);
        acc[7] += __uint_as_float(v0.w & 0xffff0000u);
      }
      uint4 hv = *(const uint4*)(h + (size_t)node * D + c);
      acc[0] = fmaf(ep, __uint_as_float(hv.x << 16), acc[0]);
      acc[1] = fmaf(ep, __uint_as_float(hv.x & 0xffff0000u), acc[1]);
      acc[2] = fmaf(ep, __uint_as_float(hv.y << 16), acc[2]);
      acc[3] = fmaf(ep, __uint_as_float(hv.y & 0xffff0000u), acc[3]);
      acc[4] = fmaf(ep, __uint_as_float(hv.z << 16), acc[4]);
      acc[5] = fmaf(ep, __uint_as_float(hv.z & 0xffff0000u), acc[5]);
      acc[6] = fmaf(ep, __uint_as_float(hv.w << 16), acc[6]);
      acc[7] = fmaf(ep, __uint_as_float(hv.w & 0xffff0000u), acc[7]);
    }
    uint4 o;
    o.x = (unsigned)f2bf(acc[0]) | ((unsigned)f2bf(acc[1]) << 16);
    o.y = (unsigned)f2bf(acc[2]) | ((unsigned)f2bf(acc[3]) << 16);
    o.z = (unsigned)f2bf(acc[4]) | ((unsigned)f2bf(acc[5]) << 16);
    o.w = (unsigned)f2bf(acc[6]) | ((unsigned)f2bf(acc[7]) << 16);
    *(uint4*)&stile[nl * TSTRIDE + c] = o;
  }
  __syncthreads();

  // phase B: GEMM pair, A-fragments from stile
  int wave = tid >> 6, lane = tid & 63;
  int quad = lane >> 4, l16 = lane & 15;
  int rl = wave * 16 + quad * 4;
  bf16x8 afr[4];
  const unsigned short* lrow = &stile[(wave * 16 + l16) * TSTRIDE];
  #pragma unroll
  for (int kk = 0; kk < 4; kk++)
    afr[kk] = *(const bf16x8*)(lrow + kk * 32 + quad * 8);
  __syncthreads();   // all reads done before epilogue overwrites

  f32x4 acc[8];
  mfma_gemm(afr, WT1, l16, quad, acc);
  epilogue_to_lds(acc, sc1, stile, rl, l16);
  __syncthreads();

  #pragma unroll
  for (int kk = 0; kk < 4; kk++)
    afr[kk] = *(const bf16x8*)(lrow + kk * 32 + quad * 8);
  __syncthreads();

  mfma_gemm(afr, WT2, l16, quad, acc);
  epilogue_to_lds(acc, sc2, stile, rl, l16);
  __syncthreads();

  #pragma unroll
  for (int u = tid; u < 1024; u += 256) {
    int r = u >> 4, cs = (u & 15) * 8;
    int row = blockIdx.x * 64 + r;
    if (row < N)
      *(uint4*)(out + (size_t)row * D + cs) = *(const uint4*)&stile[r * TSTRIDE + cs];
  }
}

// ---------------- attention MLP: fused LDS-tiled 3-stage GEMM (h bf16) ----------------
__global__ __launch_bounds__(256) void k_attention(const unsigned short* __restrict__ h,
    const float* __restrict__ aW1, const float* __restrict__ ab1,
    const float* __restrict__ aW2, const float* __restrict__ ab2,
    const float* __restrict__ aW3, const float* __restrict__ ab3,
    const float* __restrict__ temp, float* __restrict__ scores, int n) {
  __shared__ float smem[16384];              // 64KB
  float* sH  = smem;                         // [64][128]
  float* sW1 = smem + 8192;                  // [128][64]
  int tid = threadIdx.x;
  int node0 = blockIdx.x * 64;

  for (int i = tid; i < 1024; i += 256) {
    int r = i >> 4, c8 = (i & 15) << 3;
    int nd = min(node0 + r, n - 1);
    uint4 u = *(const uint4*)(h + (size_t)nd * D + c8);
    float* dst = &sH[r * 128 + c8];
    dst[0] = __uint_as_float(u.x << 16); dst[1] = __uint_as_float(u.x & 0xffff0000u);
    dst[2] = __uint_as_float(u.y << 16); dst[3] = __uint_as_float(u.y & 0xffff0000u);
    dst[4] = __uint_as_float(u.z << 16); dst[5] = __uint_as_float(u.z & 0xffff0000u);
    dst[6] = __uint_as_float(u.w << 16); dst[7] = __uint_as_float(u.w & 0xffff0000u);
  }
  for (int i4 = tid; i4 < 2048; i4 += 256)
    *(float4*)&sW1[i4 * 4] = *(const float4*)(aW1 + i4 * 4);
  __syncthreads();

  int tx = tid & 31, ty = tid >> 5;
  int c0 = tx * 2, r0 = ty * 8;
  float acc[8][2];
  #pragma unroll
  for (int i = 0; i < 8; i++) { acc[i][0] = 0.f; acc[i][1] = 0.f; }
  #pragma unroll 4
  for (int kk = 0; kk < 128; kk += 4) {
    float2 b0 = *(float2*)&sW1[(kk + 0) * 64 + c0];
    float2 b1 = *(float2*)&sW1[(kk + 1) * 64 + c0];
    float2 b2 = *(float2*)&sW1[(kk + 2) * 64 + c0];
    float2 b3 = *(float2*)&sW1[(kk + 3) * 64 + c0];
    #pragma unroll
    for (int i = 0; i < 8; i++) {
      float4 a = *(float4*)&sH[(r0 + i) * 128 + kk];
      acc[i][0] += a.x * b0.x + a.y * b1.x + a.z * b2.x + a.w * b3.x;
      acc[i][1] += a.x * b0.y + a.y * b1.y + a.z * b2.y + a.w * b3.y;
    }
  }
  float bb0 = ab1[c0], bb1 = ab1[c0 + 1];
  __syncthreads();

  float* a1B = smem;                          // [64][68]
  float* sW2 = smem + 8192;                   // [64][32]
  float* a2B = smem + 8192 + 2048;            // [64][36]
  #pragma unroll
  for (int i = 0; i < 8; i++) {
    float v0 = acc[i][0] + bb0; v0 = fmaxf(v0, 0.2f * v0);
    float v1 = acc[i][1] + bb1; v1 = fmaxf(v1, 0.2f * v1);
    *(float2*)&a1B[(r0 + i) * 68 + c0] = make_float2(v0, v1);
  }
  for (int i4 = tid; i4 < 512; i4 += 256)
    *(float4*)&sW2[i4 * 4] = *(const float4*)(aW2 + i4 * 4);
  __syncthreads();

  int tx2 = tid & 7, ty2 = tid >> 3;
  int cc0 = tx2 * 4, rr0 = ty2 * 2;
  float acc2[2][4];
  #pragma unroll
  for (int i = 0; i < 2; i++)
    #pragma unroll
    for (int j = 0; j < 4; j++) acc2[i][j] = 0.f;
  #pragma unroll 4
  for (int k = 0; k < 64; k += 4) {
    float4 b0 = *(float4*)&sW2[(k + 0) * 32 + cc0];
    float4 b1 = *(float4*)&sW2[(k + 1) * 32 + cc0];
    float4 b2 = *(float4*)&sW2[(k + 2) * 32 + cc0];
    float4 b3 = *(float4*)&sW2[(k + 3) * 32 + cc0];
    #pragma unroll
    for (int i = 0; i < 2; i++) {
      float4 a = *(float4*)&a1B[(rr0 + i) * 68 + k];
      acc2[i][0] += a.x * b0.x + a.y * b1.x + a.z * b2.x + a.w * b3.x;
      acc2[i][1] += a.x * b0.y + a.y * b1.y + a.z * b2.y + a.w * b3.y;
      acc2[i][2] += a.x * b0.z + a.y * b1.z + a.z * b2.z + a.w * b3.z;
      acc2[i][3] += a.x * b0.w + a.y * b1.w + a.z * b2.w + a.w * b3.w;
    }
  }
  float4 bias2 = *(const float4*)(ab2 + cc0);
  #pragma unroll
  for (int i = 0; i < 2; i++) {
    float4 o;
    o.x = acc2[i][0] + bias2.x; o.x = fmaxf(o.x, 0.2f * o.x);
    o.y = acc2[i][1] + bias2.y; o.y = fmaxf(o.y, 0.2f * o.y);
    o.z = acc2[i][2] + bias2.z; o.z = fmaxf(o.z, 0.2f * o.z);
    o.w = acc2[i][3] + bias2.w; o.w = fmaxf(o.w, 0.2f * o.w);
    *(float4*)&a2B[(rr0 + i) * 36 + cc0] = o;
  }
  __syncthreads();

  if (tid < 64) {
    float s = ab3[0];
    #pragma unroll 8
    for (int k = 0; k < 32; k++) s = fmaf(a2B[tid * 36 + k], aW3[k], s);
    s = fminf(fmaxf(s, -10.f), 10.f);
    int node = node0 + tid;
    if (node < n) scores[node] = 1.0f / (1.0f + __expf(-s * temp[0]));
  }
}

// ---------------- attention-weighted pool (batch sorted, h bf16) ----------------
__global__ __launch_bounds__(128) void k_pool(const unsigned short* __restrict__ h,
    const float* __restrict__ scores, const int* __restrict__ batch,
    float* __restrict__ ge, int n) {
  const int NPB = 32;
  int f = threadIdx.x;
  int n0 = blockIdx.x * NPB;
  if (n0 >= n) return;
  int nend = min(n0 + NPB, n);
  float acc = 0.f;
  int cur = batch[n0];
  for (int i = n0; i < nend; i++) {
    int b = batch[i];
    if (b != cur) {
      atomicAdd(&ge[(size_t)cur * D + f], acc);
      acc = 0.f;
      cur = b;
    }
    acc = fmaf(bf2f(h[(size_t)i * D + f]), scores[i], acc);
  }
  atomicAdd(&ge[(size_t)cur * D + f], acc);
}

// ---------------- classifier: block per graph ----------------
__global__ __launch_bounds__(128) void k_classifier(const float* __restrict__ ge,
    const float* __restrict__ cW1, const float* __restrict__ cb1,
    const float* __restrict__ cW2, const float* __restrict__ cb2,
    float* __restrict__ logits, int B) {
  __shared__ float sg[D];
  __shared__ float st[D];
  int g = blockIdx.x;
  int tid = threadIdx.x;
  sg[tid] = ge[(size_t)g * D + tid];
  __syncthreads();
  float a = cb1[tid];
  #pragma unroll 8
  for (int k = 0; k < D; k++) a = fmaf(sg[k], cW1[k * D + tid], a);
  st[tid] = fmaxf(a, 0.f);
  __syncthreads();
  if (tid < 3) {
    float a2 = cb2[tid];
    for (int k = 0; k < D; k++) a2 = fmaf(st[k], cW2[k * 3 + tid], a2);
    logits[(size_t)g * 3 + tid] = a2;
  }
}

extern "C" void kernel_launch(void* const* d_in, const int* in_sizes, int n_in,
                              void* d_out, int out_size, void* d_ws, size_t ws_size,
                              hipStream_t stream) {
  const float* x     = (const float*)d_in[0];
  const int*   ei    = (const int*)d_in[1];
  const int*   batch = (const int*)d_in[2];
  const float* enc_W = (const float*)d_in[3];
  const float* enc_b = (const float*)d_in[4];
  const float* W1    = (const float*)d_in[5];
  const float* b1    = (const float*)d_in[6];
  const float* g1    = (const float*)d_in[7];
  const float* beta1 = (const float*)d_in[8];
  const float* rm1   = (const float*)d_in[9];
  const float* rv1   = (const float*)d_in[10];
  const float* W2    = (const float*)d_in[11];
  const float* b2    = (const float*)d_in[12];
  const float* g2    = (const float*)d_in[13];
  const float* beta2 = (const float*)d_in[14];
  const float* rm2   = (const float*)d_in[15];
  const float* rv2   = (const float*)d_in[16];
  const float* eps   = (const float*)d_in[17];
  const float* og    = (const float*)d_in[18];
  const float* ob    = (const float*)d_in[19];
  const float* orm   = (const float*)d_in[20];
  const float* orv   = (const float*)d_in[21];
  const float* aW1   = (const float*)d_in[22];
  const float* ab1   = (const float*)d_in[23];
  const float* aW2   = (const float*)d_in[24];
  const float* ab2   = (const float*)d_in[25];
  const float* aW3   = (const float*)d_in[26];
  const float* ab3   = (const float*)d_in[27];
  const float* temp  = (const float*)d_in[28];
  const float* cW1   = (const float*)d_in[29];
  const float* cb1   = (const float*)d_in[30];
  const float* cW2   = (const float*)d_in[31];
  const float* cb2   = (const float*)d_in[32];

  int N = in_sizes[0] / D;
  int E = in_sizes[1] / 2;
  int B = (out_size - N) / (3 + D);
  int nb = (N + 511) >> BSH;     // buckets of 512 nodes (<=128 for N<=65536)

  // workspace layout (hbufA/hbufB ping-pong across layers)
  unsigned short* hbufA = (unsigned short*)d_ws;
  unsigned short* hbufB = hbufA + (size_t)N * D;
  int* row_ptr = (int*)(hbufB + (size_t)N * D);
  int* colidx  = row_ptr + N + 1;
  int* bcnt    = colidx + E;            // nb*BPAD
  int* boff    = bcnt + nb * BPAD;      // nb+1
  int* bcur    = boff + nb + 1;         // nb*BPAD
  uintptr_t p = (uintptr_t)(bcur + nb * BPAD);
  p = (p + 15) & ~(uintptr_t)15;
  unsigned* pairs = (unsigned*)p;       // E packed records
  unsigned short* WT = (unsigned short*)(pairs + E);   // 7*128*128 bf16
  float4* sc_all = (float4*)(WT + 7 * D * D);          // 7*128 float4

  float* logits = (float*)d_out;
  float* ge     = logits + (size_t)B * 3;
  float* scores = ge + (size_t)B * D;

  k_prep_w<<<7, 256, 0, stream>>>(enc_W, W1, W2, WT);
  k_scales<<<7, 128, 0, stream>>>(enc_b, b1, g1, beta1, rm1, rv1,
                                  b2, g2, beta2, rm2, rv2, og, ob, orm, orv, sc_all);

  // bucketed CSR build (packed 4B records, LDS-staged scatter)
  hipMemsetAsync(bcnt, 0, (size_t)nb * BPAD * sizeof(int), stream);
  k_bhist<<<256, 256, 0, stream>>>(ei, bcnt, E, nb);
  k_bktscan<<<1, 128, 0, stream>>>(bcnt, boff, bcur, row_ptr, nb, N, E);
  k_bscatter<<<(E + 2047) / 2048, 256, 0, stream>>>(ei, bcur, pairs, E, nb);
  k_bplace<<<nb, 256, 0, stream>>>(pairs, boff, row_ptr, colidx, N);

  int gblocks = (N + 63) / 64;
  // encoder: h = relu(x@enc_W + enc_b)
  k_mfma<<<gblocks, 256, 0, stream>>>(x, WT, sc_all, hbufA, N);

  unsigned short* cur = hbufA;
  unsigned short* nxt = hbufB;
  for (int l = 0; l < 3; l++) {
    k_layer<<<gblocks, 256, 0, stream>>>(cur, row_ptr, colidx, eps, l,
        WT + (size_t)(1 + 2 * l) * D * D, WT + (size_t)(2 + 2 * l) * D * D,
        sc_all + (1 + 2 * l) * D, sc_all + (2 + 2 * l) * D, nxt, N);
    unsigned short* t = cur; cur = nxt; nxt = t;
  }

  k_attention<<<gblocks, 256, 0, stream>>>(cur, aW1, ab1, aW2, ab2, aW3, ab3,
                                           temp, scores, N);
  hipMemsetAsync(ge, 0, (size_t)B * D * sizeof(float), stream);
  k_pool<<<(N + 31) / 32, 128, 0, stream>>>(cur, scores, batch, ge, N);
  k_classifier<<<B, 128, 0, stream>>>(ge, cW1, cb1, cW2, cb2, logits, B);
}